// Round 2
// baseline (69047.241 us; speedup 1.0000x reference)
//
#include <hip/hip_runtime.h>
#include <hip/hip_bf16.h>
#include <cstdint>
#include <cstddef>

// Net: B=256, D=512, L=8, H=8, T=71->64, DH=64.
// Round 0: correct f32 baseline. All heavy compute on vector ALU.
// ws layout (floats): X71 (B*512*71) | X64 (B*512*64) | T1 (B*1024*64, layer tmp
// uses first half; final co1 output uses the whole region). Total ~138 MB.

__device__ __forceinline__ float lrelu(float v) { return v > 0.f ? v : 0.2f * v; }

// ---------------------------------------------------------------------------
// Stage 1: embeddings + LayerNorm over T=71. One thread per (b,d), two passes.
// Output X71[b][d][t]  (B,512,71)
// ---------------------------------------------------------------------------
__global__ __launch_bounds__(256) void build_ln_kernel(
    const int* __restrict__ fen, const int* __restrict__ move,
    const float* __restrict__ rank_emb, const float* __restrict__ file_emb,
    const float* __restrict__ fen_emb, const float* __restrict__ move_emb,
    const float* __restrict__ abs_emb, const float* __restrict__ lnw,
    const float* __restrict__ lnb, float* __restrict__ X71)
{
  const int gid = blockIdx.x * 256 + threadIdx.x;   // < 256*512
  const int b = gid >> 9, d = gid & 511;
  const int* fb = fen + b * 133;

  float sum = 0.f, sq = 0.f, mu = 0.f, rstd = 0.f;
  #pragma unroll 1
  for (int pass = 0; pass < 2; ++pass) {
    if (pass) {
      mu = sum * (1.f / 71.f);
      float var = sq * (1.f / 71.f) - mu * mu;
      rstd = rsqrtf(var + 1e-5f);
    }
    #pragma unroll 1
    for (int t = 0; t < 71; ++t) {
      float a = abs_emb[t * 512 + d];
      float v;
      if (t < 64) {
        float pos = rank_emb[(t >> 3) * 512 + d] + file_emb[(t & 7) * 512 + d];
        v = 0.5f * (fen_emb[fb[t] * 512 + d] + fen_emb[fb[64 + t] * 512 + d] + pos) + a;
      } else if (t < 69) {
        // fen index 128 + (t-64) == t + 64
        v = fen_emb[fb[t + 64] * 512 + d] + a;
      } else {
        int j = t - 69;
        int s = move[b * 2 + j];
        float pos = rank_emb[(s >> 3) * 512 + d] + file_emb[(s & 7) * 512 + d];
        v = (pos + move_emb[j * 512 + d]) * 0.58f + a;
      }
      if (pass) X71[(size_t)gid * 71 + t] = (v - mu) * rstd * lnw[t] + lnb[t];
      else { sum += v; sq += v * v; }
    }
  }
}

// ---------------------------------------------------------------------------
// Fused MHA: per-(b,h) block. lrelu(x) -> QKV gemm (weights staged in LDS) ->
// RMS over token axis -> softmax(QK^T/8) -> PV. Writes y (B,512,64).
// qkv LDS rows padded to 65 floats: bank = (row+lane)%32, conflict-free.
// ---------------------------------------------------------------------------
template <int T>
__global__ __launch_bounds__(256) void mha_kernel(
    const float* __restrict__ x,   // (B,512,T)
    const float* __restrict__ w,   // (3,8,512,64)
    const float* __restrict__ nw,  // scalar rms weight
    float* __restrict__ y)         // (B,512,64)
{
  const int b = blockIdx.x >> 3;
  const int h = blockIdx.x & 7;
  const int tid = threadIdx.x;
  const int lane = tid & 63;
  const int wv = tid >> 6;

  __shared__ float qkv[3 * T * 65];
  __shared__ float wl[3 * 16 * 64];   // [n][dc][dh] for current 16-d chunk
  __shared__ float xs[16 * T];        // lrelu(x) chunk [dc][t]
  __shared__ float scale[192];
  __shared__ float plds[64 * (T + 1)];

  for (int i = tid; i < 3 * T * 65; i += 256) qkv[i] = 0.f;
  __syncthreads();

  const float* wh = w + (size_t)h * 512 * 64;
  for (int c0 = 0; c0 < 512; c0 += 16) {
    for (int i = tid; i < 16 * T; i += 256) {
      int dc = i / T, t = i - dc * T;
      xs[i] = lrelu(x[((size_t)b * 512 + c0 + dc) * T + t]);
    }
    for (int i = tid; i < 3 * 16 * 64; i += 256) {
      int n = i >> 10;
      int rem = i & 1023;
      int dc = rem >> 6, dh = rem & 63;
      wl[i] = wh[((size_t)n * 8 * 512 + c0 + dc) * 64 + dh];
    }
    __syncthreads();
    for (int n = 0; n < 3; ++n) {
      for (int tb = wv * 4; tb < T; tb += 16) {
        const int t1 = (tb + 1 < T) ? tb + 1 : T - 1;
        const int t2 = (tb + 2 < T) ? tb + 2 : T - 1;
        const int t3 = (tb + 3 < T) ? tb + 3 : T - 1;
        float a0 = 0.f, a1 = 0.f, a2 = 0.f, a3 = 0.f;
        #pragma unroll
        for (int dc = 0; dc < 16; ++dc) {
          float wvv = wl[(n * 16 + dc) * 64 + lane];
          a0 += xs[dc * T + tb] * wvv;
          a1 += xs[dc * T + t1] * wvv;
          a2 += xs[dc * T + t2] * wvv;
          a3 += xs[dc * T + t3] * wvv;
        }
        qkv[(n * T + tb) * 65 + lane] += a0;
        if (tb + 1 < T) qkv[(n * T + tb + 1) * 65 + lane] += a1;
        if (tb + 2 < T) qkv[(n * T + tb + 2) * 65 + lane] += a2;
        if (tb + 3 < T) qkv[(n * T + tb + 3) * 65 + lane] += a3;
      }
    }
    __syncthreads();
  }

  // RMS over token axis per (n, dh)
  if (tid < 192) {
    int n = tid >> 6, dh = tid & 63;
    float ss = 0.f;
    for (int t = 0; t < T; ++t) { float v = qkv[(n * T + t) * 65 + dh]; ss += v * v; }
    scale[tid] = nw[0] * rsqrtf(ss * (1.f / T) + 1e-6f);
  }
  __syncthreads();
  for (int i = tid; i < 3 * T * 64; i += 256) {
    int n = i / (T * 64);
    int rem = i - n * T * 64;
    int t = rem >> 6, dh = rem & 63;
    qkv[(n * T + t) * 65 + dh] *= scale[n * 64 + dh];
  }
  __syncthreads();

  const float* qm = qkv;
  const float* km = qkv + T * 65;
  const float* vm = qkv + 2 * T * 65;

  // scores + softmax, query rows t < 64 (only those feed the output slice)
  for (int t = wv; t < 64; t += 4) {
    float s0 = 0.f, s1 = 0.f;
    #pragma unroll 8
    for (int dh = 0; dh < 64; ++dh) {
      s0 += qm[t * 65 + dh] * km[lane * 65 + dh];
    }
    bool has1 = false;
    if constexpr (T > 64) {
      has1 = (lane + 64 < T);
      if (has1) {
        #pragma unroll 8
        for (int dh = 0; dh < 64; ++dh)
          s1 += qm[t * 65 + dh] * km[(lane + 64) * 65 + dh];
      }
    }
    s0 *= 0.125f;
    s1 *= 0.125f;
    float mx = has1 ? fmaxf(s0, s1) : s0;
    #pragma unroll
    for (int off = 32; off; off >>= 1) mx = fmaxf(mx, __shfl_xor(mx, off));
    float e0 = __expf(s0 - mx);
    float e1 = has1 ? __expf(s1 - mx) : 0.f;
    float sm = e0 + e1;
    #pragma unroll
    for (int off = 32; off; off >>= 1) sm += __shfl_xor(sm, off);
    float inv = 1.f / sm;
    plds[t * (T + 1) + lane] = e0 * inv;
    if constexpr (T > 64) {
      if (lane < T - 64) plds[t * (T + 1) + 64 + lane] = e1 * inv;
    }
  }
  __syncthreads();

  // out[b, h*64+dh, t] = sum_j p[t][j] * v[j][dh]
  float* yb = y + ((size_t)b * 512 + h * 64 + lane) * 64;
  for (int t = wv; t < 64; t += 4) {
    float acc = 0.f;
    #pragma unroll 8
    for (int j = 0; j < T; ++j)
      acc += plds[t * (T + 1) + j] * vm[j * 65 + lane];
    yb[t] = acc;
  }
}

// ---------------------------------------------------------------------------
// dst[r][t] = a[r][t (stride aStride)] + bsrc[r][t]; grid covers B*512*64.
// ---------------------------------------------------------------------------
__global__ __launch_bounds__(256) void add_slice_kernel(
    float* __restrict__ dst, const float* __restrict__ a, int aStride,
    const float* __restrict__ bsrc)
{
  size_t gid = (size_t)blockIdx.x * 256 + threadIdx.x;
  size_t r = gid >> 6;
  int t = (int)(gid & 63);
  dst[gid] = a[r * aStride + t] + bsrc[gid];
}

// ---------------------------------------------------------------------------
// 3x3 SAME conv on 8x8, lrelu applied to input. Block = (b, 64-oc tile).
// LDS: 16-channel input chunk + weights for the chunk. acc[16] per thread.
// Optional residual added in the epilogue.
// ---------------------------------------------------------------------------
__global__ __launch_bounds__(256) void conv3x3_kernel(
    const float* __restrict__ x,    // (B, CIN, 64)
    const float* __restrict__ w,    // (COUT, CIN, 9)
    const float* __restrict__ bias, // (COUT)
    const float* __restrict__ res,  // residual (B, COUT, 64) or nullptr
    float* __restrict__ out,        // (B, COUT, 64)
    int CIN, int COUT)
{
  const int nt = COUT >> 6;
  const int b = blockIdx.x / nt;
  const int ot = blockIdx.x - b * nt;
  const int tid = threadIdx.x;
  const int p = tid & 63;
  const int wg = tid >> 6;
  const int i0 = p >> 3, j0 = p & 7;

  __shared__ float xs[16 * 64];
  __shared__ float wl[64 * 16 * 9];

  float acc[16];
  #pragma unroll
  for (int i = 0; i < 16; ++i) acc[i] = bias[ot * 64 + wg * 16 + i];

  for (int c0 = 0; c0 < CIN; c0 += 16) {
    for (int idx = tid; idx < 1024; idx += 256) {
      int c = idx >> 6, pp = idx & 63;
      xs[idx] = lrelu(x[((size_t)b * CIN + c0 + c) * 64 + pp]);
    }
    for (int idx = tid; idx < 9216; idx += 256) {
      int o = idx / 144, rem = idx - o * 144;
      wl[idx] = w[((size_t)(ot * 64 + o) * CIN + c0) * 9 + rem];
    }
    __syncthreads();
    #pragma unroll
    for (int k = 0; k < 9; ++k) {
      const int dy = k / 3 - 1, dx = k - (k / 3) * 3 - 1;
      const int ii = i0 + dy, jj = j0 + dx;
      const bool valid = ((unsigned)ii < 8u) && ((unsigned)jj < 8u);
      const int np = ii * 8 + jj;
      #pragma unroll 4
      for (int c = 0; c < 16; ++c) {
        float xv = valid ? xs[c * 64 + np] : 0.f;
        const float* wp = &wl[(wg * 16) * 144 + c * 9 + k];
        #pragma unroll
        for (int i = 0; i < 16; ++i)
          acc[i] += xv * wp[i * 144];
      }
    }
    __syncthreads();
  }
  #pragma unroll
  for (int i = 0; i < 16; ++i) {
    int o = ot * 64 + wg * 16 + i;
    size_t idx = ((size_t)b * COUT + o) * 64 + p;
    float v = acc[i];
    if (res) v += res[idx];
    out[idx] = v;
  }
}

// ---------------------------------------------------------------------------
// RMS over the 64 spatial positions per (b, channel) row, in place.
// ---------------------------------------------------------------------------
__global__ __launch_bounds__(256) void rms_spatial_kernel(
    float* __restrict__ y, const float* __restrict__ nw, int nrows)
{
  int gid = blockIdx.x * 256 + threadIdx.x;
  if (gid >= nrows) return;
  float* row = y + (size_t)gid * 64;
  float ss = 0.f;
  #pragma unroll 8
  for (int p = 0; p < 64; ++p) { float v = row[p]; ss += v * v; }
  float sc = nw[0] * rsqrtf(ss * (1.f / 64.f) + 1e-6f);
  #pragma unroll 8
  for (int p = 0; p < 64; ++p) row[p] *= sc;
}

// ---------------------------------------------------------------------------
// Final VALID 8x8 conv: out[b] = sum_{c,p} lrelu(F1[b,c,p]) * w[c,p] + bias.
// ---------------------------------------------------------------------------
__global__ __launch_bounds__(256) void co2_kernel(
    const float* __restrict__ xf,  // (B, 1024, 64)
    const float* __restrict__ w,   // (1024*64)
    const float* __restrict__ cb,  // scalar
    float* __restrict__ out)
{
  const int b = blockIdx.x, tid = threadIdx.x;
  const float* xb = xf + (size_t)b * 65536;
  float acc = 0.f;
  for (int i = tid; i < 65536; i += 256)
    acc += lrelu(xb[i]) * w[i];
  #pragma unroll
  for (int off = 32; off; off >>= 1) acc += __shfl_down(acc, off);
  __shared__ float red[4];
  if ((tid & 63) == 0) red[tid >> 6] = acc;
  __syncthreads();
  if (tid == 0) out[b] = red[0] + red[1] + red[2] + red[3] + cb[0];
}

// ---------------------------------------------------------------------------
extern "C" void kernel_launch(void* const* d_in, const int* in_sizes, int n_in,
                              void* d_out, int out_size, void* d_ws, size_t ws_size,
                              hipStream_t stream)
{
  const int*   fen        = (const int*)d_in[0];
  const int*   move       = (const int*)d_in[1];
  const float* rank_emb   = (const float*)d_in[2];
  const float* file_emb   = (const float*)d_in[3];
  const float* fen_emb    = (const float*)d_in[4];
  const float* move_emb   = (const float*)d_in[5];
  const float* abs_emb    = (const float*)d_in[6];
  const float* ln_w       = (const float*)d_in[7];
  const float* ln_b       = (const float*)d_in[8];
  const float* emb_qkv    = (const float*)d_in[9];
  const float* emb_norm_w = (const float*)d_in[10];
  const float* qkv        = (const float*)d_in[11];
  const float* mha_norm_w = (const float*)d_in[12];
  const float* conv1_w    = (const float*)d_in[13];
  const float* conv1_b    = (const float*)d_in[14];
  const float* conv2_w    = (const float*)d_in[15];
  const float* conv2_b    = (const float*)d_in[16];
  const float* cb_norm_w  = (const float*)d_in[17];
  const float* out_norm_w = (const float*)d_in[18];
  const float* co1_w      = (const float*)d_in[19];
  const float* co1_b      = (const float*)d_in[20];
  const float* co2_w      = (const float*)d_in[21];
  const float* co2_b      = (const float*)d_in[22];
  float* out = (float*)d_out;

  float* ws  = (float*)d_ws;
  float* X71 = ws;                               // 256*512*71 = 9,306,112
  float* X64 = X71 + (size_t)256 * 512 * 71;     // 256*512*64 = 8,388,608
  float* T1  = X64 + (size_t)256 * 512 * 64;     // 16,777,216 (layer tmp / co1 out)
  float* F1  = T1;

  // embeddings + layernorm
  build_ln_kernel<<<512, 256, 0, stream>>>(fen, move, rank_emb, file_emb,
                                           fen_emb, move_emb, abs_emb,
                                           ln_w, ln_b, X71);
  // embedding MHA (T=71), then x = x[:, :, :64] + y[:, :, :64]
  mha_kernel<71><<<2048, 256, 0, stream>>>(X71, emb_qkv, emb_norm_w, T1);
  add_slice_kernel<<<32768, 256, 0, stream>>>(X64, X71, 71, T1);

  for (int l = 0; l < 8; ++l) {
    const float* w1 = conv1_w + (size_t)l * 512 * 512 * 9;
    const float* w2 = conv2_w + (size_t)l * 512 * 512 * 9;
    // conv block: conv1 -> rms(spatial) -> conv2 (+residual into X64)
    conv3x3_kernel<<<2048, 256, 0, stream>>>(X64, w1, conv1_b + l * 512,
                                             nullptr, T1, 512, 512);
    rms_spatial_kernel<<<512, 256, 0, stream>>>(T1, cb_norm_w + l, 256 * 512);
    conv3x3_kernel<<<2048, 256, 0, stream>>>(T1, w2, conv2_b + l * 512,
                                             X64, X64, 512, 512);
    // MHA + residual
    mha_kernel<64><<<2048, 256, 0, stream>>>(X64, qkv + (size_t)l * 3 * 8 * 512 * 64,
                                             mha_norm_w + l, T1);
    add_slice_kernel<<<32768, 256, 0, stream>>>(X64, X64, 64, T1);
  }

  // head: co1 (512->1024 SAME) -> rms(spatial) -> co2 (VALID 8x8 -> scalar)
  conv3x3_kernel<<<4096, 256, 0, stream>>>(X64, co1_w, co1_b, nullptr, F1, 512, 1024);
  rms_spatial_kernel<<<1024, 256, 0, stream>>>(F1, out_norm_w, 256 * 1024);
  co2_kernel<<<256, 256, 0, stream>>>(F1, co2_w, co2_b, out);
}

// Round 3
// 68572.394 us; speedup vs baseline: 1.0069x; 1.0069x over previous
//
#include <hip/hip_runtime.h>
#include <hip/hip_bf16.h>
#include <cstdint>
#include <cstddef>

// Net: B=256, D=512, L=8, H=8, T=71->64, DH=64.
// Round 0: correct f32 baseline. All heavy compute on vector ALU.
// ws layout (floats): X71 (B*512*71) | X64 (B*512*64) | T1 (B*1024*64, layer tmp
// uses first half; final co1 output uses the whole region). Total ~138 MB.

__device__ __forceinline__ float lrelu(float v) { return v > 0.f ? v : 0.2f * v; }

// ---------------------------------------------------------------------------
// Stage 1: embeddings + LayerNorm over T=71. One thread per (b,d), two passes.
// Output X71[b][d][t]  (B,512,71)
// ---------------------------------------------------------------------------
__global__ __launch_bounds__(256) void build_ln_kernel(
    const int* __restrict__ fen, const int* __restrict__ move,
    const float* __restrict__ rank_emb, const float* __restrict__ file_emb,
    const float* __restrict__ fen_emb, const float* __restrict__ move_emb,
    const float* __restrict__ abs_emb, const float* __restrict__ lnw,
    const float* __restrict__ lnb, float* __restrict__ X71)
{
  const int gid = blockIdx.x * 256 + threadIdx.x;   // < 256*512
  const int b = gid >> 9, d = gid & 511;
  const int* fb = fen + b * 133;

  float sum = 0.f, sq = 0.f, mu = 0.f, rstd = 0.f;
  #pragma unroll 1
  for (int pass = 0; pass < 2; ++pass) {
    if (pass) {
      mu = sum * (1.f / 71.f);
      float var = sq * (1.f / 71.f) - mu * mu;
      rstd = rsqrtf(var + 1e-5f);
    }
    #pragma unroll 1
    for (int t = 0; t < 71; ++t) {
      float a = abs_emb[t * 512 + d];
      float v;
      if (t < 64) {
        float pos = rank_emb[(t >> 3) * 512 + d] + file_emb[(t & 7) * 512 + d];
        v = 0.5f * (fen_emb[fb[t] * 512 + d] + fen_emb[fb[64 + t] * 512 + d] + pos) + a;
      } else if (t < 69) {
        // fen index 128 + (t-64) == t + 64
        v = fen_emb[fb[t + 64] * 512 + d] + a;
      } else {
        int j = t - 69;
        int s = move[b * 2 + j];
        float pos = rank_emb[(s >> 3) * 512 + d] + file_emb[(s & 7) * 512 + d];
        v = (pos + move_emb[j * 512 + d]) * 0.58f + a;
      }
      if (pass) X71[(size_t)gid * 71 + t] = (v - mu) * rstd * lnw[t] + lnb[t];
      else { sum += v; sq += v * v; }
    }
  }
}

// ---------------------------------------------------------------------------
// Fused MHA: per-(b,h) block. lrelu(x) -> QKV gemm (weights staged in LDS) ->
// RMS over token axis -> softmax(QK^T/8) -> PV. Writes y (B,512,64).
// qkv LDS rows padded to 65 floats: bank = (row+lane)%32, conflict-free.
// ---------------------------------------------------------------------------
template <int T>
__global__ __launch_bounds__(256) void mha_kernel(
    const float* __restrict__ x,   // (B,512,T)
    const float* __restrict__ w,   // (3,8,512,64)
    const float* __restrict__ nw,  // scalar rms weight
    float* __restrict__ y)         // (B,512,64)
{
  const int b = blockIdx.x >> 3;
  const int h = blockIdx.x & 7;
  const int tid = threadIdx.x;
  const int lane = tid & 63;
  const int wv = tid >> 6;

  __shared__ float qkv[3 * T * 65];
  __shared__ float wl[3 * 16 * 64];   // [n][dc][dh] for current 16-d chunk
  __shared__ float xs[16 * T];        // lrelu(x) chunk [dc][t]
  __shared__ float scale[192];
  __shared__ float plds[64 * (T + 1)];

  for (int i = tid; i < 3 * T * 65; i += 256) qkv[i] = 0.f;
  __syncthreads();

  const float* wh = w + (size_t)h * 512 * 64;
  for (int c0 = 0; c0 < 512; c0 += 16) {
    for (int i = tid; i < 16 * T; i += 256) {
      int dc = i / T, t = i - dc * T;
      xs[i] = lrelu(x[((size_t)b * 512 + c0 + dc) * T + t]);
    }
    for (int i = tid; i < 3 * 16 * 64; i += 256) {
      int n = i >> 10;
      int rem = i & 1023;
      int dc = rem >> 6, dh = rem & 63;
      wl[i] = wh[((size_t)n * 8 * 512 + c0 + dc) * 64 + dh];
    }
    __syncthreads();
    for (int n = 0; n < 3; ++n) {
      for (int tb = wv * 4; tb < T; tb += 16) {
        const int t1 = (tb + 1 < T) ? tb + 1 : T - 1;
        const int t2 = (tb + 2 < T) ? tb + 2 : T - 1;
        const int t3 = (tb + 3 < T) ? tb + 3 : T - 1;
        float a0 = 0.f, a1 = 0.f, a2 = 0.f, a3 = 0.f;
        #pragma unroll
        for (int dc = 0; dc < 16; ++dc) {
          float wvv = wl[(n * 16 + dc) * 64 + lane];
          a0 += xs[dc * T + tb] * wvv;
          a1 += xs[dc * T + t1] * wvv;
          a2 += xs[dc * T + t2] * wvv;
          a3 += xs[dc * T + t3] * wvv;
        }
        qkv[(n * T + tb) * 65 + lane] += a0;
        if (tb + 1 < T) qkv[(n * T + tb + 1) * 65 + lane] += a1;
        if (tb + 2 < T) qkv[(n * T + tb + 2) * 65 + lane] += a2;
        if (tb + 3 < T) qkv[(n * T + tb + 3) * 65 + lane] += a3;
      }
    }
    __syncthreads();
  }

  // RMS over token axis per (n, dh)
  if (tid < 192) {
    int n = tid >> 6, dh = tid & 63;
    float ss = 0.f;
    for (int t = 0; t < T; ++t) { float v = qkv[(n * T + t) * 65 + dh]; ss += v * v; }
    scale[tid] = nw[0] * rsqrtf(ss * (1.f / T) + 1e-6f);
  }
  __syncthreads();
  for (int i = tid; i < 3 * T * 64; i += 256) {
    int n = i / (T * 64);
    int rem = i - n * T * 64;
    int t = rem >> 6, dh = rem & 63;
    qkv[(n * T + t) * 65 + dh] *= scale[n * 64 + dh];
  }
  __syncthreads();

  const float* qm = qkv;
  const float* km = qkv + T * 65;
  const float* vm = qkv + 2 * T * 65;

  // scores + softmax, query rows t < 64 (only those feed the output slice)
  for (int t = wv; t < 64; t += 4) {
    float s0 = 0.f, s1 = 0.f;
    #pragma unroll 8
    for (int dh = 0; dh < 64; ++dh) {
      s0 += qm[t * 65 + dh] * km[lane * 65 + dh];
    }
    bool has1 = false;
    if constexpr (T > 64) {
      has1 = (lane + 64 < T);
      if (has1) {
        #pragma unroll 8
        for (int dh = 0; dh < 64; ++dh)
          s1 += qm[t * 65 + dh] * km[(lane + 64) * 65 + dh];
      }
    }
    s0 *= 0.125f;
    s1 *= 0.125f;
    float mx = has1 ? fmaxf(s0, s1) : s0;
    #pragma unroll
    for (int off = 32; off; off >>= 1) mx = fmaxf(mx, __shfl_xor(mx, off));
    float e0 = __expf(s0 - mx);
    float e1 = has1 ? __expf(s1 - mx) : 0.f;
    float sm = e0 + e1;
    #pragma unroll
    for (int off = 32; off; off >>= 1) sm += __shfl_xor(sm, off);
    float inv = 1.f / sm;
    plds[t * (T + 1) + lane] = e0 * inv;
    if constexpr (T > 64) {
      if (lane < T - 64) plds[t * (T + 1) + 64 + lane] = e1 * inv;
    }
  }
  __syncthreads();

  // out[b, h*64+dh, t] = sum_j p[t][j] * v[j][dh]
  float* yb = y + ((size_t)b * 512 + h * 64 + lane) * 64;
  for (int t = wv; t < 64; t += 4) {
    float acc = 0.f;
    #pragma unroll 8
    for (int j = 0; j < T; ++j)
      acc += plds[t * (T + 1) + j] * vm[j * 65 + lane];
    yb[t] = acc;
  }
}

// ---------------------------------------------------------------------------
// dst[r][t] = a[r][t (stride aStride)] + bsrc[r][t]; grid covers B*512*64.
// ---------------------------------------------------------------------------
__global__ __launch_bounds__(256) void add_slice_kernel(
    float* __restrict__ dst, const float* __restrict__ a, int aStride,
    const float* __restrict__ bsrc)
{
  size_t gid = (size_t)blockIdx.x * 256 + threadIdx.x;
  size_t r = gid >> 6;
  int t = (int)(gid & 63);
  dst[gid] = a[r * aStride + t] + bsrc[gid];
}

// ---------------------------------------------------------------------------
// 3x3 SAME conv on 8x8, lrelu applied to input. Block = (b, 64-oc tile).
// LDS: 16-channel input chunk + weights for the chunk. acc[16] per thread.
// Optional residual added in the epilogue.
// ---------------------------------------------------------------------------
__global__ __launch_bounds__(256) void conv3x3_kernel(
    const float* __restrict__ x,    // (B, CIN, 64)
    const float* __restrict__ w,    // (COUT, CIN, 9)
    const float* __restrict__ bias, // (COUT)
    const float* __restrict__ res,  // residual (B, COUT, 64) or nullptr
    float* __restrict__ out,        // (B, COUT, 64)
    int CIN, int COUT)
{
  const int nt = COUT >> 6;
  const int b = blockIdx.x / nt;
  const int ot = blockIdx.x - b * nt;
  const int tid = threadIdx.x;
  const int p = tid & 63;
  const int wg = tid >> 6;
  const int i0 = p >> 3, j0 = p & 7;

  __shared__ float xs[16 * 64];
  __shared__ float wl[64 * 16 * 9];

  float acc[16];
  #pragma unroll
  for (int i = 0; i < 16; ++i) acc[i] = bias[ot * 64 + wg * 16 + i];

  for (int c0 = 0; c0 < CIN; c0 += 16) {
    for (int idx = tid; idx < 1024; idx += 256) {
      int c = idx >> 6, pp = idx & 63;
      xs[idx] = lrelu(x[((size_t)b * CIN + c0 + c) * 64 + pp]);
    }
    for (int idx = tid; idx < 9216; idx += 256) {
      int o = idx / 144, rem = idx - o * 144;
      wl[idx] = w[((size_t)(ot * 64 + o) * CIN + c0) * 9 + rem];
    }
    __syncthreads();
    #pragma unroll
    for (int k = 0; k < 9; ++k) {
      const int dy = k / 3 - 1, dx = k - (k / 3) * 3 - 1;
      const int ii = i0 + dy, jj = j0 + dx;
      const bool valid = ((unsigned)ii < 8u) && ((unsigned)jj < 8u);
      const int np = ii * 8 + jj;
      #pragma unroll 4
      for (int c = 0; c < 16; ++c) {
        float xv = valid ? xs[c * 64 + np] : 0.f;
        const float* wp = &wl[(wg * 16) * 144 + c * 9 + k];
        #pragma unroll
        for (int i = 0; i < 16; ++i)
          acc[i] += xv * wp[i * 144];
      }
    }
    __syncthreads();
  }
  #pragma unroll
  for (int i = 0; i < 16; ++i) {
    int o = ot * 64 + wg * 16 + i;
    size_t idx = ((size_t)b * COUT + o) * 64 + p;
    float v = acc[i];
    if (res) v += res[idx];
    out[idx] = v;
  }
}

// ---------------------------------------------------------------------------
// RMS over the 64 spatial positions per (b, channel) row, in place.
// ---------------------------------------------------------------------------
__global__ __launch_bounds__(256) void rms_spatial_kernel(
    float* __restrict__ y, const float* __restrict__ nw, int nrows)
{
  int gid = blockIdx.x * 256 + threadIdx.x;
  if (gid >= nrows) return;
  float* row = y + (size_t)gid * 64;
  float ss = 0.f;
  #pragma unroll 8
  for (int p = 0; p < 64; ++p) { float v = row[p]; ss += v * v; }
  float sc = nw[0] * rsqrtf(ss * (1.f / 64.f) + 1e-6f);
  #pragma unroll 8
  for (int p = 0; p < 64; ++p) row[p] *= sc;
}

// ---------------------------------------------------------------------------
// Final VALID 8x8 conv: out[b] = sum_{c,p} lrelu(F1[b,c,p]) * w[c,p] + bias.
// ---------------------------------------------------------------------------
__global__ __launch_bounds__(256) void co2_kernel(
    const float* __restrict__ xf,  // (B, 1024, 64)
    const float* __restrict__ w,   // (1024*64)
    const float* __restrict__ cb,  // scalar
    float* __restrict__ out)
{
  const int b = blockIdx.x, tid = threadIdx.x;
  const float* xb = xf + (size_t)b * 65536;
  float acc = 0.f;
  for (int i = tid; i < 65536; i += 256)
    acc += lrelu(xb[i]) * w[i];
  #pragma unroll
  for (int off = 32; off; off >>= 1) acc += __shfl_down(acc, off);
  __shared__ float red[4];
  if ((tid & 63) == 0) red[tid >> 6] = acc;
  __syncthreads();
  if (tid == 0) out[b] = red[0] + red[1] + red[2] + red[3] + cb[0];
}

// ---------------------------------------------------------------------------
extern "C" void kernel_launch(void* const* d_in, const int* in_sizes, int n_in,
                              void* d_out, int out_size, void* d_ws, size_t ws_size,
                              hipStream_t stream)
{
  const int*   fen        = (const int*)d_in[0];
  const int*   move       = (const int*)d_in[1];
  const float* rank_emb   = (const float*)d_in[2];
  const float* file_emb   = (const float*)d_in[3];
  const float* fen_emb    = (const float*)d_in[4];
  const float* move_emb   = (const float*)d_in[5];
  const float* abs_emb    = (const float*)d_in[6];
  const float* ln_w       = (const float*)d_in[7];
  const float* ln_b       = (const float*)d_in[8];
  const float* emb_qkv    = (const float*)d_in[9];
  const float* emb_norm_w = (const float*)d_in[10];
  const float* qkv        = (const float*)d_in[11];
  const float* mha_norm_w = (const float*)d_in[12];
  const float* conv1_w    = (const float*)d_in[13];
  const float* conv1_b    = (const float*)d_in[14];
  const float* conv2_w    = (const float*)d_in[15];
  const float* conv2_b    = (const float*)d_in[16];
  const float* cb_norm_w  = (const float*)d_in[17];
  const float* out_norm_w = (const float*)d_in[18];
  const float* co1_w      = (const float*)d_in[19];
  const float* co1_b      = (const float*)d_in[20];
  const float* co2_w      = (const float*)d_in[21];
  const float* co2_b      = (const float*)d_in[22];
  float* out = (float*)d_out;

  float* ws  = (float*)d_ws;
  float* X71 = ws;                               // 256*512*71 = 9,306,112
  float* X64 = X71 + (size_t)256 * 512 * 71;     // 256*512*64 = 8,388,608
  float* T1  = X64 + (size_t)256 * 512 * 64;     // 16,777,216 (layer tmp / co1 out)
  float* F1  = T1;

  // embeddings + layernorm
  build_ln_kernel<<<512, 256, 0, stream>>>(fen, move, rank_emb, file_emb,
                                           fen_emb, move_emb, abs_emb,
                                           ln_w, ln_b, X71);
  // embedding MHA (T=71), then x = x[:, :, :64] + y[:, :, :64]
  mha_kernel<71><<<2048, 256, 0, stream>>>(X71, emb_qkv, emb_norm_w, T1);
  add_slice_kernel<<<32768, 256, 0, stream>>>(X64, X71, 71, T1);

  for (int l = 0; l < 8; ++l) {
    const float* w1 = conv1_w + (size_t)l * 512 * 512 * 9;
    const float* w2 = conv2_w + (size_t)l * 512 * 512 * 9;
    // conv block: conv1 -> rms(spatial) -> conv2 (+residual into X64)
    conv3x3_kernel<<<2048, 256, 0, stream>>>(X64, w1, conv1_b + l * 512,
                                             nullptr, T1, 512, 512);
    rms_spatial_kernel<<<512, 256, 0, stream>>>(T1, cb_norm_w + l, 256 * 512);
    conv3x3_kernel<<<2048, 256, 0, stream>>>(T1, w2, conv2_b + l * 512,
                                             X64, X64, 512, 512);
    // MHA + residual
    mha_kernel<64><<<2048, 256, 0, stream>>>(X64, qkv + (size_t)l * 3 * 8 * 512 * 64,
                                             mha_norm_w + l, T1);
    add_slice_kernel<<<32768, 256, 0, stream>>>(X64, X64, 64, T1);
  }

  // head: co1 (512->1024 SAME) -> rms(spatial) -> co2 (VALID 8x8 -> scalar)
  conv3x3_kernel<<<4096, 256, 0, stream>>>(X64, co1_w, co1_b, nullptr, F1, 512, 1024);
  rms_spatial_kernel<<<1024, 256, 0, stream>>>(F1, out_norm_w, 256 * 1024);
  co2_kernel<<<256, 256, 0, stream>>>(F1, co2_w, co2_b, out);
}

// Round 4
// 68527.417 us; speedup vs baseline: 1.0076x; 1.0007x over previous
//
#include <hip/hip_runtime.h>
#include <hip/hip_bf16.h>
#include <cstdint>
#include <cstddef>

// Net: B=256, D=512, L=8, H=8, T=71->64, DH=64.
// Round 0: correct f32 baseline. All heavy compute on vector ALU.
// ws layout (floats): X71 (B*512*71) | X64 (B*512*64) | T1 (B*1024*64, layer tmp
// uses first half; final co1 output uses the whole region). Total ~138 MB.

__device__ __forceinline__ float lrelu(float v) { return v > 0.f ? v : 0.2f * v; }

// ---------------------------------------------------------------------------
// Stage 1: embeddings + LayerNorm over T=71. One thread per (b,d), two passes.
// Output X71[b][d][t]  (B,512,71)
// ---------------------------------------------------------------------------
__global__ __launch_bounds__(256) void build_ln_kernel(
    const int* __restrict__ fen, const int* __restrict__ move,
    const float* __restrict__ rank_emb, const float* __restrict__ file_emb,
    const float* __restrict__ fen_emb, const float* __restrict__ move_emb,
    const float* __restrict__ abs_emb, const float* __restrict__ lnw,
    const float* __restrict__ lnb, float* __restrict__ X71)
{
  const int gid = blockIdx.x * 256 + threadIdx.x;   // < 256*512
  const int b = gid >> 9, d = gid & 511;
  const int* fb = fen + b * 133;

  float sum = 0.f, sq = 0.f, mu = 0.f, rstd = 0.f;
  #pragma unroll 1
  for (int pass = 0; pass < 2; ++pass) {
    if (pass) {
      mu = sum * (1.f / 71.f);
      float var = sq * (1.f / 71.f) - mu * mu;
      rstd = rsqrtf(var + 1e-5f);
    }
    #pragma unroll 1
    for (int t = 0; t < 71; ++t) {
      float a = abs_emb[t * 512 + d];
      float v;
      if (t < 64) {
        float pos = rank_emb[(t >> 3) * 512 + d] + file_emb[(t & 7) * 512 + d];
        v = 0.5f * (fen_emb[fb[t] * 512 + d] + fen_emb[fb[64 + t] * 512 + d] + pos) + a;
      } else if (t < 69) {
        // fen index 128 + (t-64) == t + 64
        v = fen_emb[fb[t + 64] * 512 + d] + a;
      } else {
        int j = t - 69;
        int s = move[b * 2 + j];
        float pos = rank_emb[(s >> 3) * 512 + d] + file_emb[(s & 7) * 512 + d];
        v = (pos + move_emb[j * 512 + d]) * 0.58f + a;
      }
      if (pass) X71[(size_t)gid * 71 + t] = (v - mu) * rstd * lnw[t] + lnb[t];
      else { sum += v; sq += v * v; }
    }
  }
}

// ---------------------------------------------------------------------------
// Fused MHA: per-(b,h) block. lrelu(x) -> QKV gemm (weights staged in LDS) ->
// RMS over token axis -> softmax(QK^T/8) -> PV. Writes y (B,512,64).
// qkv LDS rows padded to 65 floats: bank = (row+lane)%32, conflict-free.
// ---------------------------------------------------------------------------
template <int T>
__global__ __launch_bounds__(256) void mha_kernel(
    const float* __restrict__ x,   // (B,512,T)
    const float* __restrict__ w,   // (3,8,512,64)
    const float* __restrict__ nw,  // scalar rms weight
    float* __restrict__ y)         // (B,512,64)
{
  const int b = blockIdx.x >> 3;
  const int h = blockIdx.x & 7;
  const int tid = threadIdx.x;
  const int lane = tid & 63;
  const int wv = tid >> 6;

  __shared__ float qkv[3 * T * 65];
  __shared__ float wl[3 * 16 * 64];   // [n][dc][dh] for current 16-d chunk
  __shared__ float xs[16 * T];        // lrelu(x) chunk [dc][t]
  __shared__ float scale[192];
  __shared__ float plds[64 * (T + 1)];

  for (int i = tid; i < 3 * T * 65; i += 256) qkv[i] = 0.f;
  __syncthreads();

  const float* wh = w + (size_t)h * 512 * 64;
  for (int c0 = 0; c0 < 512; c0 += 16) {
    for (int i = tid; i < 16 * T; i += 256) {
      int dc = i / T, t = i - dc * T;
      xs[i] = lrelu(x[((size_t)b * 512 + c0 + dc) * T + t]);
    }
    for (int i = tid; i < 3 * 16 * 64; i += 256) {
      int n = i >> 10;
      int rem = i & 1023;
      int dc = rem >> 6, dh = rem & 63;
      wl[i] = wh[((size_t)n * 8 * 512 + c0 + dc) * 64 + dh];
    }
    __syncthreads();
    for (int n = 0; n < 3; ++n) {
      for (int tb = wv * 4; tb < T; tb += 16) {
        const int t1 = (tb + 1 < T) ? tb + 1 : T - 1;
        const int t2 = (tb + 2 < T) ? tb + 2 : T - 1;
        const int t3 = (tb + 3 < T) ? tb + 3 : T - 1;
        float a0 = 0.f, a1 = 0.f, a2 = 0.f, a3 = 0.f;
        #pragma unroll
        for (int dc = 0; dc < 16; ++dc) {
          float wvv = wl[(n * 16 + dc) * 64 + lane];
          a0 += xs[dc * T + tb] * wvv;
          a1 += xs[dc * T + t1] * wvv;
          a2 += xs[dc * T + t2] * wvv;
          a3 += xs[dc * T + t3] * wvv;
        }
        qkv[(n * T + tb) * 65 + lane] += a0;
        if (tb + 1 < T) qkv[(n * T + tb + 1) * 65 + lane] += a1;
        if (tb + 2 < T) qkv[(n * T + tb + 2) * 65 + lane] += a2;
        if (tb + 3 < T) qkv[(n * T + tb + 3) * 65 + lane] += a3;
      }
    }
    __syncthreads();
  }

  // RMS over token axis per (n, dh)
  if (tid < 192) {
    int n = tid >> 6, dh = tid & 63;
    float ss = 0.f;
    for (int t = 0; t < T; ++t) { float v = qkv[(n * T + t) * 65 + dh]; ss += v * v; }
    scale[tid] = nw[0] * rsqrtf(ss * (1.f / T) + 1e-6f);
  }
  __syncthreads();
  for (int i = tid; i < 3 * T * 64; i += 256) {
    int n = i / (T * 64);
    int rem = i - n * T * 64;
    int t = rem >> 6, dh = rem & 63;
    qkv[(n * T + t) * 65 + dh] *= scale[n * 64 + dh];
  }
  __syncthreads();

  const float* qm = qkv;
  const float* km = qkv + T * 65;
  const float* vm = qkv + 2 * T * 65;

  // scores + softmax, query rows t < 64 (only those feed the output slice)
  for (int t = wv; t < 64; t += 4) {
    float s0 = 0.f, s1 = 0.f;
    #pragma unroll 8
    for (int dh = 0; dh < 64; ++dh) {
      s0 += qm[t * 65 + dh] * km[lane * 65 + dh];
    }
    bool has1 = false;
    if constexpr (T > 64) {
      has1 = (lane + 64 < T);
      if (has1) {
        #pragma unroll 8
        for (int dh = 0; dh < 64; ++dh)
          s1 += qm[t * 65 + dh] * km[(lane + 64) * 65 + dh];
      }
    }
    s0 *= 0.125f;
    s1 *= 0.125f;
    float mx = has1 ? fmaxf(s0, s1) : s0;
    #pragma unroll
    for (int off = 32; off; off >>= 1) mx = fmaxf(mx, __shfl_xor(mx, off));
    float e0 = __expf(s0 - mx);
    float e1 = has1 ? __expf(s1 - mx) : 0.f;
    float sm = e0 + e1;
    #pragma unroll
    for (int off = 32; off; off >>= 1) sm += __shfl_xor(sm, off);
    float inv = 1.f / sm;
    plds[t * (T + 1) + lane] = e0 * inv;
    if constexpr (T > 64) {
      if (lane < T - 64) plds[t * (T + 1) + 64 + lane] = e1 * inv;
    }
  }
  __syncthreads();

  // out[b, h*64+dh, t] = sum_j p[t][j] * v[j][dh]
  float* yb = y + ((size_t)b * 512 + h * 64 + lane) * 64;
  for (int t = wv; t < 64; t += 4) {
    float acc = 0.f;
    #pragma unroll 8
    for (int j = 0; j < T; ++j)
      acc += plds[t * (T + 1) + j] * vm[j * 65 + lane];
    yb[t] = acc;
  }
}

// ---------------------------------------------------------------------------
// dst[r][t] = a[r][t (stride aStride)] + bsrc[r][t]; grid covers B*512*64.
// ---------------------------------------------------------------------------
__global__ __launch_bounds__(256) void add_slice_kernel(
    float* __restrict__ dst, const float* __restrict__ a, int aStride,
    const float* __restrict__ bsrc)
{
  size_t gid = (size_t)blockIdx.x * 256 + threadIdx.x;
  size_t r = gid >> 6;
  int t = (int)(gid & 63);
  dst[gid] = a[r * aStride + t] + bsrc[gid];
}

// ---------------------------------------------------------------------------
// 3x3 SAME conv on 8x8, lrelu applied to input. Block = (b, 64-oc tile).
// LDS: 16-channel input chunk + weights for the chunk. acc[16] per thread.
// Optional residual added in the epilogue.
// ---------------------------------------------------------------------------
__global__ __launch_bounds__(256) void conv3x3_kernel(
    const float* __restrict__ x,    // (B, CIN, 64)
    const float* __restrict__ w,    // (COUT, CIN, 9)
    const float* __restrict__ bias, // (COUT)
    const float* __restrict__ res,  // residual (B, COUT, 64) or nullptr
    float* __restrict__ out,        // (B, COUT, 64)
    int CIN, int COUT)
{
  const int nt = COUT >> 6;
  const int b = blockIdx.x / nt;
  const int ot = blockIdx.x - b * nt;
  const int tid = threadIdx.x;
  const int p = tid & 63;
  const int wg = tid >> 6;
  const int i0 = p >> 3, j0 = p & 7;

  __shared__ float xs[16 * 64];
  __shared__ float wl[64 * 16 * 9];

  float acc[16];
  #pragma unroll
  for (int i = 0; i < 16; ++i) acc[i] = bias[ot * 64 + wg * 16 + i];

  for (int c0 = 0; c0 < CIN; c0 += 16) {
    for (int idx = tid; idx < 1024; idx += 256) {
      int c = idx >> 6, pp = idx & 63;
      xs[idx] = lrelu(x[((size_t)b * CIN + c0 + c) * 64 + pp]);
    }
    for (int idx = tid; idx < 9216; idx += 256) {
      int o = idx / 144, rem = idx - o * 144;
      wl[idx] = w[((size_t)(ot * 64 + o) * CIN + c0) * 9 + rem];
    }
    __syncthreads();
    #pragma unroll
    for (int k = 0; k < 9; ++k) {
      const int dy = k / 3 - 1, dx = k - (k / 3) * 3 - 1;
      const int ii = i0 + dy, jj = j0 + dx;
      const bool valid = ((unsigned)ii < 8u) && ((unsigned)jj < 8u);
      const int np = ii * 8 + jj;
      #pragma unroll 4
      for (int c = 0; c < 16; ++c) {
        float xv = valid ? xs[c * 64 + np] : 0.f;
        const float* wp = &wl[(wg * 16) * 144 + c * 9 + k];
        #pragma unroll
        for (int i = 0; i < 16; ++i)
          acc[i] += xv * wp[i * 144];
      }
    }
    __syncthreads();
  }
  #pragma unroll
  for (int i = 0; i < 16; ++i) {
    int o = ot * 64 + wg * 16 + i;
    size_t idx = ((size_t)b * COUT + o) * 64 + p;
    float v = acc[i];
    if (res) v += res[idx];
    out[idx] = v;
  }
}

// ---------------------------------------------------------------------------
// RMS over the 64 spatial positions per (b, channel) row, in place.
// ---------------------------------------------------------------------------
__global__ __launch_bounds__(256) void rms_spatial_kernel(
    float* __restrict__ y, const float* __restrict__ nw, int nrows)
{
  int gid = blockIdx.x * 256 + threadIdx.x;
  if (gid >= nrows) return;
  float* row = y + (size_t)gid * 64;
  float ss = 0.f;
  #pragma unroll 8
  for (int p = 0; p < 64; ++p) { float v = row[p]; ss += v * v; }
  float sc = nw[0] * rsqrtf(ss * (1.f / 64.f) + 1e-6f);
  #pragma unroll 8
  for (int p = 0; p < 64; ++p) row[p] *= sc;
}

// ---------------------------------------------------------------------------
// Final VALID 8x8 conv: out[b] = sum_{c,p} lrelu(F1[b,c,p]) * w[c,p] + bias.
// ---------------------------------------------------------------------------
__global__ __launch_bounds__(256) void co2_kernel(
    const float* __restrict__ xf,  // (B, 1024, 64)
    const float* __restrict__ w,   // (1024*64)
    const float* __restrict__ cb,  // scalar
    float* __restrict__ out)
{
  const int b = blockIdx.x, tid = threadIdx.x;
  const float* xb = xf + (size_t)b * 65536;
  float acc = 0.f;
  for (int i = tid; i < 65536; i += 256)
    acc += lrelu(xb[i]) * w[i];
  #pragma unroll
  for (int off = 32; off; off >>= 1) acc += __shfl_down(acc, off);
  __shared__ float red[4];
  if ((tid & 63) == 0) red[tid >> 6] = acc;
  __syncthreads();
  if (tid == 0) out[b] = red[0] + red[1] + red[2] + red[3] + cb[0];
}

// ---------------------------------------------------------------------------
extern "C" void kernel_launch(void* const* d_in, const int* in_sizes, int n_in,
                              void* d_out, int out_size, void* d_ws, size_t ws_size,
                              hipStream_t stream)
{
  const int*   fen        = (const int*)d_in[0];
  const int*   move       = (const int*)d_in[1];
  const float* rank_emb   = (const float*)d_in[2];
  const float* file_emb   = (const float*)d_in[3];
  const float* fen_emb    = (const float*)d_in[4];
  const float* move_emb   = (const float*)d_in[5];
  const float* abs_emb    = (const float*)d_in[6];
  const float* ln_w       = (const float*)d_in[7];
  const float* ln_b       = (const float*)d_in[8];
  const float* emb_qkv    = (const float*)d_in[9];
  const float* emb_norm_w = (const float*)d_in[10];
  const float* qkv        = (const float*)d_in[11];
  const float* mha_norm_w = (const float*)d_in[12];
  const float* conv1_w    = (const float*)d_in[13];
  const float* conv1_b    = (const float*)d_in[14];
  const float* conv2_w    = (const float*)d_in[15];
  const float* conv2_b    = (const float*)d_in[16];
  const float* cb_norm_w  = (const float*)d_in[17];
  const float* out_norm_w = (const float*)d_in[18];
  const float* co1_w      = (const float*)d_in[19];
  const float* co1_b      = (const float*)d_in[20];
  const float* co2_w      = (const float*)d_in[21];
  const float* co2_b      = (const float*)d_in[22];
  float* out = (float*)d_out;

  float* ws  = (float*)d_ws;
  float* X71 = ws;                               // 256*512*71 = 9,306,112
  float* X64 = X71 + (size_t)256 * 512 * 71;     // 256*512*64 = 8,388,608
  float* T1  = X64 + (size_t)256 * 512 * 64;     // 16,777,216 (layer tmp / co1 out)
  float* F1  = T1;

  // embeddings + layernorm
  build_ln_kernel<<<512, 256, 0, stream>>>(fen, move, rank_emb, file_emb,
                                           fen_emb, move_emb, abs_emb,
                                           ln_w, ln_b, X71);
  // embedding MHA (T=71), then x = x[:, :, :64] + y[:, :, :64]
  mha_kernel<71><<<2048, 256, 0, stream>>>(X71, emb_qkv, emb_norm_w, T1);
  add_slice_kernel<<<32768, 256, 0, stream>>>(X64, X71, 71, T1);

  for (int l = 0; l < 8; ++l) {
    const float* w1 = conv1_w + (size_t)l * 512 * 512 * 9;
    const float* w2 = conv2_w + (size_t)l * 512 * 512 * 9;
    // conv block: conv1 -> rms(spatial) -> conv2 (+residual into X64)
    conv3x3_kernel<<<2048, 256, 0, stream>>>(X64, w1, conv1_b + l * 512,
                                             nullptr, T1, 512, 512);
    rms_spatial_kernel<<<512, 256, 0, stream>>>(T1, cb_norm_w + l, 256 * 512);
    conv3x3_kernel<<<2048, 256, 0, stream>>>(T1, w2, conv2_b + l * 512,
                                             X64, X64, 512, 512);
    // MHA + residual
    mha_kernel<64><<<2048, 256, 0, stream>>>(X64, qkv + (size_t)l * 3 * 8 * 512 * 64,
                                             mha_norm_w + l, T1);
    add_slice_kernel<<<32768, 256, 0, stream>>>(X64, X64, 64, T1);
  }

  // head: co1 (512->1024 SAME) -> rms(spatial) -> co2 (VALID 8x8 -> scalar)
  conv3x3_kernel<<<4096, 256, 0, stream>>>(X64, co1_w, co1_b, nullptr, F1, 512, 1024);
  rms_spatial_kernel<<<1024, 256, 0, stream>>>(F1, out_norm_w, 256 * 1024);
  co2_kernel<<<256, 256, 0, stream>>>(F1, co2_w, co2_b, out);
}

// Round 5
// 46257.968 us; speedup vs baseline: 1.4927x; 1.4814x over previous
//
#include <hip/hip_runtime.h>
#include <hip/hip_bf16.h>
#include <cstdint>
#include <cstddef>

// Net: B=256, D=512, L=8, H=8, T=71->64, DH=64.
// Round 4: MHA rewritten as bf16-MFMA QKV projection + fused RMS/attn kernel.
// Convs remain f32 VALU (next round: port the validated MFMA pattern).
// ws layout (bytes):
//   X71  bf16  256*512*71          = 18,612,224
//   X64  f32   256*512*64          = 33,554,432
//   T1   f32   256*1024*64         = 67,108,864  (conv tmp; aliased by qkv_ws bf16 55.8MB)
//   Wq   bf16  9*1536*512          = 14,155,776
//   total 133.4 MB (<= 138 MB proven available in round 0)

typedef float f32x4 __attribute__((ext_vector_type(4)));
typedef short short8 __attribute__((ext_vector_type(8)));

__device__ __forceinline__ float lrelu(float v) { return v > 0.f ? v : 0.2f * v; }
__device__ __forceinline__ __hip_bfloat16 tobf(float v) { return __float2bfloat16(v); }
__device__ __forceinline__ float frombf(__hip_bfloat16 v) { return __bfloat162float(v); }

// ---------------------------------------------------------------------------
// One-time weight repack: emb_qkv (3,8,512,64) + qkv (8,3,8,512,64) f32
//   -> Wq[L=0..8][j = n*512 + h*64 + dh][d] bf16  (d contiguous)
// ---------------------------------------------------------------------------
__global__ __launch_bounds__(256) void repack_qkv_w(
    const float* __restrict__ emb_qkv, const float* __restrict__ qkvw,
    __hip_bfloat16* __restrict__ Wq)
{
  int o = blockIdx.x * 256 + threadIdx.x;        // < 9*1536*512
  int L = o / (1536 * 512);
  int rem = o - L * 1536 * 512;
  int j = rem >> 9;
  int d = rem & 511;
  int n = j >> 9, h = (j >> 6) & 7, dh = j & 63;
  float v;
  if (L == 0) v = emb_qkv[(((n * 8 + h) * 512 + d) << 6) + dh];
  else        v = qkvw[((((size_t)(L - 1) * 3 + n) * 8 + h) * 512 + d) * 64 + dh];
  Wq[o] = tobf(v);
}

// ---------------------------------------------------------------------------
// Stage 1: embeddings + LayerNorm over T=71 -> X71 bf16 (B,512,71)
// ---------------------------------------------------------------------------
__global__ __launch_bounds__(256) void build_ln_kernel(
    const int* __restrict__ fen, const int* __restrict__ move,
    const float* __restrict__ rank_emb, const float* __restrict__ file_emb,
    const float* __restrict__ fen_emb, const float* __restrict__ move_emb,
    const float* __restrict__ abs_emb, const float* __restrict__ lnw,
    const float* __restrict__ lnb, __hip_bfloat16* __restrict__ X71)
{
  const int gid = blockIdx.x * 256 + threadIdx.x;   // < 256*512
  const int b = gid >> 9, d = gid & 511;
  const int* fb = fen + b * 133;

  float sum = 0.f, sq = 0.f, mu = 0.f, rstd = 0.f;
  #pragma unroll 1
  for (int pass = 0; pass < 2; ++pass) {
    if (pass) {
      mu = sum * (1.f / 71.f);
      float var = sq * (1.f / 71.f) - mu * mu;
      rstd = rsqrtf(var + 1e-5f);
    }
    #pragma unroll 1
    for (int t = 0; t < 71; ++t) {
      float a = abs_emb[t * 512 + d];
      float v;
      if (t < 64) {
        float pos = rank_emb[(t >> 3) * 512 + d] + file_emb[(t & 7) * 512 + d];
        v = 0.5f * (fen_emb[fb[t] * 512 + d] + fen_emb[fb[64 + t] * 512 + d] + pos) + a;
      } else if (t < 69) {
        v = fen_emb[fb[t + 64] * 512 + d] + a;
      } else {
        int j = t - 69;
        int s = move[b * 2 + j];
        float pos = rank_emb[(s >> 3) * 512 + d] + file_emb[(s & 7) * 512 + d];
        v = (pos + move_emb[j * 512 + d]) * 0.58f + a;
      }
      if (pass) X71[(size_t)gid * 71 + t] = tobf((v - mu) * rstd * lnw[t] + lnb[t]);
      else { sum += v; sq += v * v; }
    }
  }
}

// ---------------------------------------------------------------------------
// QKV projection GEMM (bf16 MFMA 16x16x32):
//   out[(b,t)][j] = sum_d lrelu(x[b,d,t]) * Wq[j][d],  j in [jb, jb+256)
// Block: 4 waves, wave = TP x 64 tile (MI x 4 fragments). K chunked by 64.
// LDS rows padded to 72 bf16 (144B) -> bank-staggered b128 reads/b16 writes.
// ---------------------------------------------------------------------------
template <int T, int TP, bool INBF>
__global__ __launch_bounds__(256) void proj_kernel(
    const void* __restrict__ xin, const __hip_bfloat16* __restrict__ Wq,
    __hip_bfloat16* __restrict__ qw)
{
  const int b  = blockIdx.x / 6;
  const int jb = (blockIdx.x % 6) * 256;
  const int tid = threadIdx.x;
  const int lane = tid & 63, wv = tid >> 6;
  const int lr = lane & 15, lg = lane >> 4;

  __shared__ __hip_bfloat16 xt[TP * 72];
  __shared__ __hip_bfloat16 wl[256 * 72];

  constexpr int MI = TP / 16;
  f32x4 acc[MI][4];
  #pragma unroll
  for (int mi = 0; mi < MI; ++mi)
    #pragma unroll
    for (int ni = 0; ni < 4; ++ni) acc[mi][ni] = {0.f, 0.f, 0.f, 0.f};

  for (int c0 = 0; c0 < 512; c0 += 64) {
    // stage activations (lrelu + transpose to [t][c], bf16)
    if constexpr (INBF) {
      const __hip_bfloat16* x = (const __hip_bfloat16*)xin;
      for (int i = tid; i < 64 * TP; i += 256) {
        int d = i / TP, t = i - d * TP;
        float v = (t < T) ? lrelu(frombf(x[((size_t)(b * 512 + c0 + d)) * T + t])) : 0.f;
        xt[t * 72 + d] = tobf(v);
      }
    } else {
      const float* x = (const float*)xin;
      for (int i = tid; i < 64 * TP; i += 256) {
        int d = i >> 6, t = i & 63;
        float v = lrelu(x[((size_t)(b * 512 + c0 + d)) * 64 + t]);
        xt[t * 72 + d] = tobf(v);
      }
    }
    // stage weights: wl[j][c] <- Wq[jb+j][c0+c], 16B vector copies
    for (int i = tid; i < 2048; i += 256) {
      int j = i >> 3, cb = i & 7;
      *(uint4*)&wl[j * 72 + cb * 8] =
          *(const uint4*)&Wq[(size_t)(jb + j) * 512 + c0 + cb * 8];
    }
    __syncthreads();
    #pragma unroll
    for (int ks = 0; ks < 2; ++ks) {
      short8 a[MI], bb[4];
      #pragma unroll
      for (int mi = 0; mi < MI; ++mi)
        a[mi] = *(const short8*)&xt[(mi * 16 + lr) * 72 + ks * 32 + lg * 8];
      #pragma unroll
      for (int ni = 0; ni < 4; ++ni)
        bb[ni] = *(const short8*)&wl[(wv * 64 + ni * 16 + lr) * 72 + ks * 32 + lg * 8];
      #pragma unroll
      for (int mi = 0; mi < MI; ++mi)
        #pragma unroll
        for (int ni = 0; ni < 4; ++ni)
          acc[mi][ni] = __builtin_amdgcn_mfma_f32_16x16x32_bf16(
              a[mi], bb[ni], acc[mi][ni], 0, 0, 0);
    }
    __syncthreads();
  }
  // epilogue: D col = lane&15 (j), row = (lane>>4)*4 + r (t)  [m89 layout]
  #pragma unroll
  for (int mi = 0; mi < MI; ++mi) {
    #pragma unroll
    for (int ni = 0; ni < 4; ++ni) {
      int j = jb + wv * 64 + ni * 16 + lr;
      #pragma unroll
      for (int r = 0; r < 4; ++r) {
        int t = mi * 16 + lg * 4 + r;
        if (TP == T || t < T)
          qw[((size_t)b * T + t) * 1536 + j] = tobf(acc[mi][ni][r]);
      }
    }
  }
}

// ---------------------------------------------------------------------------
// Fused RMS(token axis) + softmax + PV + residual, per (b,h) block.
// qw: [b][t][j=n*512+h*64+dh] bf16. out[b][h*64+dh][t] = res + P·V.
// ---------------------------------------------------------------------------
template <int T, bool RESBF>
__global__ __launch_bounds__(256) void attn_kernel(
    const __hip_bfloat16* __restrict__ qw, const float* __restrict__ nw,
    const void* __restrict__ res, float* __restrict__ out)
{
  constexpr int PL = (T & 1) ? T : T + 1;   // odd stride -> conflict-free row reads
  const int b = blockIdx.x >> 3, h = blockIdx.x & 7;
  const int tid = threadIdx.x, lane = tid & 63, wv = tid >> 6;

  __shared__ float smx[3 * T * 65];
  __shared__ float scl[192];
  __shared__ float plds[64 * PL];

  for (int i = tid; i < 3 * T * 64; i += 256) {
    int n = i / (T * 64), rem = i - n * (T * 64);
    int t = rem >> 6, dh = rem & 63;
    smx[n * T * 65 + t * 65 + dh] =
        frombf(qw[((size_t)b * T + t) * 1536 + n * 512 + (h << 6) + dh]);
  }
  __syncthreads();
  if (tid < 192) {
    int n = tid >> 6, dh = tid & 63;
    float ss = 0.f;
    for (int t = 0; t < T; ++t) { float v = smx[n * T * 65 + t * 65 + dh]; ss += v * v; }
    scl[tid] = nw[0] * rsqrtf(ss * (1.f / T) + 1e-6f);
  }
  __syncthreads();
  for (int i = tid; i < 3 * T * 64; i += 256) {
    int n = i / (T * 64), rem = i - n * (T * 64);
    int t = rem >> 6, dh = rem & 63;
    smx[n * T * 65 + t * 65 + dh] *= scl[(n << 6) + dh];
  }
  __syncthreads();

  const float* qm = smx;
  const float* km = smx + T * 65;
  const float* vm = smx + 2 * T * 65;

  for (int t = wv; t < 64; t += 4) {
    float s0 = 0.f, s1 = 0.f;
    #pragma unroll 8
    for (int dh = 0; dh < 64; ++dh) s0 += qm[t * 65 + dh] * km[lane * 65 + dh];
    bool has1 = false;
    if constexpr (T > 64) {
      has1 = (lane + 64 < T);
      if (has1) {
        #pragma unroll 8
        for (int dh = 0; dh < 64; ++dh) s1 += qm[t * 65 + dh] * km[(lane + 64) * 65 + dh];
      }
    }
    s0 *= 0.125f; s1 *= 0.125f;
    float mx = has1 ? fmaxf(s0, s1) : s0;
    #pragma unroll
    for (int off = 32; off; off >>= 1) mx = fmaxf(mx, __shfl_xor(mx, off));
    float e0 = __expf(s0 - mx);
    float e1 = has1 ? __expf(s1 - mx) : 0.f;
    float sm = e0 + e1;
    #pragma unroll
    for (int off = 32; off; off >>= 1) sm += __shfl_xor(sm, off);
    float inv = 1.f / sm;
    plds[t * PL + lane] = e0 * inv;
    if constexpr (T > 64) {
      if (lane < T - 64) plds[t * PL + 64 + lane] = e1 * inv;
    }
  }
  __syncthreads();

  // PV: lane = query row t; vm reads are lane-uniform broadcasts.
  for (int dh = wv; dh < 64; dh += 4) {
    float acc = 0.f;
    #pragma unroll 8
    for (int j = 0; j < T; ++j) acc += plds[lane * PL + j] * vm[j * 65 + dh];
    size_t oidx = ((size_t)(b * 512 + (h << 6) + dh)) * 64 + lane;
    float rv;
    if constexpr (RESBF)
      rv = frombf(((const __hip_bfloat16*)res)[((size_t)(b * 512 + (h << 6) + dh)) * T + lane]);
    else
      rv = ((const float*)res)[oidx];
    out[oidx] = rv + acc;
  }
}

// ---------------------------------------------------------------------------
// 3x3 SAME conv on 8x8 (unchanged from round 0)
// ---------------------------------------------------------------------------
__global__ __launch_bounds__(256) void conv3x3_kernel(
    const float* __restrict__ x, const float* __restrict__ w,
    const float* __restrict__ bias, const float* __restrict__ res,
    float* __restrict__ out, int CIN, int COUT)
{
  const int nt = COUT >> 6;
  const int b = blockIdx.x / nt;
  const int ot = blockIdx.x - b * nt;
  const int tid = threadIdx.x;
  const int p = tid & 63;
  const int wg = tid >> 6;
  const int i0 = p >> 3, j0 = p & 7;

  __shared__ float xs[16 * 64];
  __shared__ float wl[64 * 16 * 9];

  float acc[16];
  #pragma unroll
  for (int i = 0; i < 16; ++i) acc[i] = bias[ot * 64 + wg * 16 + i];

  for (int c0 = 0; c0 < CIN; c0 += 16) {
    for (int idx = tid; idx < 1024; idx += 256) {
      int c = idx >> 6, pp = idx & 63;
      xs[idx] = lrelu(x[((size_t)b * CIN + c0 + c) * 64 + pp]);
    }
    for (int idx = tid; idx < 9216; idx += 256) {
      int o = idx / 144, rem = idx - o * 144;
      wl[idx] = w[((size_t)(ot * 64 + o) * CIN + c0) * 9 + rem];
    }
    __syncthreads();
    #pragma unroll
    for (int k = 0; k < 9; ++k) {
      const int dy = k / 3 - 1, dx = k - (k / 3) * 3 - 1;
      const int ii = i0 + dy, jj = j0 + dx;
      const bool valid = ((unsigned)ii < 8u) && ((unsigned)jj < 8u);
      const int np = ii * 8 + jj;
      #pragma unroll 4
      for (int c = 0; c < 16; ++c) {
        float xv = valid ? xs[c * 64 + np] : 0.f;
        const float* wp = &wl[(wg * 16) * 144 + c * 9 + k];
        #pragma unroll
        for (int i = 0; i < 16; ++i)
          acc[i] += xv * wp[i * 144];
      }
    }
    __syncthreads();
  }
  #pragma unroll
  for (int i = 0; i < 16; ++i) {
    int o = ot * 64 + wg * 16 + i;
    size_t idx = ((size_t)b * COUT + o) * 64 + p;
    float v = acc[i];
    if (res) v += res[idx];
    out[idx] = v;
  }
}

// ---------------------------------------------------------------------------
__global__ __launch_bounds__(256) void rms_spatial_kernel(
    float* __restrict__ y, const float* __restrict__ nw, int nrows)
{
  int gid = blockIdx.x * 256 + threadIdx.x;
  if (gid >= nrows) return;
  float* row = y + (size_t)gid * 64;
  float ss = 0.f;
  #pragma unroll 8
  for (int p = 0; p < 64; ++p) { float v = row[p]; ss += v * v; }
  float sc = nw[0] * rsqrtf(ss * (1.f / 64.f) + 1e-6f);
  #pragma unroll 8
  for (int p = 0; p < 64; ++p) row[p] *= sc;
}

// ---------------------------------------------------------------------------
__global__ __launch_bounds__(256) void co2_kernel(
    const float* __restrict__ xf, const float* __restrict__ w,
    const float* __restrict__ cb, float* __restrict__ out)
{
  const int b = blockIdx.x, tid = threadIdx.x;
  const float* xb = xf + (size_t)b * 65536;
  float acc = 0.f;
  for (int i = tid; i < 65536; i += 256)
    acc += lrelu(xb[i]) * w[i];
  #pragma unroll
  for (int off = 32; off; off >>= 1) acc += __shfl_down(acc, off);
  __shared__ float red[4];
  if ((tid & 63) == 0) red[tid >> 6] = acc;
  __syncthreads();
  if (tid == 0) out[b] = red[0] + red[1] + red[2] + red[3] + cb[0];
}

// ---------------------------------------------------------------------------
extern "C" void kernel_launch(void* const* d_in, const int* in_sizes, int n_in,
                              void* d_out, int out_size, void* d_ws, size_t ws_size,
                              hipStream_t stream)
{
  const int*   fen        = (const int*)d_in[0];
  const int*   move       = (const int*)d_in[1];
  const float* rank_emb   = (const float*)d_in[2];
  const float* file_emb   = (const float*)d_in[3];
  const float* fen_emb    = (const float*)d_in[4];
  const float* move_emb   = (const float*)d_in[5];
  const float* abs_emb    = (const float*)d_in[6];
  const float* ln_w       = (const float*)d_in[7];
  const float* ln_b       = (const float*)d_in[8];
  const float* emb_qkv    = (const float*)d_in[9];
  const float* emb_norm_w = (const float*)d_in[10];
  const float* qkvw_in    = (const float*)d_in[11];
  const float* mha_norm_w = (const float*)d_in[12];
  const float* conv1_w    = (const float*)d_in[13];
  const float* conv1_b    = (const float*)d_in[14];
  const float* conv2_w    = (const float*)d_in[15];
  const float* conv2_b    = (const float*)d_in[16];
  const float* cb_norm_w  = (const float*)d_in[17];
  const float* out_norm_w = (const float*)d_in[18];
  const float* co1_w      = (const float*)d_in[19];
  const float* co1_b      = (const float*)d_in[20];
  const float* co2_w      = (const float*)d_in[21];
  const float* co2_b      = (const float*)d_in[22];
  float* out = (float*)d_out;

  char* base = (char*)d_ws;
  __hip_bfloat16* X71 = (__hip_bfloat16*)base;                       // 18,612,224 B
  float* X64 = (float*)(base + 18612224);                            // 33,554,432 B
  float* T1  = (float*)(base + 18612224 + 33554432);                 // 67,108,864 B
  __hip_bfloat16* Wq = (__hip_bfloat16*)(base + 18612224 + 33554432 + 67108864);
  __hip_bfloat16* qkvws = (__hip_bfloat16*)T1;   // 55.8 MB <= 67.1 MB, T1 dead then
  float* F1 = T1;

  // one-time QKV weight repack (9 layers)
  repack_qkv_w<<<27648, 256, 0, stream>>>(emb_qkv, qkvw_in, Wq);

  // embeddings + layernorm -> X71 (bf16)
  build_ln_kernel<<<512, 256, 0, stream>>>(fen, move, rank_emb, file_emb,
                                           fen_emb, move_emb, abs_emb,
                                           ln_w, ln_b, X71);
  // embedding MHA (T=71): proj -> attn (residual = X71[:, :, :64]) -> X64
  proj_kernel<71, 80, true><<<1536, 256, 0, stream>>>(X71, Wq, qkvws);
  attn_kernel<71, true><<<2048, 256, 0, stream>>>(qkvws, emb_norm_w, X71, X64);

  for (int l = 0; l < 8; ++l) {
    const float* w1 = conv1_w + (size_t)l * 512 * 512 * 9;
    const float* w2 = conv2_w + (size_t)l * 512 * 512 * 9;
    conv3x3_kernel<<<2048, 256, 0, stream>>>(X64, w1, conv1_b + l * 512,
                                             nullptr, T1, 512, 512);
    rms_spatial_kernel<<<512, 256, 0, stream>>>(T1, cb_norm_w + l, 256 * 512);
    conv3x3_kernel<<<2048, 256, 0, stream>>>(T1, w2, conv2_b + l * 512,
                                             X64, X64, 512, 512);
    // MHA (T=64), residual folded into attn epilogue
    proj_kernel<64, 64, false><<<1536, 256, 0, stream>>>(
        X64, Wq + (size_t)(l + 1) * 1536 * 512, qkvws);
    attn_kernel<64, false><<<2048, 256, 0, stream>>>(qkvws, mha_norm_w + l, X64, X64);
  }

  // head: co1 (512->1024 SAME) -> rms(spatial) -> co2 (VALID 8x8 -> scalar)
  conv3x3_kernel<<<4096, 256, 0, stream>>>(X64, co1_w, co1_b, nullptr, F1, 512, 1024);
  rms_spatial_kernel<<<1024, 256, 0, stream>>>(F1, out_norm_w, 256 * 1024);
  co2_kernel<<<256, 256, 0, stream>>>(F1, co2_w, co2_b, out);
}

// Round 6
// 7465.625 us; speedup vs baseline: 9.2487x; 6.1961x over previous
//
#include <hip/hip_runtime.h>
#include <hip/hip_bf16.h>
#include <cstdint>
#include <cstddef>

// Net: B=256, D=512, L=8, H=8, T=71->64, DH=64.
// Round 6: convs ported to bf16 MFMA (16x16x32), RMS + residual fused into
// conv epilogues. MHA = round-5 proj/attn (validated). Everything heavy on MFMA.
// ws layout (bytes), total 133,431,296 (same as validated round 5):
//   X71  bf16 @ 0          18,612,224   (embeds; region reused as WcA/WcB after)
//   X64  f32  @ 18,612,224 33,554,432   (residual stream)
//   T1   f32  @ 52,166,656 67,108,864   (conv tmp 33.5MB / qkvws bf16 55.8MB / F1 67MB)
//   Wq   bf16 @119,275,520 14,155,776   (repacked QKV weights, 9 layers)

typedef float f32x4 __attribute__((ext_vector_type(4)));
typedef short short8 __attribute__((ext_vector_type(8)));

__device__ __forceinline__ float lrelu(float v) { return v > 0.f ? v : 0.2f * v; }
__device__ __forceinline__ __hip_bfloat16 tobf(float v) { return __float2bfloat16(v); }
__device__ __forceinline__ float frombf(__hip_bfloat16 v) { return __bfloat162float(v); }

// ---------------------------------------------------------------------------
// One-time QKV weight repack: emb_qkv (3,8,512,64) + qkv (8,3,8,512,64) f32
//   -> Wq[L=0..8][j = n*512 + h*64 + dh][d] bf16  (d contiguous)
// ---------------------------------------------------------------------------
__global__ __launch_bounds__(256) void repack_qkv_w(
    const float* __restrict__ emb_qkv, const float* __restrict__ qkvw,
    __hip_bfloat16* __restrict__ Wq)
{
  int o = blockIdx.x * 256 + threadIdx.x;        // < 9*1536*512
  int L = o / (1536 * 512);
  int rem = o - L * 1536 * 512;
  int j = rem >> 9;
  int d = rem & 511;
  int n = j >> 9, h = (j >> 6) & 7, dh = j & 63;
  float v;
  if (L == 0) v = emb_qkv[(((n * 8 + h) * 512 + d) << 6) + dh];
  else        v = qkvw[((((size_t)(L - 1) * 3 + n) * 8 + h) * 512 + d) * 64 + dh];
  Wq[o] = tobf(v);
}

// ---------------------------------------------------------------------------
// Per-layer conv weight repack: w (COUT,512,3,3) f32 -> Wc[o][cc][k][c'] bf16
// K-global order = cc*576 + k*64 + c'  (matches conv_mfma's A enumeration).
// ---------------------------------------------------------------------------
__global__ __launch_bounds__(256) void repack_conv_w(
    const float* __restrict__ w, __hip_bfloat16* __restrict__ Wc, int total)
{
  int i = blockIdx.x * 256 + threadIdx.x;
  if (i >= total) return;
  int o = i / 4608;
  int rem = i - o * 4608;
  int cc = rem / 576;
  int r2 = rem - cc * 576;
  int k = r2 >> 6, cp = r2 & 63;
  Wc[i] = tobf(w[((size_t)o * 512 + cc * 64 + cp) * 9 + k]);
}

// ---------------------------------------------------------------------------
// Stage 1: embeddings + LayerNorm over T=71 -> X71 bf16 (B,512,71)
// ---------------------------------------------------------------------------
__global__ __launch_bounds__(256) void build_ln_kernel(
    const int* __restrict__ fen, const int* __restrict__ move,
    const float* __restrict__ rank_emb, const float* __restrict__ file_emb,
    const float* __restrict__ fen_emb, const float* __restrict__ move_emb,
    const float* __restrict__ abs_emb, const float* __restrict__ lnw,
    const float* __restrict__ lnb, __hip_bfloat16* __restrict__ X71)
{
  const int gid = blockIdx.x * 256 + threadIdx.x;   // < 256*512
  const int b = gid >> 9, d = gid & 511;
  const int* fb = fen + b * 133;

  float sum = 0.f, sq = 0.f, mu = 0.f, rstd = 0.f;
  #pragma unroll 1
  for (int pass = 0; pass < 2; ++pass) {
    if (pass) {
      mu = sum * (1.f / 71.f);
      float var = sq * (1.f / 71.f) - mu * mu;
      rstd = rsqrtf(var + 1e-5f);
    }
    #pragma unroll 1
    for (int t = 0; t < 71; ++t) {
      float a = abs_emb[t * 512 + d];
      float v;
      if (t < 64) {
        float pos = rank_emb[(t >> 3) * 512 + d] + file_emb[(t & 7) * 512 + d];
        v = 0.5f * (fen_emb[fb[t] * 512 + d] + fen_emb[fb[64 + t] * 512 + d] + pos) + a;
      } else if (t < 69) {
        v = fen_emb[fb[t + 64] * 512 + d] + a;
      } else {
        int j = t - 69;
        int s = move[b * 2 + j];
        float pos = rank_emb[(s >> 3) * 512 + d] + file_emb[(s & 7) * 512 + d];
        v = (pos + move_emb[j * 512 + d]) * 0.58f + a;
      }
      if (pass) X71[(size_t)gid * 71 + t] = tobf((v - mu) * rstd * lnw[t] + lnb[t]);
      else { sum += v; sq += v * v; }
    }
  }
}

// ---------------------------------------------------------------------------
// QKV projection GEMM (bf16 MFMA 16x16x32) — validated round 5.
// ---------------------------------------------------------------------------
template <int T, int TP, bool INBF>
__global__ __launch_bounds__(256) void proj_kernel(
    const void* __restrict__ xin, const __hip_bfloat16* __restrict__ Wq,
    __hip_bfloat16* __restrict__ qw)
{
  const int b  = blockIdx.x / 6;
  const int jb = (blockIdx.x % 6) * 256;
  const int tid = threadIdx.x;
  const int lane = tid & 63, wv = tid >> 6;
  const int lr = lane & 15, lg = lane >> 4;

  __shared__ __hip_bfloat16 xt[TP * 72];
  __shared__ __hip_bfloat16 wl[256 * 72];

  constexpr int MI = TP / 16;
  f32x4 acc[MI][4];
  #pragma unroll
  for (int mi = 0; mi < MI; ++mi)
    #pragma unroll
    for (int ni = 0; ni < 4; ++ni) acc[mi][ni] = {0.f, 0.f, 0.f, 0.f};

  for (int c0 = 0; c0 < 512; c0 += 64) {
    if constexpr (INBF) {
      const __hip_bfloat16* x = (const __hip_bfloat16*)xin;
      for (int i = tid; i < 64 * TP; i += 256) {
        int d = i / TP, t = i - d * TP;
        float v = (t < T) ? lrelu(frombf(x[((size_t)(b * 512 + c0 + d)) * T + t])) : 0.f;
        xt[t * 72 + d] = tobf(v);
      }
    } else {
      const float* x = (const float*)xin;
      for (int i = tid; i < 64 * TP; i += 256) {
        int d = i >> 6, t = i & 63;
        float v = lrelu(x[((size_t)(b * 512 + c0 + d)) * 64 + t]);
        xt[t * 72 + d] = tobf(v);
      }
    }
    for (int i = tid; i < 2048; i += 256) {
      int j = i >> 3, cb = i & 7;
      *(uint4*)&wl[j * 72 + cb * 8] =
          *(const uint4*)&Wq[(size_t)(jb + j) * 512 + c0 + cb * 8];
    }
    __syncthreads();
    #pragma unroll
    for (int ks = 0; ks < 2; ++ks) {
      short8 a[MI], bb[4];
      #pragma unroll
      for (int mi = 0; mi < MI; ++mi)
        a[mi] = *(const short8*)&xt[(mi * 16 + lr) * 72 + ks * 32 + lg * 8];
      #pragma unroll
      for (int ni = 0; ni < 4; ++ni)
        bb[ni] = *(const short8*)&wl[(wv * 64 + ni * 16 + lr) * 72 + ks * 32 + lg * 8];
      #pragma unroll
      for (int mi = 0; mi < MI; ++mi)
        #pragma unroll
        for (int ni = 0; ni < 4; ++ni)
          acc[mi][ni] = __builtin_amdgcn_mfma_f32_16x16x32_bf16(
              a[mi], bb[ni], acc[mi][ni], 0, 0, 0);
    }
    __syncthreads();
  }
  #pragma unroll
  for (int mi = 0; mi < MI; ++mi) {
    #pragma unroll
    for (int ni = 0; ni < 4; ++ni) {
      int j = jb + wv * 64 + ni * 16 + lr;
      #pragma unroll
      for (int r = 0; r < 4; ++r) {
        int t = mi * 16 + lg * 4 + r;
        if (TP == T || t < T)
          qw[((size_t)b * T + t) * 1536 + j] = tobf(acc[mi][ni][r]);
      }
    }
  }
}

// ---------------------------------------------------------------------------
// Fused RMS(token axis) + softmax + PV + residual — validated round 5.
// ---------------------------------------------------------------------------
template <int T, bool RESBF>
__global__ __launch_bounds__(256) void attn_kernel(
    const __hip_bfloat16* __restrict__ qw, const float* __restrict__ nw,
    const void* __restrict__ res, float* __restrict__ out)
{
  constexpr int PL = (T & 1) ? T : T + 1;
  const int b = blockIdx.x >> 3, h = blockIdx.x & 7;
  const int tid = threadIdx.x, lane = tid & 63, wv = tid >> 6;

  __shared__ float smx[3 * T * 65];
  __shared__ float scl[192];
  __shared__ float plds[64 * PL];

  for (int i = tid; i < 3 * T * 64; i += 256) {
    int n = i / (T * 64), rem = i - n * (T * 64);
    int t = rem >> 6, dh = rem & 63;
    smx[n * T * 65 + t * 65 + dh] =
        frombf(qw[((size_t)b * T + t) * 1536 + n * 512 + (h << 6) + dh]);
  }
  __syncthreads();
  if (tid < 192) {
    int n = tid >> 6, dh = tid & 63;
    float ss = 0.f;
    for (int t = 0; t < T; ++t) { float v = smx[n * T * 65 + t * 65 + dh]; ss += v * v; }
    scl[tid] = nw[0] * rsqrtf(ss * (1.f / T) + 1e-6f);
  }
  __syncthreads();
  for (int i = tid; i < 3 * T * 64; i += 256) {
    int n = i / (T * 64), rem = i - n * (T * 64);
    int t = rem >> 6, dh = rem & 63;
    smx[n * T * 65 + t * 65 + dh] *= scl[(n << 6) + dh];
  }
  __syncthreads();

  const float* qm = smx;
  const float* km = smx + T * 65;
  const float* vm = smx + 2 * T * 65;

  for (int t = wv; t < 64; t += 4) {
    float s0 = 0.f, s1 = 0.f;
    #pragma unroll 8
    for (int dh = 0; dh < 64; ++dh) s0 += qm[t * 65 + dh] * km[lane * 65 + dh];
    bool has1 = false;
    if constexpr (T > 64) {
      has1 = (lane + 64 < T);
      if (has1) {
        #pragma unroll 8
        for (int dh = 0; dh < 64; ++dh) s1 += qm[t * 65 + dh] * km[(lane + 64) * 65 + dh];
      }
    }
    s0 *= 0.125f; s1 *= 0.125f;
    float mx = has1 ? fmaxf(s0, s1) : s0;
    #pragma unroll
    for (int off = 32; off; off >>= 1) mx = fmaxf(mx, __shfl_xor(mx, off));
    float e0 = __expf(s0 - mx);
    float e1 = has1 ? __expf(s1 - mx) : 0.f;
    float sm = e0 + e1;
    #pragma unroll
    for (int off = 32; off; off >>= 1) sm += __shfl_xor(sm, off);
    float inv = 1.f / sm;
    plds[t * PL + lane] = e0 * inv;
    if constexpr (T > 64) {
      if (lane < T - 64) plds[t * PL + 64 + lane] = e1 * inv;
    }
  }
  __syncthreads();

  for (int dh = wv; dh < 64; dh += 4) {
    float acc = 0.f;
    #pragma unroll 8
    for (int j = 0; j < T; ++j) acc += plds[lane * PL + j] * vm[j * 65 + dh];
    size_t oidx = ((size_t)(b * 512 + (h << 6) + dh)) * 64 + lane;
    float rv;
    if constexpr (RESBF)
      rv = frombf(((const __hip_bfloat16*)res)[((size_t)(b * 512 + (h << 6) + dh)) * T + lane]);
    else
      rv = ((const float*)res)[oidx];
    out[oidx] = rv + acc;
  }
}

// ---------------------------------------------------------------------------
// MFMA conv 3x3 SAME on 8x8 board, CIN=512.
//   out[b,o,p] = sum_{c,k} lrelu(x[b,c,p+off(k)]) * w[o,c,k]  (+bias, opt RMS,
//   opt residual). GEMM view: M=64 spatial, N=256-tile of COUT, K=4608.
// A staged per c-chunk in a zero-bordered 10x10 board layout -> SAME padding
// is pure address arithmetic (border rows stay 0). B streamed per (cc,k).
// Fragment pattern identical to proj_kernel (validated).
// RMSOUT: fuse RMS over the 64 spatial positions (scalar weight nw).
// RESADD: add residual f32 in the epilogue.
// ---------------------------------------------------------------------------
template <bool RMSOUT, bool RESADD>
__global__ __launch_bounds__(256) void conv_mfma(
    const float* __restrict__ x,            // (B,512,64) f32
    const __hip_bfloat16* __restrict__ Wc,  // [COUT][cc=8][k=9][c'=64] bf16
    const float* __restrict__ bias,         // (COUT)
    const float* __restrict__ nw,           // scalar rms weight (RMSOUT)
    const float* __restrict__ res,          // (B,COUT,64) f32 (RESADD)
    float* __restrict__ out,                // (B,COUT,64) f32
    int COUT)
{
  const int ntc = COUT >> 8;
  const int b = blockIdx.x / ntc;
  const int nt = blockIdx.x - b * ntc;
  const int o0 = nt << 8;
  const int tid = threadIdx.x;
  const int lane = tid & 63, wv = tid >> 6;
  const int lr = lane & 15, lg = lane >> 4;

  __shared__ __hip_bfloat16 xt[100 * 72];   // 10x10 padded board rows x 64 c'
  __shared__ __hip_bfloat16 wl[256 * 72];   // [o-row][c'] for current (cc,k)

  f32x4 acc[4][4];
  #pragma unroll
  for (int mi = 0; mi < 4; ++mi)
    #pragma unroll
    for (int ni = 0; ni < 4; ++ni) acc[mi][ni] = {0.f, 0.f, 0.f, 0.f};

  for (int i = tid; i < 7200; i += 256) xt[i] = tobf(0.f);
  __syncthreads();

  for (int cc = 0; cc < 8; ++cc) {
    // stage lrelu(x) chunk, transposed to [board-row][c']
    for (int i = tid; i < 4096; i += 256) {
      int ci = i >> 6, p = i & 63;
      float v = lrelu(x[((size_t)b * 512 + cc * 64 + ci) * 64 + p]);
      xt[(((p >> 3) + 1) * 10 + (p & 7) + 1) * 72 + ci] = tobf(v);
    }
    const __hip_bfloat16* Wcc = Wc + (size_t)o0 * 4608 + cc * 576;
    for (int k = 0; k < 9; ++k) {
      for (int i = tid; i < 2048; i += 256) {
        int j = i >> 3, c8 = i & 7;
        *(uint4*)&wl[j * 72 + c8 * 8] =
            *(const uint4*)&Wcc[(size_t)j * 4608 + k * 64 + c8 * 8];
      }
      __syncthreads();
      const int dy = k / 3 - 1, dx = k - (k / 3) * 3 - 1;
      const int ii0 = (lr >> 3) + dy + 1;    // + mi*2 per fragment
      const int jj0 = (lr & 7) + dx + 1;
      #pragma unroll
      for (int ks = 0; ks < 2; ++ks) {
        short8 av[4], bv[4];
        #pragma unroll
        for (int mi = 0; mi < 4; ++mi)
          av[mi] = *(const short8*)&xt[((ii0 + mi * 2) * 10 + jj0) * 72 + ks * 32 + lg * 8];
        #pragma unroll
        for (int ni = 0; ni < 4; ++ni)
          bv[ni] = *(const short8*)&wl[(wv * 64 + ni * 16 + lr) * 72 + ks * 32 + lg * 8];
        #pragma unroll
        for (int mi = 0; mi < 4; ++mi)
          #pragma unroll
          for (int ni = 0; ni < 4; ++ni)
            acc[mi][ni] = __builtin_amdgcn_mfma_f32_16x16x32_bf16(
                av[mi], bv[ni], acc[mi][ni], 0, 0, 0);
      }
      __syncthreads();
    }
  }

  // epilogue: +bias, optional spatial-RMS (all 64 p for column o live on the
  // 4 lanes sharing lr across lg: fold with shfl_xor 16/32), optional residual.
  #pragma unroll
  for (int ni = 0; ni < 4; ++ni) {
    const int o = o0 + wv * 64 + ni * 16 + lr;
    const float bvs = bias[o];
    float sc = 1.f;
    if constexpr (RMSOUT) {
      float ss = 0.f;
      #pragma unroll
      for (int mi = 0; mi < 4; ++mi)
        #pragma unroll
        for (int r = 0; r < 4; ++r) {
          float v = acc[mi][ni][r] + bvs;
          ss += v * v;
        }
      ss += __shfl_xor(ss, 16);
      ss += __shfl_xor(ss, 32);
      sc = nw[0] * rsqrtf(ss * (1.f / 64.f) + 1e-6f);
    }
    #pragma unroll
    for (int mi = 0; mi < 4; ++mi) {
      size_t idx = ((size_t)b * COUT + o) * 64 + mi * 16 + lg * 4;
      f32x4 v;
      #pragma unroll
      for (int r = 0; r < 4; ++r) v[r] = (acc[mi][ni][r] + bvs) * sc;
      if constexpr (RESADD) v += *(const f32x4*)&res[idx];
      *(f32x4*)&out[idx] = v;
    }
  }
}

// ---------------------------------------------------------------------------
// Final VALID 8x8 conv: out[b] = sum_{c,p} lrelu(F1[b,c,p]) * w[c,p] + bias.
// ---------------------------------------------------------------------------
__global__ __launch_bounds__(256) void co2_kernel(
    const float* __restrict__ xf, const float* __restrict__ w,
    const float* __restrict__ cb, float* __restrict__ out)
{
  const int b = blockIdx.x, tid = threadIdx.x;
  const float* xb = xf + (size_t)b * 65536;
  float acc = 0.f;
  for (int i = tid; i < 65536; i += 256)
    acc += lrelu(xb[i]) * w[i];
  #pragma unroll
  for (int off = 32; off; off >>= 1) acc += __shfl_down(acc, off);
  __shared__ float red[4];
  if ((tid & 63) == 0) red[tid >> 6] = acc;
  __syncthreads();
  if (tid == 0) out[b] = red[0] + red[1] + red[2] + red[3] + cb[0];
}

// ---------------------------------------------------------------------------
extern "C" void kernel_launch(void* const* d_in, const int* in_sizes, int n_in,
                              void* d_out, int out_size, void* d_ws, size_t ws_size,
                              hipStream_t stream)
{
  const int*   fen        = (const int*)d_in[0];
  const int*   move       = (const int*)d_in[1];
  const float* rank_emb   = (const float*)d_in[2];
  const float* file_emb   = (const float*)d_in[3];
  const float* fen_emb    = (const float*)d_in[4];
  const float* move_emb   = (const float*)d_in[5];
  const float* abs_emb    = (const float*)d_in[6];
  const float* ln_w       = (const float*)d_in[7];
  const float* ln_b       = (const float*)d_in[8];
  const float* emb_qkv    = (const float*)d_in[9];
  const float* emb_norm_w = (const float*)d_in[10];
  const float* qkvw_in    = (const float*)d_in[11];
  const float* mha_norm_w = (const float*)d_in[12];
  const float* conv1_w    = (const float*)d_in[13];
  const float* conv1_b    = (const float*)d_in[14];
  const float* conv2_w    = (const float*)d_in[15];
  const float* conv2_b    = (const float*)d_in[16];
  const float* cb_norm_w  = (const float*)d_in[17];
  const float* out_norm_w = (const float*)d_in[18];
  const float* co1_w      = (const float*)d_in[19];
  const float* co1_b      = (const float*)d_in[20];
  const float* co2_w      = (const float*)d_in[21];
  const float* co2_b      = (const float*)d_in[22];
  float* out = (float*)d_out;

  char* base = (char*)d_ws;
  __hip_bfloat16* X71 = (__hip_bfloat16*)base;                       // 18,612,224 B
  float* X64 = (float*)(base + 18612224);                            // 33,554,432 B
  float* T1  = (float*)(base + 18612224 + 33554432);                 // 67,108,864 B
  __hip_bfloat16* Wq = (__hip_bfloat16*)(base + 18612224 + 33554432 + 67108864);
  __hip_bfloat16* qkvws = (__hip_bfloat16*)T1;   // 55.8 MB, alias (T1 dead then)
  float* F1 = T1;                                // 67 MB co1 output, alias
  // conv weight buffers alias X71 region (dead after embedding attn):
  __hip_bfloat16* WcA = (__hip_bfloat16*)base;                 // up to 9,437,184 B (co1)
  __hip_bfloat16* WcB = (__hip_bfloat16*)(base + 4718592);     // 4,718,592 B

  // one-time QKV weight repack (9 layers)
  repack_qkv_w<<<27648, 256, 0, stream>>>(emb_qkv, qkvw_in, Wq);

  // embeddings + layernorm -> X71 (bf16)
  build_ln_kernel<<<512, 256, 0, stream>>>(fen, move, rank_emb, file_emb,
                                           fen_emb, move_emb, abs_emb,
                                           ln_w, ln_b, X71);
  // embedding MHA (T=71): proj -> attn (residual = X71[:, :, :64]) -> X64
  proj_kernel<71, 80, true><<<1536, 256, 0, stream>>>(X71, Wq, qkvws);
  attn_kernel<71, true><<<2048, 256, 0, stream>>>(qkvws, emb_norm_w, X71, X64);

  for (int l = 0; l < 8; ++l) {
    // conv block: repack w1 -> conv1(+RMS fused) -> repack w2 -> conv2(+res)
    repack_conv_w<<<9216, 256, 0, stream>>>(conv1_w + (size_t)l * 512 * 512 * 9,
                                            WcA, 512 * 4608);
    conv_mfma<true, false><<<512, 256, 0, stream>>>(X64, WcA, conv1_b + l * 512,
                                                    cb_norm_w + l, nullptr, T1, 512);
    repack_conv_w<<<9216, 256, 0, stream>>>(conv2_w + (size_t)l * 512 * 512 * 9,
                                            WcB, 512 * 4608);
    conv_mfma<false, true><<<512, 256, 0, stream>>>(T1, WcB, conv2_b + l * 512,
                                                    nullptr, X64, X64, 512);
    // MHA (T=64), residual folded into attn epilogue
    proj_kernel<64, 64, false><<<1536, 256, 0, stream>>>(
        X64, Wq + (size_t)(l + 1) * 1536 * 512, qkvws);
    attn_kernel<64, false><<<2048, 256, 0, stream>>>(qkvws, mha_norm_w + l, X64, X64);
  }

  // head: co1 (512->1024 SAME, RMS fused) -> co2 (VALID 8x8 -> scalar)
  repack_conv_w<<<18432, 256, 0, stream>>>(co1_w, WcA, 1024 * 4608);
  conv_mfma<true, false><<<1024, 256, 0, stream>>>(X64, WcA, co1_b,
                                                   out_norm_w, nullptr, F1, 1024);
  co2_kernel<<<256, 256, 0, stream>>>(F1, co2_w, co2_b, out);
}

// Round 7
// 4463.028 us; speedup vs baseline: 15.4709x; 1.6728x over previous
//
#include <hip/hip_runtime.h>
#include <hip/hip_bf16.h>
#include <cstdint>
#include <cstddef>

// Net: B=256, D=512, L=8, H=8, T=71->64, DH=64.
// Round 7: conv restructured — weights stream global->VGPR as pre-swizzled
// MFMA fragment slabs (no LDS round-trip, no per-k barriers); LDS holds only
// the 10x10 zero-bordered activation board, double-buffered (1 barrier/cc).
// ws layout (bytes), total 133,431,296 (unchanged, validated):
//   X71  bf16 @ 0          18,612,224   (embeds; region reused as WcA/WcB after)
//   X64  f32  @ 18,612,224 33,554,432   (residual stream)
//   T1   f32  @ 52,166,656 67,108,864   (conv tmp / qkvws bf16 / F1)
//   Wq   bf16 @119,275,520 14,155,776   (repacked QKV weights, 9 layers)

typedef float f32x4 __attribute__((ext_vector_type(4)));
typedef short short8 __attribute__((ext_vector_type(8)));

__device__ __forceinline__ float lrelu(float v) { return v > 0.f ? v : 0.2f * v; }
__device__ __forceinline__ __hip_bfloat16 tobf(float v) { return __float2bfloat16(v); }
__device__ __forceinline__ float frombf(__hip_bfloat16 v) { return __bfloat162float(v); }

// ---------------------------------------------------------------------------
// One-time QKV weight repack (validated round 5).
// ---------------------------------------------------------------------------
__global__ __launch_bounds__(256) void repack_qkv_w(
    const float* __restrict__ emb_qkv, const float* __restrict__ qkvw,
    __hip_bfloat16* __restrict__ Wq)
{
  int o = blockIdx.x * 256 + threadIdx.x;        // < 9*1536*512
  int L = o / (1536 * 512);
  int rem = o - L * 1536 * 512;
  int j = rem >> 9;
  int d = rem & 511;
  int n = j >> 9, h = (j >> 6) & 7, dh = j & 63;
  float v;
  if (L == 0) v = emb_qkv[(((n * 8 + h) * 512 + d) << 6) + dh];
  else        v = qkvw[((((size_t)(L - 1) * 3 + n) * 8 + h) * 512 + d) * 64 + dh];
  Wq[o] = tobf(v);
}

// ---------------------------------------------------------------------------
// Conv weight repack into fragment slabs:
//   W2[((((cc*9+k)*NJ + oj)*2 + ks)*64 + lg*16+lr)*8 + e] = w[o][c][k]
//   with o = oj*16+lr, c = cc*64 + ks*32 + lg*8 + e, NJ = COUT/16.
// Each (cc,k,oj,ks) slab is 1KB; a wave's B-fragment load is one contiguous
// global_load_dwordx4 (lane*16B). Thread = (oj,cbg,lr): reads 72 consecutive
// floats' worth of w[o][c0..c0+8][0..9] (288B contiguous), writes 9x16B.
// ---------------------------------------------------------------------------
__global__ __launch_bounds__(256) void repack_conv_w2(
    const float* __restrict__ w, __hip_bfloat16* __restrict__ W2, int COUT)
{
  const int t = blockIdx.x * 256 + threadIdx.x;   // < COUT*64
  if (t >= (COUT << 6)) return;
  const int lr = t & 15;
  const int cbg = (t >> 4) & 63;
  const int oj = t >> 10;
  const int cc = cbg >> 3, ks = (cbg >> 2) & 1, lg = cbg & 3;
  const int o = oj * 16 + lr;
  const int NJ = COUT >> 4;
  const float* src = w + ((size_t)o * 512 + cbg * 8) * 9;  // 72 consecutive f32
  #pragma unroll
  for (int k = 0; k < 9; ++k) {
    __hip_bfloat16 tmp[8];
    #pragma unroll
    for (int e = 0; e < 8; ++e) tmp[e] = tobf(src[e * 9 + k]);
    size_t di = ((((size_t)cc * 9 + k) * NJ + oj) * 2 + ks) * 512 + (lg * 16 + lr) * 8;
    *(uint4*)&W2[di] = *(const uint4*)tmp;
  }
}

// ---------------------------------------------------------------------------
// Stage 1: embeddings + LayerNorm over T=71 -> X71 bf16 (validated).
// ---------------------------------------------------------------------------
__global__ __launch_bounds__(256) void build_ln_kernel(
    const int* __restrict__ fen, const int* __restrict__ move,
    const float* __restrict__ rank_emb, const float* __restrict__ file_emb,
    const float* __restrict__ fen_emb, const float* __restrict__ move_emb,
    const float* __restrict__ abs_emb, const float* __restrict__ lnw,
    const float* __restrict__ lnb, __hip_bfloat16* __restrict__ X71)
{
  const int gid = blockIdx.x * 256 + threadIdx.x;   // < 256*512
  const int b = gid >> 9, d = gid & 511;
  const int* fb = fen + b * 133;

  float sum = 0.f, sq = 0.f, mu = 0.f, rstd = 0.f;
  #pragma unroll 1
  for (int pass = 0; pass < 2; ++pass) {
    if (pass) {
      mu = sum * (1.f / 71.f);
      float var = sq * (1.f / 71.f) - mu * mu;
      rstd = rsqrtf(var + 1e-5f);
    }
    #pragma unroll 1
    for (int t = 0; t < 71; ++t) {
      float a = abs_emb[t * 512 + d];
      float v;
      if (t < 64) {
        float pos = rank_emb[(t >> 3) * 512 + d] + file_emb[(t & 7) * 512 + d];
        v = 0.5f * (fen_emb[fb[t] * 512 + d] + fen_emb[fb[64 + t] * 512 + d] + pos) + a;
      } else if (t < 69) {
        v = fen_emb[fb[t + 64] * 512 + d] + a;
      } else {
        int j = t - 69;
        int s = move[b * 2 + j];
        float pos = rank_emb[(s >> 3) * 512 + d] + file_emb[(s & 7) * 512 + d];
        v = (pos + move_emb[j * 512 + d]) * 0.58f + a;
      }
      if (pass) X71[(size_t)gid * 71 + t] = tobf((v - mu) * rstd * lnw[t] + lnb[t]);
      else { sum += v; sq += v * v; }
    }
  }
}

// ---------------------------------------------------------------------------
// QKV projection GEMM (bf16 MFMA 16x16x32) — validated round 5.
// ---------------------------------------------------------------------------
template <int T, int TP, bool INBF>
__global__ __launch_bounds__(256) void proj_kernel(
    const void* __restrict__ xin, const __hip_bfloat16* __restrict__ Wq,
    __hip_bfloat16* __restrict__ qw)
{
  const int b  = blockIdx.x / 6;
  const int jb = (blockIdx.x % 6) * 256;
  const int tid = threadIdx.x;
  const int lane = tid & 63, wv = tid >> 6;
  const int lr = lane & 15, lg = lane >> 4;

  __shared__ __hip_bfloat16 xt[TP * 72];
  __shared__ __hip_bfloat16 wl[256 * 72];

  constexpr int MI = TP / 16;
  f32x4 acc[MI][4];
  #pragma unroll
  for (int mi = 0; mi < MI; ++mi)
    #pragma unroll
    for (int ni = 0; ni < 4; ++ni) acc[mi][ni] = {0.f, 0.f, 0.f, 0.f};

  for (int c0 = 0; c0 < 512; c0 += 64) {
    if constexpr (INBF) {
      const __hip_bfloat16* x = (const __hip_bfloat16*)xin;
      for (int i = tid; i < 64 * TP; i += 256) {
        int d = i / TP, t = i - d * TP;
        float v = (t < T) ? lrelu(frombf(x[((size_t)(b * 512 + c0 + d)) * T + t])) : 0.f;
        xt[t * 72 + d] = tobf(v);
      }
    } else {
      const float* x = (const float*)xin;
      for (int i = tid; i < 64 * TP; i += 256) {
        int d = i >> 6, t = i & 63;
        float v = lrelu(x[((size_t)(b * 512 + c0 + d)) * 64 + t]);
        xt[t * 72 + d] = tobf(v);
      }
    }
    for (int i = tid; i < 2048; i += 256) {
      int j = i >> 3, cb = i & 7;
      *(uint4*)&wl[j * 72 + cb * 8] =
          *(const uint4*)&Wq[(size_t)(jb + j) * 512 + c0 + cb * 8];
    }
    __syncthreads();
    #pragma unroll
    for (int ks = 0; ks < 2; ++ks) {
      short8 a[MI], bb[4];
      #pragma unroll
      for (int mi = 0; mi < MI; ++mi)
        a[mi] = *(const short8*)&xt[(mi * 16 + lr) * 72 + ks * 32 + lg * 8];
      #pragma unroll
      for (int ni = 0; ni < 4; ++ni)
        bb[ni] = *(const short8*)&wl[(wv * 64 + ni * 16 + lr) * 72 + ks * 32 + lg * 8];
      #pragma unroll
      for (int mi = 0; mi < MI; ++mi)
        #pragma unroll
        for (int ni = 0; ni < 4; ++ni)
          acc[mi][ni] = __builtin_amdgcn_mfma_f32_16x16x32_bf16(
              a[mi], bb[ni], acc[mi][ni], 0, 0, 0);
    }
    __syncthreads();
  }
  #pragma unroll
  for (int mi = 0; mi < MI; ++mi) {
    #pragma unroll
    for (int ni = 0; ni < 4; ++ni) {
      int j = jb + wv * 64 + ni * 16 + lr;
      #pragma unroll
      for (int r = 0; r < 4; ++r) {
        int t = mi * 16 + lg * 4 + r;
        if (TP == T || t < T)
          qw[((size_t)b * T + t) * 1536 + j] = tobf(acc[mi][ni][r]);
      }
    }
  }
}

// ---------------------------------------------------------------------------
// Fused RMS(token axis) + softmax + PV + residual — validated round 5.
// ---------------------------------------------------------------------------
template <int T, bool RESBF>
__global__ __launch_bounds__(256) void attn_kernel(
    const __hip_bfloat16* __restrict__ qw, const float* __restrict__ nw,
    const void* __restrict__ res, float* __restrict__ out)
{
  constexpr int PL = (T & 1) ? T : T + 1;
  const int b = blockIdx.x >> 3, h = blockIdx.x & 7;
  const int tid = threadIdx.x, lane = tid & 63, wv = tid >> 6;

  __shared__ float smx[3 * T * 65];
  __shared__ float scl[192];
  __shared__ float plds[64 * PL];

  for (int i = tid; i < 3 * T * 64; i += 256) {
    int n = i / (T * 64), rem = i - n * (T * 64);
    int t = rem >> 6, dh = rem & 63;
    smx[n * T * 65 + t * 65 + dh] =
        frombf(qw[((size_t)b * T + t) * 1536 + n * 512 + (h << 6) + dh]);
  }
  __syncthreads();
  if (tid < 192) {
    int n = tid >> 6, dh = tid & 63;
    float ss = 0.f;
    for (int t = 0; t < T; ++t) { float v = smx[n * T * 65 + t * 65 + dh]; ss += v * v; }
    scl[tid] = nw[0] * rsqrtf(ss * (1.f / T) + 1e-6f);
  }
  __syncthreads();
  for (int i = tid; i < 3 * T * 64; i += 256) {
    int n = i / (T * 64), rem = i - n * (T * 64);
    int t = rem >> 6, dh = rem & 63;
    smx[n * T * 65 + t * 65 + dh] *= scl[(n << 6) + dh];
  }
  __syncthreads();

  const float* qm = smx;
  const float* km = smx + T * 65;
  const float* vm = smx + 2 * T * 65;

  for (int t = wv; t < 64; t += 4) {
    float s0 = 0.f, s1 = 0.f;
    #pragma unroll 8
    for (int dh = 0; dh < 64; ++dh) s0 += qm[t * 65 + dh] * km[lane * 65 + dh];
    bool has1 = false;
    if constexpr (T > 64) {
      has1 = (lane + 64 < T);
      if (has1) {
        #pragma unroll 8
        for (int dh = 0; dh < 64; ++dh) s1 += qm[t * 65 + dh] * km[(lane + 64) * 65 + dh];
      }
    }
    s0 *= 0.125f; s1 *= 0.125f;
    float mx = has1 ? fmaxf(s0, s1) : s0;
    #pragma unroll
    for (int off = 32; off; off >>= 1) mx = fmaxf(mx, __shfl_xor(mx, off));
    float e0 = __expf(s0 - mx);
    float e1 = has1 ? __expf(s1 - mx) : 0.f;
    float sm = e0 + e1;
    #pragma unroll
    for (int off = 32; off; off >>= 1) sm += __shfl_xor(sm, off);
    float inv = 1.f / sm;
    plds[t * PL + lane] = e0 * inv;
    if constexpr (T > 64) {
      if (lane < T - 64) plds[t * PL + 64 + lane] = e1 * inv;
    }
  }
  __syncthreads();

  for (int dh = wv; dh < 64; dh += 4) {
    float acc = 0.f;
    #pragma unroll 8
    for (int j = 0; j < T; ++j) acc += plds[lane * PL + j] * vm[j * 65 + dh];
    size_t oidx = ((size_t)(b * 512 + (h << 6) + dh)) * 64 + lane;
    float rv;
    if constexpr (RESBF)
      rv = frombf(((const __hip_bfloat16*)res)[((size_t)(b * 512 + (h << 6) + dh)) * T + lane]);
    else
      rv = ((const float*)res)[oidx];
    out[oidx] = rv + acc;
  }
}

// ---------------------------------------------------------------------------
// MFMA conv 3x3 SAME on 8x8, CIN=512, weights direct global->VGPR.
// Block = (b, 256-oc tile), 4 waves (wave = N 64-slice). M=64 spatial.
// Per cc: [issue cc+1 activation loads to regs] [9k x {8 coalesced weight
// fragment loads, 8 ds_read_b128 A-fragments, 32 MFMA}] [write cc+1 LDS]
// [barrier]. One barrier per cc; no weight LDS at all.
// ---------------------------------------------------------------------------
template <bool RMSOUT, bool RESADD>
__global__ __launch_bounds__(256) void conv_mfma2(
    const float* __restrict__ x,            // (B,512,64) f32
    const __hip_bfloat16* __restrict__ W2,  // fragment slabs (see repack)
    const float* __restrict__ bias,         // (COUT)
    const float* __restrict__ nw,           // scalar rms weight (RMSOUT)
    const float* __restrict__ res,          // (B,COUT,64) f32 (RESADD)
    float* __restrict__ out,                // (B,COUT,64) f32
    int COUT)
{
  const int ntc = COUT >> 8;
  const int b = blockIdx.x / ntc;
  const int nt = blockIdx.x - b * ntc;
  const int o0 = nt << 8;
  const int NJ = COUT >> 4;
  const int tid = threadIdx.x;
  const int lane = tid & 63, wv = tid >> 6;
  const int lr = lane & 15, lg = lane >> 4;

  __shared__ __hip_bfloat16 xt[2][100 * 72];  // 10x10 zero-bordered boards

  f32x4 acc[4][4];
  #pragma unroll
  for (int mi = 0; mi < 4; ++mi)
    #pragma unroll
    for (int ni = 0; ni < 4; ++ni) acc[mi][ni] = {0.f, 0.f, 0.f, 0.f};

  // zero both buffers (borders must be 0; interior overwritten per cc)
  for (int i = tid; i < 7200; i += 256) { xt[0][i] = tobf(0.f); xt[1][i] = tobf(0.f); }

  f32x4 sreg[4];
  const int s_ci = tid >> 4;                 // channel within chunk (0..63: u adds +16)
  const int s_p4 = (tid & 15) << 2;          // position group
  const int s_row = (((s_p4 >> 3) + 1) * 10 + (s_p4 & 7) + 1) * 72;  // p4..p4+3 same board row

  #define STAGE_LOAD(cc_)                                                     \
    {                                                                         \
      const float* xb_ = x + ((size_t)b * 512 + (cc_) * 64 + s_ci) * 64 + s_p4; \
      _Pragma("unroll")                                                       \
      for (int u = 0; u < 4; ++u) sreg[u] = *(const f32x4*)&xb_[u * 1024];    \
    }
  #define STAGE_WRITE(buf_)                                                   \
    {                                                                         \
      _Pragma("unroll")                                                       \
      for (int u = 0; u < 4; ++u) {                                           \
        _Pragma("unroll")                                                     \
        for (int j = 0; j < 4; ++j)                                           \
          xt[buf_][s_row + j * 72 + s_ci + u * 16] = tobf(lrelu(sreg[u][j])); \
      }                                                                       \
    }

  STAGE_LOAD(0);
  __syncthreads();            // zero-init visible before interior writes
  STAGE_WRITE(0);
  __syncthreads();

  const int ojb2 = ((o0 >> 4) + wv * 4) * 2;  // slab sub-index for this wave

  for (int cc = 0; cc < 8; ++cc) {
    const int cur = cc & 1;
    if (cc < 7) STAGE_LOAD(cc + 1);
    const __hip_bfloat16* xb = xt[cur];

    #pragma unroll
    for (int k = 0; k < 9; ++k) {
      const int dy = k / 3 - 1, dx = k - (k / 3) * 3 - 1;
      const int ii0 = (lr >> 3) + dy + 1;
      const int jj0 = (lr & 7) + dx + 1;
      const size_t slab = ((size_t)(cc * 9 + k) * NJ) * 2 + ojb2;
      short8 bv[2][4], av[2][4];
      #pragma unroll
      for (int ni = 0; ni < 4; ++ni)
        #pragma unroll
        for (int ks = 0; ks < 2; ++ks)
          bv[ks][ni] = *(const short8*)&W2[(slab + ni * 2 + ks) * 512 + lane * 8];
      #pragma unroll
      for (int ks = 0; ks < 2; ++ks)
        #pragma unroll
        for (int mi = 0; mi < 4; ++mi)
          av[ks][mi] = *(const short8*)&xb[((ii0 + mi * 2) * 10 + jj0) * 72 + ks * 32 + lg * 8];
      #pragma unroll
      for (int ks = 0; ks < 2; ++ks)
        #pragma unroll
        for (int mi = 0; mi < 4; ++mi)
          #pragma unroll
          for (int ni = 0; ni < 4; ++ni)
            acc[mi][ni] = __builtin_amdgcn_mfma_f32_16x16x32_bf16(
                av[ks][mi], bv[ks][ni], acc[mi][ni], 0, 0, 0);
    }
    if (cc < 7) STAGE_WRITE(cur ^ 1);
    __syncthreads();
  }
  #undef STAGE_LOAD
  #undef STAGE_WRITE

  // epilogue: +bias, optional spatial-RMS (fold lg via shfl_xor 16/32),
  // optional residual — validated round 6.
  #pragma unroll
  for (int ni = 0; ni < 4; ++ni) {
    const int o = o0 + wv * 64 + ni * 16 + lr;
    const float bvs = bias[o];
    float sc = 1.f;
    if constexpr (RMSOUT) {
      float ss = 0.f;
      #pragma unroll
      for (int mi = 0; mi < 4; ++mi)
        #pragma unroll
        for (int r = 0; r < 4; ++r) {
          float v = acc[mi][ni][r] + bvs;
          ss += v * v;
        }
      ss += __shfl_xor(ss, 16);
      ss += __shfl_xor(ss, 32);
      sc = nw[0] * rsqrtf(ss * (1.f / 64.f) + 1e-6f);
    }
    #pragma unroll
    for (int mi = 0; mi < 4; ++mi) {
      size_t idx = ((size_t)b * COUT + o) * 64 + mi * 16 + lg * 4;
      f32x4 v;
      #pragma unroll
      for (int r = 0; r < 4; ++r) v[r] = (acc[mi][ni][r] + bvs) * sc;
      if constexpr (RESADD) v += *(const f32x4*)&res[idx];
      *(f32x4*)&out[idx] = v;
    }
  }
}

// ---------------------------------------------------------------------------
// Final VALID 8x8 conv: out[b] = sum_{c,p} lrelu(F1[b,c,p]) * w[c,p] + bias.
// ---------------------------------------------------------------------------
__global__ __launch_bounds__(256) void co2_kernel(
    const float* __restrict__ xf, const float* __restrict__ w,
    const float* __restrict__ cb, float* __restrict__ out)
{
  const int b = blockIdx.x, tid = threadIdx.x;
  const float* xb = xf + (size_t)b * 65536;
  float acc = 0.f;
  for (int i = tid; i < 65536; i += 256)
    acc += lrelu(xb[i]) * w[i];
  #pragma unroll
  for (int off = 32; off; off >>= 1) acc += __shfl_down(acc, off);
  __shared__ float red[4];
  if ((tid & 63) == 0) red[tid >> 6] = acc;
  __syncthreads();
  if (tid == 0) out[b] = red[0] + red[1] + red[2] + red[3] + cb[0];
}

// ---------------------------------------------------------------------------
extern "C" void kernel_launch(void* const* d_in, const int* in_sizes, int n_in,
                              void* d_out, int out_size, void* d_ws, size_t ws_size,
                              hipStream_t stream)
{
  const int*   fen        = (const int*)d_in[0];
  const int*   move       = (const int*)d_in[1];
  const float* rank_emb   = (const float*)d_in[2];
  const float* file_emb   = (const float*)d_in[3];
  const float* fen_emb    = (const float*)d_in[4];
  const float* move_emb   = (const float*)d_in[5];
  const float* abs_emb    = (const float*)d_in[6];
  const float* ln_w       = (const float*)d_in[7];
  const float* ln_b       = (const float*)d_in[8];
  const float* emb_qkv    = (const float*)d_in[9];
  const float* emb_norm_w = (const float*)d_in[10];
  const float* qkvw_in    = (const float*)d_in[11];
  const float* mha_norm_w = (const float*)d_in[12];
  const float* conv1_w    = (const float*)d_in[13];
  const float* conv1_b    = (const float*)d_in[14];
  const float* conv2_w    = (const float*)d_in[15];
  const float* conv2_b    = (const float*)d_in[16];
  const float* cb_norm_w  = (const float*)d_in[17];
  const float* out_norm_w = (const float*)d_in[18];
  const float* co1_w      = (const float*)d_in[19];
  const float* co1_b      = (const float*)d_in[20];
  const float* co2_w      = (const float*)d_in[21];
  const float* co2_b      = (const float*)d_in[22];
  float* out = (float*)d_out;

  char* base = (char*)d_ws;
  __hip_bfloat16* X71 = (__hip_bfloat16*)base;                       // 18,612,224 B
  float* X64 = (float*)(base + 18612224);                            // 33,554,432 B
  float* T1  = (float*)(base + 18612224 + 33554432);                 // 67,108,864 B
  __hip_bfloat16* Wq = (__hip_bfloat16*)(base + 18612224 + 33554432 + 67108864);
  __hip_bfloat16* qkvws = (__hip_bfloat16*)T1;   // 55.8 MB, alias (T1 dead then)
  float* F1 = T1;                                // 67 MB co1 output, alias
  // conv weight slabs alias X71 region (dead after embedding attn):
  __hip_bfloat16* WcA = (__hip_bfloat16*)base;                 // up to 9,437,184 B (co1)
  __hip_bfloat16* WcB = (__hip_bfloat16*)(base + 4718592);     // 4,718,592 B

  // one-time QKV weight repack (9 layers)
  repack_qkv_w<<<27648, 256, 0, stream>>>(emb_qkv, qkvw_in, Wq);

  // embeddings + layernorm -> X71 (bf16)
  build_ln_kernel<<<512, 256, 0, stream>>>(fen, move, rank_emb, file_emb,
                                           fen_emb, move_emb, abs_emb,
                                           ln_w, ln_b, X71);
  // embedding MHA (T=71): proj -> attn (residual = X71[:, :, :64]) -> X64
  proj_kernel<71, 80, true><<<1536, 256, 0, stream>>>(X71, Wq, qkvws);
  attn_kernel<71, true><<<2048, 256, 0, stream>>>(qkvws, emb_norm_w, X71, X64);

  for (int l = 0; l < 8; ++l) {
    repack_conv_w2<<<128, 256, 0, stream>>>(conv1_w + (size_t)l * 512 * 512 * 9,
                                            WcA, 512);
    conv_mfma2<true, false><<<512, 256, 0, stream>>>(X64, WcA, conv1_b + l * 512,
                                                     cb_norm_w + l, nullptr, T1, 512);
    repack_conv_w2<<<128, 256, 0, stream>>>(conv2_w + (size_t)l * 512 * 512 * 9,
                                            WcB, 512);
    conv_mfma2<false, true><<<512, 256, 0, stream>>>(T1, WcB, conv2_b + l * 512,
                                                     nullptr, X64, X64, 512);
    // MHA (T=64), residual folded into attn epilogue
    proj_kernel<64, 64, false><<<1536, 256, 0, stream>>>(
        X64, Wq + (size_t)(l + 1) * 1536 * 512, qkvws);
    attn_kernel<64, false><<<2048, 256, 0, stream>>>(qkvws, mha_norm_w + l, X64, X64);
  }

  // head: co1 (512->1024 SAME, RMS fused) -> co2 (VALID 8x8 -> scalar)
  repack_conv_w2<<<256, 256, 0, stream>>>(co1_w, WcA, 1024);
  conv_mfma2<true, false><<<1024, 256, 0, stream>>>(X64, WcA, co1_b,
                                                    out_norm_w, nullptr, F1, 1024);
  co2_kernel<<<256, 256, 0, stream>>>(F1, co2_w, co2_b, out);
}

// Round 8
// 2890.683 us; speedup vs baseline: 23.8861x; 1.5439x over previous
//
#include <hip/hip_runtime.h>
#include <hip/hip_bf16.h>
#include <cstdint>
#include <cstddef>

// Net: B=256, D=512, L=8, H=8, T=71->64, DH=64.
// Round 8: attention restructured to MFMA. proj fuses the token-axis RMS
// (f32, pre-quantization) and emits Q,K as [b][t][1024] plus V transposed
// [b][dh'][t]; attn2 is a small 2-phase MFMA kernel (S=QK^T, O=PV) with a
// wave-parallel two-pass softmax, P aliased onto the S buffer.
// ws layout (bytes), total 133,431,296 (unchanged, validated):
//   X71  bf16 @ 0          18,612,224   (embeds; region reused as WcA/WcB after)
//   X64  f32  @ 18,612,224 33,554,432   (residual stream)
//   T1   f32  @ 52,166,656 67,108,864   (conv tmp 33.5MB | qk2 37.2MB + vT 21MB | F1 67MB)
//   Wq   bf16 @119,275,520 14,155,776   (repacked QKV weights, 9 layers)

typedef float f32x4 __attribute__((ext_vector_type(4)));
typedef short short8 __attribute__((ext_vector_type(8)));

__device__ __forceinline__ float lrelu(float v) { return v > 0.f ? v : 0.2f * v; }
__device__ __forceinline__ __hip_bfloat16 tobf(float v) { return __float2bfloat16(v); }
__device__ __forceinline__ float frombf(__hip_bfloat16 v) { return __bfloat162float(v); }

// ---------------------------------------------------------------------------
// One-time QKV weight repack (validated round 5).
// ---------------------------------------------------------------------------
__global__ __launch_bounds__(256) void repack_qkv_w(
    const float* __restrict__ emb_qkv, const float* __restrict__ qkvw,
    __hip_bfloat16* __restrict__ Wq)
{
  int o = blockIdx.x * 256 + threadIdx.x;        // < 9*1536*512
  int L = o / (1536 * 512);
  int rem = o - L * 1536 * 512;
  int j = rem >> 9;
  int d = rem & 511;
  int n = j >> 9, h = (j >> 6) & 7, dh = j & 63;
  float v;
  if (L == 0) v = emb_qkv[(((n * 8 + h) * 512 + d) << 6) + dh];
  else        v = qkvw[((((size_t)(L - 1) * 3 + n) * 8 + h) * 512 + d) * 64 + dh];
  Wq[o] = tobf(v);
}

// ---------------------------------------------------------------------------
// Conv weight repack into fragment slabs (validated round 7).
// ---------------------------------------------------------------------------
__global__ __launch_bounds__(256) void repack_conv_w2(
    const float* __restrict__ w, __hip_bfloat16* __restrict__ W2, int COUT)
{
  const int t = blockIdx.x * 256 + threadIdx.x;   // < COUT*64
  if (t >= (COUT << 6)) return;
  const int lr = t & 15;
  const int cbg = (t >> 4) & 63;
  const int oj = t >> 10;
  const int cc = cbg >> 3, ks = (cbg >> 2) & 1, lg = cbg & 3;
  const int o = oj * 16 + lr;
  const int NJ = COUT >> 4;
  const float* src = w + ((size_t)o * 512 + cbg * 8) * 9;  // 72 consecutive f32
  #pragma unroll
  for (int k = 0; k < 9; ++k) {
    __hip_bfloat16 tmp[8];
    #pragma unroll
    for (int e = 0; e < 8; ++e) tmp[e] = tobf(src[e * 9 + k]);
    size_t di = ((((size_t)cc * 9 + k) * NJ + oj) * 2 + ks) * 512 + (lg * 16 + lr) * 8;
    *(uint4*)&W2[di] = *(const uint4*)tmp;
  }
}

// ---------------------------------------------------------------------------
// Stage 1: embeddings + LayerNorm over T=71 -> X71 bf16 (validated).
// ---------------------------------------------------------------------------
__global__ __launch_bounds__(256) void build_ln_kernel(
    const int* __restrict__ fen, const int* __restrict__ move,
    const float* __restrict__ rank_emb, const float* __restrict__ file_emb,
    const float* __restrict__ fen_emb, const float* __restrict__ move_emb,
    const float* __restrict__ abs_emb, const float* __restrict__ lnw,
    const float* __restrict__ lnb, __hip_bfloat16* __restrict__ X71)
{
  const int gid = blockIdx.x * 256 + threadIdx.x;   // < 256*512
  const int b = gid >> 9, d = gid & 511;
  const int* fb = fen + b * 133;

  float sum = 0.f, sq = 0.f, mu = 0.f, rstd = 0.f;
  #pragma unroll 1
  for (int pass = 0; pass < 2; ++pass) {
    if (pass) {
      mu = sum * (1.f / 71.f);
      float var = sq * (1.f / 71.f) - mu * mu;
      rstd = rsqrtf(var + 1e-5f);
    }
    #pragma unroll 1
    for (int t = 0; t < 71; ++t) {
      float a = abs_emb[t * 512 + d];
      float v;
      if (t < 64) {
        float pos = rank_emb[(t >> 3) * 512 + d] + file_emb[(t & 7) * 512 + d];
        v = 0.5f * (fen_emb[fb[t] * 512 + d] + fen_emb[fb[64 + t] * 512 + d] + pos) + a;
      } else if (t < 69) {
        v = fen_emb[fb[t + 64] * 512 + d] + a;
      } else {
        int j = t - 69;
        int s = move[b * 2 + j];
        float pos = rank_emb[(s >> 3) * 512 + d] + file_emb[(s & 7) * 512 + d];
        v = (pos + move_emb[j * 512 + d]) * 0.58f + a;
      }
      if (pass) X71[(size_t)gid * 71 + t] = tobf((v - mu) * rstd * lnw[t] + lnb[t]);
      else { sum += v; sq += v * v; }
    }
  }
}

// ---------------------------------------------------------------------------
// QKV projection GEMM (bf16 MFMA 16x16x32) + fused token-axis RMS (f32).
// Outputs: qk[b][t][j<1024] (Q|K, RMS'd, bf16) and vT[b][jj][t] (V^T, RMS'd).
// RMS per column j: register sumsq + shfl_xor(16/32) fold across lg groups
// (rows t>=T are zero-padded in the A staging, so they contribute 0).
// ---------------------------------------------------------------------------
template <int T, int TP, bool INBF>
__global__ __launch_bounds__(256) void proj_kernel(
    const void* __restrict__ xin, const __hip_bfloat16* __restrict__ Wq,
    const float* __restrict__ nw,
    __hip_bfloat16* __restrict__ qk, __hip_bfloat16* __restrict__ vT)
{
  const int b  = blockIdx.x / 6;
  const int jb = (blockIdx.x % 6) * 256;
  const int tid = threadIdx.x;
  const int lane = tid & 63, wv = tid >> 6;
  const int lr = lane & 15, lg = lane >> 4;

  __shared__ __hip_bfloat16 xt[TP * 72];
  __shared__ __hip_bfloat16 wl[256 * 72];

  constexpr int MI = TP / 16;
  f32x4 acc[MI][4];
  #pragma unroll
  for (int mi = 0; mi < MI; ++mi)
    #pragma unroll
    for (int ni = 0; ni < 4; ++ni) acc[mi][ni] = {0.f, 0.f, 0.f, 0.f};

  for (int c0 = 0; c0 < 512; c0 += 64) {
    if constexpr (INBF) {
      const __hip_bfloat16* x = (const __hip_bfloat16*)xin;
      for (int i = tid; i < 64 * TP; i += 256) {
        int d = i / TP, t = i - d * TP;
        float v = (t < T) ? lrelu(frombf(x[((size_t)(b * 512 + c0 + d)) * T + t])) : 0.f;
        xt[t * 72 + d] = tobf(v);
      }
    } else {
      const float* x = (const float*)xin;
      for (int i = tid; i < 64 * TP; i += 256) {
        int d = i >> 6, t = i & 63;
        float v = lrelu(x[((size_t)(b * 512 + c0 + d)) * 64 + t]);
        xt[t * 72 + d] = tobf(v);
      }
    }
    for (int i = tid; i < 2048; i += 256) {
      int j = i >> 3, cb = i & 7;
      *(uint4*)&wl[j * 72 + cb * 8] =
          *(const uint4*)&Wq[(size_t)(jb + j) * 512 + c0 + cb * 8];
    }
    __syncthreads();
    #pragma unroll
    for (int ks = 0; ks < 2; ++ks) {
      short8 a[MI], bb[4];
      #pragma unroll
      for (int mi = 0; mi < MI; ++mi)
        a[mi] = *(const short8*)&xt[(mi * 16 + lr) * 72 + ks * 32 + lg * 8];
      #pragma unroll
      for (int ni = 0; ni < 4; ++ni)
        bb[ni] = *(const short8*)&wl[(wv * 64 + ni * 16 + lr) * 72 + ks * 32 + lg * 8];
      #pragma unroll
      for (int mi = 0; mi < MI; ++mi)
        #pragma unroll
        for (int ni = 0; ni < 4; ++ni)
          acc[mi][ni] = __builtin_amdgcn_mfma_f32_16x16x32_bf16(
              a[mi], bb[ni], acc[mi][ni], 0, 0, 0);
    }
    __syncthreads();
  }

  // epilogue: per-column RMS over token axis, then Q/K or V^T writes.
  #pragma unroll
  for (int ni = 0; ni < 4; ++ni) {
    const int j = jb + wv * 64 + ni * 16 + lr;
    float ss = 0.f;
    #pragma unroll
    for (int mi = 0; mi < MI; ++mi)
      #pragma unroll
      for (int r = 0; r < 4; ++r) ss += acc[mi][ni][r] * acc[mi][ni][r];
    ss += __shfl_xor(ss, 16);
    ss += __shfl_xor(ss, 32);
    const float sc = nw[0] * rsqrtf(ss * (1.f / T) + 1e-6f);
    if (j < 1024) {
      #pragma unroll
      for (int mi = 0; mi < MI; ++mi)
        #pragma unroll
        for (int r = 0; r < 4; ++r) {
          int t = mi * 16 + lg * 4 + r;
          if (TP == T || t < T)
            qk[((size_t)b * T + t) * 1024 + j] = tobf(acc[mi][ni][r] * sc);
        }
    } else {
      const int jj = j - 1024;
      #pragma unroll
      for (int mi = 0; mi < MI; ++mi)
        #pragma unroll
        for (int r = 0; r < 4; ++r) {
          int t = mi * 16 + lg * 4 + r;   // rows t>=T are true zeros -> valid pad
          vT[((size_t)b * 512 + jj) * TP + t] = tobf(acc[mi][ni][r] * sc);
        }
    }
  }
}

// ---------------------------------------------------------------------------
// MFMA attention per (b,h): S = Q·K^T/8 -> softmax -> O = P·V (+residual).
// Q,K staged [token][dh] stride 72; V^T staged [dh][t'] stride PS; S f32
// stride SC (66/82: 2-way banks on column writes); P (bf16) aliases S with a
// barrier-separated two-pass softmax. Queries t<64 only (output slice).
// ---------------------------------------------------------------------------
template <int T, bool RESBF>
__global__ __launch_bounds__(256) void attn2_kernel(
    const __hip_bfloat16* __restrict__ qk,   // [b][t][1024] RMS'd Q|K
    const __hip_bfloat16* __restrict__ vT,   // [b][jj][TP]  RMS'd V^T
    const void* __restrict__ res, float* __restrict__ out)
{
  constexpr int TP = (T == 71) ? 80 : 64;    // vT global row stride
  constexpr int TK = (T + 31) / 32;          // PV K steps (2 or 3)
  constexpr int RS = 72;                     // q/k LDS row stride (bf16)
  constexpr int PS = TK * 32 + 8;            // vt/plds LDS row stride (72/104)
  constexpr int KR = (T == 71) ? 80 : 64;    // k LDS rows (key frag coverage)
  constexpr int SC = (T == 71) ? 82 : 66;    // slds f32 row stride
  constexpr int NCF = KR / 16;               // S col frags (5 or 4)
  constexpr int NFW = (NCF + 3) / 4;         // col frags per wave
  constexpr int RANGE = (TK * 32) / 4;       // softmax cols per thread (16/24)

  constexpr int Q_OFF = 0;
  constexpr int K_OFF = Q_OFF + 64 * RS * 2;
  constexpr int V_OFF = K_OFF + KR * RS * 2;
  constexpr int S_OFF = V_OFF + 64 * PS * 2;
  constexpr int BYTES = S_OFF + 64 * SC * 4;
  __shared__ __align__(16) char smem[BYTES];
  __hip_bfloat16* qs = (__hip_bfloat16*)(smem + Q_OFF);
  __hip_bfloat16* ksh = (__hip_bfloat16*)(smem + K_OFF);
  __hip_bfloat16* vs = (__hip_bfloat16*)(smem + V_OFF);
  float* ss = (float*)(smem + S_OFF);
  __hip_bfloat16* ps = (__hip_bfloat16*)(smem + S_OFF);   // alias (two-pass)

  const int b = blockIdx.x >> 3, h = blockIdx.x & 7;
  const int tid = threadIdx.x;
  const int lane = tid & 63, wv = tid >> 6;
  const int lr = lane & 15, lg = lane >> 4;

  // zero-init (k pad rows, vt pad cols)
  for (int i = tid; i < BYTES / 16; i += 256) ((uint4*)smem)[i] = uint4{0, 0, 0, 0};
  __syncthreads();

  // stage Q (64 rows), K (T rows), V^T (64 rows x TP cols)
  const __hip_bfloat16* qb = qk + (size_t)b * T * 1024 + h * 64;
  for (int v = tid; v < 512; v += 256) {
    int t = v >> 3, d0 = (v & 7) * 8;
    *(uint4*)&qs[t * RS + d0] = *(const uint4*)&qb[(size_t)t * 1024 + d0];
  }
  for (int v = tid; v < T * 8; v += 256) {
    int t = v >> 3, d0 = (v & 7) * 8;
    *(uint4*)&ksh[t * RS + d0] = *(const uint4*)&qb[(size_t)t * 1024 + 512 + d0];
  }
  constexpr int VV = TP / 8;
  for (int v = tid; v < 64 * VV; v += 256) {
    int dh = v / VV, tc = (v - dh * VV) * 8;
    *(uint4*)&vs[dh * PS + tc] =
        *(const uint4*)&vT[((size_t)b * 512 + h * 64 + dh) * TP + tc];
  }
  __syncthreads();

  // S = Q.K^T * 0.125
  f32x4 sacc[NFW][4];
  #pragma unroll
  for (int fi = 0; fi < NFW; ++fi)
    #pragma unroll
    for (int mi = 0; mi < 4; ++mi) sacc[fi][mi] = {0.f, 0.f, 0.f, 0.f};
  #pragma unroll
  for (int ks2 = 0; ks2 < 2; ++ks2) {
    short8 a[4];
    #pragma unroll
    for (int mi = 0; mi < 4; ++mi)
      a[mi] = *(const short8*)&qs[(mi * 16 + lr) * RS + ks2 * 32 + lg * 8];
    #pragma unroll
    for (int fi = 0; fi < NFW; ++fi) {
      const int f = wv + fi * 4;
      if (f < NCF) {
        short8 bb = *(const short8*)&ksh[(f * 16 + lr) * RS + ks2 * 32 + lg * 8];
        #pragma unroll
        for (int mi = 0; mi < 4; ++mi)
          sacc[fi][mi] = __builtin_amdgcn_mfma_f32_16x16x32_bf16(
              a[mi], bb, sacc[fi][mi], 0, 0, 0);
      }
    }
  }
  #pragma unroll
  for (int fi = 0; fi < NFW; ++fi) {
    const int f = wv + fi * 4;
    if (f < NCF) {
      #pragma unroll
      for (int mi = 0; mi < 4; ++mi)
        #pragma unroll
        for (int r = 0; r < 4; ++r)
          ss[(mi * 16 + lg * 4 + r) * SC + f * 16 + lr] = sacc[fi][mi][r] * 0.125f;
    }
  }
  __syncthreads();

  // softmax: 4 threads per row; pass 1 read+reduce, pass 2 write P (bf16),
  // zero-filling pad cols T..TK*32 (P aliases S, so pads must be rewritten).
  {
    const int row = tid >> 2, q4 = tid & 3;
    float sv[RANGE];
    float mx = -3.0e38f;
    #pragma unroll
    for (int i = 0; i < RANGE; ++i) {
      int c = q4 * RANGE + i;
      sv[i] = (c < T) ? ss[row * SC + c] : -3.0e38f;
      mx = fmaxf(mx, sv[i]);
    }
    mx = fmaxf(mx, __shfl_xor(mx, 1));
    mx = fmaxf(mx, __shfl_xor(mx, 2));
    float sm = 0.f;
    #pragma unroll
    for (int i = 0; i < RANGE; ++i) {
      int c = q4 * RANGE + i;
      sv[i] = (c < T) ? __expf(sv[i] - mx) : 0.f;
      sm += sv[i];
    }
    sm += __shfl_xor(sm, 1);
    sm += __shfl_xor(sm, 2);
    const float inv = 1.f / sm;
    __syncthreads();   // all S reads complete before P overwrites the region
    #pragma unroll
    for (int i = 0; i < RANGE; ++i)
      ps[row * PS + q4 * RANGE + i] = tobf(sv[i] * inv);
  }
  __syncthreads();

  // O = P.V  (A = P rows t, B = V^T rows dh; k = t')
  f32x4 oacc[4];
  #pragma unroll
  for (int mi = 0; mi < 4; ++mi) oacc[mi] = {0.f, 0.f, 0.f, 0.f};
  #pragma unroll
  for (int ks2 = 0; ks2 < TK; ++ks2) {
    short8 bb = *(const short8*)&vs[(wv * 16 + lr) * PS + ks2 * 32 + lg * 8];
    #pragma unroll
    for (int mi = 0; mi < 4; ++mi) {
      short8 a = *(const short8*)&ps[(mi * 16 + lr) * PS + ks2 * 32 + lg * 8];
      oacc[mi] = __builtin_amdgcn_mfma_f32_16x16x32_bf16(a, bb, oacc[mi], 0, 0, 0);
    }
  }

  // epilogue: out[b, h*64+dh, t] = res + O[t][dh]
  const int dh = wv * 16 + lr;
  const size_t chb = (size_t)b * 512 + h * 64 + dh;
  #pragma unroll
  for (int mi = 0; mi < 4; ++mi) {
    const int t0 = mi * 16 + lg * 4;
    const size_t idx = chb * 64 + t0;
    f32x4 v = oacc[mi];
    if constexpr (RESBF) {
      const __hip_bfloat16* rb = (const __hip_bfloat16*)res + chb * T + t0;
      #pragma unroll
      for (int r = 0; r < 4; ++r) v[r] += frombf(rb[r]);
    } else {
      v += *(const f32x4*)&((const float*)res)[idx];
    }
    *(f32x4*)&out[idx] = v;
  }
}

// ---------------------------------------------------------------------------
// MFMA conv 3x3 SAME on 8x8, CIN=512, weights direct global->VGPR (validated
// round 7). One barrier per cc; LDS = double-buffered 10x10 activation board.
// ---------------------------------------------------------------------------
template <bool RMSOUT, bool RESADD>
__global__ __launch_bounds__(256) void conv_mfma2(
    const float* __restrict__ x,            // (B,512,64) f32
    const __hip_bfloat16* __restrict__ W2,  // fragment slabs (see repack)
    const float* __restrict__ bias,         // (COUT)
    const float* __restrict__ nw,           // scalar rms weight (RMSOUT)
    const float* __restrict__ res,          // (B,COUT,64) f32 (RESADD)
    float* __restrict__ out,                // (B,COUT,64) f32
    int COUT)
{
  const int ntc = COUT >> 8;
  const int b = blockIdx.x / ntc;
  const int nt = blockIdx.x - b * ntc;
  const int o0 = nt << 8;
  const int NJ = COUT >> 4;
  const int tid = threadIdx.x;
  const int lane = tid & 63, wv = tid >> 6;
  const int lr = lane & 15, lg = lane >> 4;

  __shared__ __hip_bfloat16 xt[2][100 * 72];  // 10x10 zero-bordered boards

  f32x4 acc[4][4];
  #pragma unroll
  for (int mi = 0; mi < 4; ++mi)
    #pragma unroll
    for (int ni = 0; ni < 4; ++ni) acc[mi][ni] = {0.f, 0.f, 0.f, 0.f};

  for (int i = tid; i < 7200; i += 256) { xt[0][i] = tobf(0.f); xt[1][i] = tobf(0.f); }

  f32x4 sreg[4];
  const int s_ci = tid >> 4;
  const int s_p4 = (tid & 15) << 2;
  const int s_row = (((s_p4 >> 3) + 1) * 10 + (s_p4 & 7) + 1) * 72;

  #define STAGE_LOAD(cc_)                                                     \
    {                                                                         \
      const float* xb_ = x + ((size_t)b * 512 + (cc_) * 64 + s_ci) * 64 + s_p4; \
      _Pragma("unroll")                                                       \
      for (int u = 0; u < 4; ++u) sreg[u] = *(const f32x4*)&xb_[u * 1024];    \
    }
  #define STAGE_WRITE(buf_)                                                   \
    {                                                                         \
      _Pragma("unroll")                                                       \
      for (int u = 0; u < 4; ++u) {                                           \
        _Pragma("unroll")                                                     \
        for (int j = 0; j < 4; ++j)                                           \
          xt[buf_][s_row + j * 72 + s_ci + u * 16] = tobf(lrelu(sreg[u][j])); \
      }                                                                       \
    }

  STAGE_LOAD(0);
  __syncthreads();
  STAGE_WRITE(0);
  __syncthreads();

  const int ojb2 = ((o0 >> 4) + wv * 4) * 2;

  for (int cc = 0; cc < 8; ++cc) {
    const int cur = cc & 1;
    if (cc < 7) STAGE_LOAD(cc + 1);
    const __hip_bfloat16* xb = xt[cur];

    #pragma unroll
    for (int k = 0; k < 9; ++k) {
      const int dy = k / 3 - 1, dx = k - (k / 3) * 3 - 1;
      const int ii0 = (lr >> 3) + dy + 1;
      const int jj0 = (lr & 7) + dx + 1;
      const size_t slab = ((size_t)(cc * 9 + k) * NJ) * 2 + ojb2;
      short8 bv[2][4], av[2][4];
      #pragma unroll
      for (int ni = 0; ni < 4; ++ni)
        #pragma unroll
        for (int ks = 0; ks < 2; ++ks)
          bv[ks][ni] = *(const short8*)&W2[(slab + ni * 2 + ks) * 512 + lane * 8];
      #pragma unroll
      for (int ks = 0; ks < 2; ++ks)
        #pragma unroll
        for (int mi = 0; mi < 4; ++mi)
          av[ks][mi] = *(const short8*)&xb[((ii0 + mi * 2) * 10 + jj0) * 72 + ks * 32 + lg * 8];
      #pragma unroll
      for (int ks = 0; ks < 2; ++ks)
        #pragma unroll
        for (int mi = 0; mi < 4; ++mi)
          #pragma unroll
          for (int ni = 0; ni < 4; ++ni)
            acc[mi][ni] = __builtin_amdgcn_mfma_f32_16x16x32_bf16(
                av[ks][mi], bv[ks][ni], acc[mi][ni], 0, 0, 0);
    }
    if (cc < 7) STAGE_WRITE(cur ^ 1);
    __syncthreads();
  }
  #undef STAGE_LOAD
  #undef STAGE_WRITE

  #pragma unroll
  for (int ni = 0; ni < 4; ++ni) {
    const int o = o0 + wv * 64 + ni * 16 + lr;
    const float bvs = bias[o];
    float sc = 1.f;
    if constexpr (RMSOUT) {
      float ssq = 0.f;
      #pragma unroll
      for (int mi = 0; mi < 4; ++mi)
        #pragma unroll
        for (int r = 0; r < 4; ++r) {
          float v = acc[mi][ni][r] + bvs;
          ssq += v * v;
        }
      ssq += __shfl_xor(ssq, 16);
      ssq += __shfl_xor(ssq, 32);
      sc = nw[0] * rsqrtf(ssq * (1.f / 64.f) + 1e-6f);
    }
    #pragma unroll
    for (int mi = 0; mi < 4; ++mi) {
      size_t idx = ((size_t)b * COUT + o) * 64 + mi * 16 + lg * 4;
      f32x4 v;
      #pragma unroll
      for (int r = 0; r < 4; ++r) v[r] = (acc[mi][ni][r] + bvs) * sc;
      if constexpr (RESADD) v += *(const f32x4*)&res[idx];
      *(f32x4*)&out[idx] = v;
    }
  }
}

// ---------------------------------------------------------------------------
// Final VALID 8x8 conv: out[b] = sum_{c,p} lrelu(F1[b,c,p]) * w[c,p] + bias.
// ---------------------------------------------------------------------------
__global__ __launch_bounds__(256) void co2_kernel(
    const float* __restrict__ xf, const float* __restrict__ w,
    const float* __restrict__ cb, float* __restrict__ out)
{
  const int b = blockIdx.x, tid = threadIdx.x;
  const float* xb = xf + (size_t)b * 65536;
  float acc = 0.f;
  for (int i = tid; i < 65536; i += 256)
    acc += lrelu(xb[i]) * w[i];
  #pragma unroll
  for (int off = 32; off; off >>= 1) acc += __shfl_down(acc, off);
  __shared__ float red[4];
  if ((tid & 63) == 0) red[tid >> 6] = acc;
  __syncthreads();
  if (tid == 0) out[b] = red[0] + red[1] + red[2] + red[3] + cb[0];
}

// ---------------------------------------------------------------------------
extern "C" void kernel_launch(void* const* d_in, const int* in_sizes, int n_in,
                              void* d_out, int out_size, void* d_ws, size_t ws_size,
                              hipStream_t stream)
{
  const int*   fen        = (const int*)d_in[0];
  const int*   move       = (const int*)d_in[1];
  const float* rank_emb   = (const float*)d_in[2];
  const float* file_emb   = (const float*)d_in[3];
  const float* fen_emb    = (const float*)d_in[4];
  const float* move_emb   = (const float*)d_in[5];
  const float* abs_emb    = (const float*)d_in[6];
  const float* ln_w       = (const float*)d_in[7];
  const float* ln_b       = (const float*)d_in[8];
  const float* emb_qkv    = (const float*)d_in[9];
  const float* emb_norm_w = (const float*)d_in[10];
  const float* qkvw_in    = (const float*)d_in[11];
  const float* mha_norm_w = (const float*)d_in[12];
  const float* conv1_w    = (const float*)d_in[13];
  const float* conv1_b    = (const float*)d_in[14];
  const float* conv2_w    = (const float*)d_in[15];
  const float* conv2_b    = (const float*)d_in[16];
  const float* cb_norm_w  = (const float*)d_in[17];
  const float* out_norm_w = (const float*)d_in[18];
  const float* co1_w      = (const float*)d_in[19];
  const float* co1_b      = (const float*)d_in[20];
  const float* co2_w      = (const float*)d_in[21];
  const float* co2_b      = (const float*)d_in[22];
  float* out = (float*)d_out;

  char* base = (char*)d_ws;
  __hip_bfloat16* X71 = (__hip_bfloat16*)base;                       // 18,612,224 B
  float* X64 = (float*)(base + 18612224);                            // 33,554,432 B
  float* T1  = (float*)(base + 18612224 + 33554432);                 // 67,108,864 B
  __hip_bfloat16* Wq = (__hip_bfloat16*)(base + 18612224 + 33554432 + 67108864);
  // attn intermediates alias T1 (dead during conv phases and vice versa):
  __hip_bfloat16* qk2 = (__hip_bfloat16*)T1;                         // <=37,224,448 B
  __hip_bfloat16* vTb = (__hip_bfloat16*)((char*)T1 + 37224448);     // <=20,971,520 B
  float* F1 = T1;                                                    // co1 out, 67MB
  // conv weight slabs alias X71 region (dead after embedding attn):
  __hip_bfloat16* WcA = (__hip_bfloat16*)base;                 // up to 9,437,184 B (co1)
  __hip_bfloat16* WcB = (__hip_bfloat16*)(base + 4718592);     // 4,718,592 B

  // one-time QKV weight repack (9 layers)
  repack_qkv_w<<<27648, 256, 0, stream>>>(emb_qkv, qkvw_in, Wq);

  // embeddings + layernorm -> X71 (bf16)
  build_ln_kernel<<<512, 256, 0, stream>>>(fen, move, rank_emb, file_emb,
                                           fen_emb, move_emb, abs_emb,
                                           ln_w, ln_b, X71);
  // embedding MHA (T=71): proj(+RMS) -> attn2 (residual = X71[:, :, :64])
  proj_kernel<71, 80, true><<<1536, 256, 0, stream>>>(X71, Wq, emb_norm_w, qk2, vTb);
  attn2_kernel<71, true><<<2048, 256, 0, stream>>>(qk2, vTb, X71, X64);

  for (int l = 0; l < 8; ++l) {
    repack_conv_w2<<<128, 256, 0, stream>>>(conv1_w + (size_t)l * 512 * 512 * 9,
                                            WcA, 512);
    conv_mfma2<true, false><<<512, 256, 0, stream>>>(X64, WcA, conv1_b + l * 512,
                                                     cb_norm_w + l, nullptr, T1, 512);
    repack_conv_w2<<<128, 256, 0, stream>>>(conv2_w + (size_t)l * 512 * 512 * 9,
                                            WcB, 512);
    conv_mfma2<false, true><<<512, 256, 0, stream>>>(T1, WcB, conv2_b + l * 512,
                                                     nullptr, X64, X64, 512);
    // MHA (T=64)
    proj_kernel<64, 64, false><<<1536, 256, 0, stream>>>(
        X64, Wq + (size_t)(l + 1) * 1536 * 512, mha_norm_w + l, qk2, vTb);
    attn2_kernel<64, false><<<2048, 256, 0, stream>>>(qk2, vTb, X64, X64);
  }

  // head: co1 (512->1024 SAME, RMS fused) -> co2 (VALID 8x8 -> scalar)
  repack_conv_w2<<<256, 256, 0, stream>>>(co1_w, WcA, 1024);
  conv_mfma2<true, false><<<1024, 256, 0, stream>>>(X64, WcA, co1_b,
                                                    out_norm_w, nullptr, F1, 1024);
  co2_kernel<<<256, 256, 0, stream>>>(F1, co2_w, co2_b, out);
}

// Round 9
// 2694.572 us; speedup vs baseline: 25.6246x; 1.0728x over previous
//
#include <hip/hip_runtime.h>
#include <hip/hip_bf16.h>
#include <cstdint>
#include <cstddef>

// Net: B=256, D=512, L=8, H=8, T=71->64, DH=64.
// Round 9: proj (T=64 path) rebuilt on the validated conv_mfma2 skeleton —
// weights stream global->VGPR as pre-swizzled fragment slabs (no weight LDS,
// 1 barrier per K-chunk), activations double-buffered in LDS. T=71 embedding
// proj keeps the round-8 kernel (runs once).
// ws layout (bytes), total 133,431,296 (unchanged):
//   X71  bf16 @ 0          18,612,224   (embeds; region reused as WcA/WcB after)
//   X64  f32  @ 18,612,224 33,554,432   (residual stream)
//   T1   f32  @ 52,166,656 67,108,864   (conv tmp | qk2 37.2MB + vT 21MB | F1)
//   Wq0  bf16 @119,275,520  1,572,864   (layer-0 QKV weights, [j][d] layout)
//   Wq2  bf16 @120,848,384 12,582,912   (layers 1..8, fragment-slab layout)

typedef float f32x4 __attribute__((ext_vector_type(4)));
typedef short short8 __attribute__((ext_vector_type(8)));

__device__ __forceinline__ float lrelu(float v) { return v > 0.f ? v : 0.2f * v; }
__device__ __forceinline__ __hip_bfloat16 tobf(float v) { return __float2bfloat16(v); }
__device__ __forceinline__ float frombf(__hip_bfloat16 v) { return __bfloat162float(v); }

// ---------------------------------------------------------------------------
// Layer-0 QKV weight repack: emb_qkv (3,8,512,64) f32 -> Wq0[j][d] bf16.
// ---------------------------------------------------------------------------
__global__ __launch_bounds__(256) void repack_qkv_w0(
    const float* __restrict__ emb_qkv, __hip_bfloat16* __restrict__ Wq0)
{
  int o = blockIdx.x * 256 + threadIdx.x;        // < 1536*512
  int j = o >> 9, d = o & 511;
  int n = j >> 9, h = (j >> 6) & 7, dh = j & 63;
  Wq0[o] = tobf(emb_qkv[(((n * 8 + h) * 512 + d) << 6) + dh]);
}

// ---------------------------------------------------------------------------
// Layers 1..8 QKV weight repack into MFMA fragment slabs:
//   Wq2[((((L*8+kc)*2+ks)*96 + nj)*64 + lane)*8 + e] = w[j][d]
//   j = nj*16 + (lane&15), d = kc*64 + ks*32 + (lane>>4)*8 + e.
// One thread per slab-lane (writes one uint4).
// ---------------------------------------------------------------------------
__global__ __launch_bounds__(256) void repack_qkv_w2(
    const float* __restrict__ qkvw, __hip_bfloat16* __restrict__ Wq2)
{
  const int t = blockIdx.x * 256 + threadIdx.x;   // < 8*8*2*96*64 = 786432
  const int lane = t & 63;
  const int nj = (t >> 6) % 96;
  int rest = (t >> 6) / 96;
  const int ks = rest & 1;
  const int kc = (rest >> 1) & 7;
  const int L = rest >> 4;                        // layer index 0..7 (net layer l)
  const int j = nj * 16 + (lane & 15);
  const int d0 = kc * 64 + ks * 32 + (lane >> 4) * 8;
  const int n = j >> 9, h = (j >> 6) & 7, dh = j & 63;
  const float* src = qkvw + ((((size_t)L * 3 + n) * 8 + h) * 512 + d0) * 64 + dh;
  __hip_bfloat16 tmp[8];
  #pragma unroll
  for (int e = 0; e < 8; ++e) tmp[e] = tobf(src[(size_t)e * 64]);
  *(uint4*)&Wq2[(size_t)t * 8] = *(const uint4*)tmp;
}

// ---------------------------------------------------------------------------
// Conv weight repack into fragment slabs (validated round 7).
// ---------------------------------------------------------------------------
__global__ __launch_bounds__(256) void repack_conv_w2(
    const float* __restrict__ w, __hip_bfloat16* __restrict__ W2, int COUT)
{
  const int t = blockIdx.x * 256 + threadIdx.x;   // < COUT*64
  if (t >= (COUT << 6)) return;
  const int lr = t & 15;
  const int cbg = (t >> 4) & 63;
  const int oj = t >> 10;
  const int cc = cbg >> 3, ks = (cbg >> 2) & 1, lg = cbg & 3;
  const int o = oj * 16 + lr;
  const int NJ = COUT >> 4;
  const float* src = w + ((size_t)o * 512 + cbg * 8) * 9;  // 72 consecutive f32
  #pragma unroll
  for (int k = 0; k < 9; ++k) {
    __hip_bfloat16 tmp[8];
    #pragma unroll
    for (int e = 0; e < 8; ++e) tmp[e] = tobf(src[e * 9 + k]);
    size_t di = ((((size_t)cc * 9 + k) * NJ + oj) * 2 + ks) * 512 + (lg * 16 + lr) * 8;
    *(uint4*)&W2[di] = *(const uint4*)tmp;
  }
}

// ---------------------------------------------------------------------------
// Stage 1: embeddings + LayerNorm over T=71 -> X71 bf16 (validated).
// ---------------------------------------------------------------------------
__global__ __launch_bounds__(256) void build_ln_kernel(
    const int* __restrict__ fen, const int* __restrict__ move,
    const float* __restrict__ rank_emb, const float* __restrict__ file_emb,
    const float* __restrict__ fen_emb, const float* __restrict__ move_emb,
    const float* __restrict__ abs_emb, const float* __restrict__ lnw,
    const float* __restrict__ lnb, __hip_bfloat16* __restrict__ X71)
{
  const int gid = blockIdx.x * 256 + threadIdx.x;   // < 256*512
  const int b = gid >> 9, d = gid & 511;
  const int* fb = fen + b * 133;

  float sum = 0.f, sq = 0.f, mu = 0.f, rstd = 0.f;
  #pragma unroll 1
  for (int pass = 0; pass < 2; ++pass) {
    if (pass) {
      mu = sum * (1.f / 71.f);
      float var = sq * (1.f / 71.f) - mu * mu;
      rstd = rsqrtf(var + 1e-5f);
    }
    #pragma unroll 1
    for (int t = 0; t < 71; ++t) {
      float a = abs_emb[t * 512 + d];
      float v;
      if (t < 64) {
        float pos = rank_emb[(t >> 3) * 512 + d] + file_emb[(t & 7) * 512 + d];
        v = 0.5f * (fen_emb[fb[t] * 512 + d] + fen_emb[fb[64 + t] * 512 + d] + pos) + a;
      } else if (t < 69) {
        v = fen_emb[fb[t + 64] * 512 + d] + a;
      } else {
        int j = t - 69;
        int s = move[b * 2 + j];
        float pos = rank_emb[(s >> 3) * 512 + d] + file_emb[(s & 7) * 512 + d];
        v = (pos + move_emb[j * 512 + d]) * 0.58f + a;
      }
      if (pass) X71[(size_t)gid * 71 + t] = tobf((v - mu) * rstd * lnw[t] + lnb[t]);
      else { sum += v; sq += v * v; }
    }
  }
}

// ---------------------------------------------------------------------------
// T=71 embedding QKV projection + fused token-axis RMS (round 8, validated).
// Runs once per forward; uses Wq0 [j][d] layout.
// ---------------------------------------------------------------------------
template <int T, int TP>
__global__ __launch_bounds__(256) void proj71_kernel(
    const __hip_bfloat16* __restrict__ xin, const __hip_bfloat16* __restrict__ Wq,
    const float* __restrict__ nw,
    __hip_bfloat16* __restrict__ qk, __hip_bfloat16* __restrict__ vT)
{
  const int b  = blockIdx.x / 6;
  const int jb = (blockIdx.x % 6) * 256;
  const int tid = threadIdx.x;
  const int lane = tid & 63, wv = tid >> 6;
  const int lr = lane & 15, lg = lane >> 4;

  __shared__ __hip_bfloat16 xt[TP * 72];
  __shared__ __hip_bfloat16 wl[256 * 72];

  constexpr int MI = TP / 16;
  f32x4 acc[MI][4];
  #pragma unroll
  for (int mi = 0; mi < MI; ++mi)
    #pragma unroll
    for (int ni = 0; ni < 4; ++ni) acc[mi][ni] = {0.f, 0.f, 0.f, 0.f};

  for (int c0 = 0; c0 < 512; c0 += 64) {
    for (int i = tid; i < 64 * TP; i += 256) {
      int d = i / TP, t = i - d * TP;
      float v = (t < T) ? lrelu(frombf(xin[((size_t)(b * 512 + c0 + d)) * T + t])) : 0.f;
      xt[t * 72 + d] = tobf(v);
    }
    for (int i = tid; i < 2048; i += 256) {
      int j = i >> 3, cb = i & 7;
      *(uint4*)&wl[j * 72 + cb * 8] =
          *(const uint4*)&Wq[(size_t)(jb + j) * 512 + c0 + cb * 8];
    }
    __syncthreads();
    #pragma unroll
    for (int ks = 0; ks < 2; ++ks) {
      short8 a[MI], bb[4];
      #pragma unroll
      for (int mi = 0; mi < MI; ++mi)
        a[mi] = *(const short8*)&xt[(mi * 16 + lr) * 72 + ks * 32 + lg * 8];
      #pragma unroll
      for (int ni = 0; ni < 4; ++ni)
        bb[ni] = *(const short8*)&wl[(wv * 64 + ni * 16 + lr) * 72 + ks * 32 + lg * 8];
      #pragma unroll
      for (int mi = 0; mi < MI; ++mi)
        #pragma unroll
        for (int ni = 0; ni < 4; ++ni)
          acc[mi][ni] = __builtin_amdgcn_mfma_f32_16x16x32_bf16(
              a[mi], bb[ni], acc[mi][ni], 0, 0, 0);
    }
    __syncthreads();
  }

  #pragma unroll
  for (int ni = 0; ni < 4; ++ni) {
    const int j = jb + wv * 64 + ni * 16 + lr;
    float ss = 0.f;
    #pragma unroll
    for (int mi = 0; mi < MI; ++mi)
      #pragma unroll
      for (int r = 0; r < 4; ++r) ss += acc[mi][ni][r] * acc[mi][ni][r];
    ss += __shfl_xor(ss, 16);
    ss += __shfl_xor(ss, 32);
    const float sc = nw[0] * rsqrtf(ss * (1.f / T) + 1e-6f);
    if (j < 1024) {
      #pragma unroll
      for (int mi = 0; mi < MI; ++mi)
        #pragma unroll
        for (int r = 0; r < 4; ++r) {
          int t = mi * 16 + lg * 4 + r;
          if (t < T)
            qk[((size_t)b * T + t) * 1024 + j] = tobf(acc[mi][ni][r] * sc);
        }
    } else {
      const int jj = j - 1024;
      #pragma unroll
      for (int mi = 0; mi < MI; ++mi)
        #pragma unroll
        for (int r = 0; r < 4; ++r) {
          int t = mi * 16 + lg * 4 + r;   // rows t>=T are true zeros -> valid pad
          vT[((size_t)b * 512 + jj) * TP + t] = tobf(acc[mi][ni][r] * sc);
        }
    }
  }
}

// ---------------------------------------------------------------------------
// T=64 QKV projection, conv_mfma2-style: weights direct global->VGPR from
// fragment slabs; LDS = double-buffered 64x72 transposed activation tile;
// 1 barrier per K-chunk. Fused token-axis RMS epilogue (validated round 8).
// ---------------------------------------------------------------------------
__global__ __launch_bounds__(256) void proj64_kernel(
    const float* __restrict__ x,            // (B,512,64) f32
    const __hip_bfloat16* __restrict__ Wq2, // fragment slabs for this layer
    const float* __restrict__ nw,
    __hip_bfloat16* __restrict__ qk, __hip_bfloat16* __restrict__ vT)
{
  const int b    = blockIdx.x / 6;
  const int jseg = blockIdx.x % 6;
  const int tid = threadIdx.x;
  const int lane = tid & 63, wv = tid >> 6;
  const int lr = lane & 15, lg = lane >> 4;

  __shared__ __hip_bfloat16 xt[2][64 * 72];

  f32x4 acc[4][4];
  #pragma unroll
  for (int mi = 0; mi < 4; ++mi)
    #pragma unroll
    for (int ni = 0; ni < 4; ++ni) acc[mi][ni] = {0.f, 0.f, 0.f, 0.f};

  f32x4 sreg[4];
  const int s_d  = tid >> 4;           // d within chunk (+u*16)
  const int s_t4 = (tid & 15) << 2;    // 4 consecutive tokens

  #define PSTAGE_LOAD(kc_)                                                    \
    {                                                                         \
      const float* xb_ = x + ((size_t)b * 512 + (kc_) * 64 + s_d) * 64 + s_t4; \
      _Pragma("unroll")                                                       \
      for (int u = 0; u < 4; ++u) sreg[u] = *(const f32x4*)&xb_[u * 1024];    \
    }
  #define PSTAGE_WRITE(buf_)                                                  \
    {                                                                         \
      _Pragma("unroll")                                                       \
      for (int u = 0; u < 4; ++u) {                                           \
        _Pragma("unroll")                                                     \
        for (int j = 0; j < 4; ++j)                                           \
          xt[buf_][(s_t4 + j) * 72 + s_d + u * 16] = tobf(lrelu(sreg[u][j])); \
      }                                                                       \
    }

  PSTAGE_LOAD(0);
  PSTAGE_WRITE(0);
  __syncthreads();

  const int njb0 = jseg * 16 + wv * 4;

  for (int kc = 0; kc < 8; ++kc) {
    const int cur = kc & 1;
    if (kc < 7) PSTAGE_LOAD(kc + 1);
    const __hip_bfloat16* xb = xt[cur];
    #pragma unroll
    for (int ks = 0; ks < 2; ++ks) {
      short8 bv[4], av[4];
      #pragma unroll
      for (int ni = 0; ni < 4; ++ni)
        bv[ni] = *(const short8*)
            &Wq2[((((size_t)kc * 2 + ks) * 96) + njb0 + ni) * 512 + lane * 8];
      #pragma unroll
      for (int mi = 0; mi < 4; ++mi)
        av[mi] = *(const short8*)&xb[(mi * 16 + lr) * 72 + ks * 32 + lg * 8];
      #pragma unroll
      for (int mi = 0; mi < 4; ++mi)
        #pragma unroll
        for (int ni = 0; ni < 4; ++ni)
          acc[mi][ni] = __builtin_amdgcn_mfma_f32_16x16x32_bf16(
              av[mi], bv[ni], acc[mi][ni], 0, 0, 0);
    }
    if (kc < 7) PSTAGE_WRITE(cur ^ 1);
    __syncthreads();
  }
  #undef PSTAGE_LOAD
  #undef PSTAGE_WRITE

  // epilogue: per-column RMS over token axis, then Q/K or V^T writes.
  #pragma unroll
  for (int ni = 0; ni < 4; ++ni) {
    const int j = jseg * 256 + wv * 64 + ni * 16 + lr;
    float ss = 0.f;
    #pragma unroll
    for (int mi = 0; mi < 4; ++mi)
      #pragma unroll
      for (int r = 0; r < 4; ++r) ss += acc[mi][ni][r] * acc[mi][ni][r];
    ss += __shfl_xor(ss, 16);
    ss += __shfl_xor(ss, 32);
    const float sc = nw[0] * rsqrtf(ss * (1.f / 64.f) + 1e-6f);
    if (j < 1024) {
      #pragma unroll
      for (int mi = 0; mi < 4; ++mi)
        #pragma unroll
        for (int r = 0; r < 4; ++r) {
          int t = mi * 16 + lg * 4 + r;
          qk[((size_t)b * 64 + t) * 1024 + j] = tobf(acc[mi][ni][r] * sc);
        }
    } else {
      const int jj = j - 1024;
      #pragma unroll
      for (int mi = 0; mi < 4; ++mi)
        #pragma unroll
        for (int r = 0; r < 4; ++r) {
          int t = mi * 16 + lg * 4 + r;
          vT[((size_t)b * 512 + jj) * 64 + t] = tobf(acc[mi][ni][r] * sc);
        }
    }
  }
}

// ---------------------------------------------------------------------------
// MFMA attention per (b,h): S = Q·K^T/8 -> softmax -> O = P·V (+residual).
// Validated round 8.
// ---------------------------------------------------------------------------
template <int T, bool RESBF>
__global__ __launch_bounds__(256) void attn2_kernel(
    const __hip_bfloat16* __restrict__ qk,   // [b][t][1024] RMS'd Q|K
    const __hip_bfloat16* __restrict__ vT,   // [b][jj][TP]  RMS'd V^T
    const void* __restrict__ res, float* __restrict__ out)
{
  constexpr int TP = (T == 71) ? 80 : 64;    // vT global row stride
  constexpr int TK = (T + 31) / 32;          // PV K steps (2 or 3)
  constexpr int RS = 72;                     // q/k LDS row stride (bf16)
  constexpr int PS = TK * 32 + 8;            // vt/plds LDS row stride (72/104)
  constexpr int KR = (T == 71) ? 80 : 64;    // k LDS rows (key frag coverage)
  constexpr int SC = (T == 71) ? 82 : 66;    // slds f32 row stride
  constexpr int NCF = KR / 16;               // S col frags (5 or 4)
  constexpr int NFW = (NCF + 3) / 4;         // col frags per wave
  constexpr int RANGE = (TK * 32) / 4;       // softmax cols per thread (16/24)

  constexpr int Q_OFF = 0;
  constexpr int K_OFF = Q_OFF + 64 * RS * 2;
  constexpr int V_OFF = K_OFF + KR * RS * 2;
  constexpr int S_OFF = V_OFF + 64 * PS * 2;
  constexpr int BYTES = S_OFF + 64 * SC * 4;
  __shared__ __align__(16) char smem[BYTES];
  __hip_bfloat16* qs = (__hip_bfloat16*)(smem + Q_OFF);
  __hip_bfloat16* ksh = (__hip_bfloat16*)(smem + K_OFF);
  __hip_bfloat16* vs = (__hip_bfloat16*)(smem + V_OFF);
  float* ss = (float*)(smem + S_OFF);
  __hip_bfloat16* ps = (__hip_bfloat16*)(smem + S_OFF);   // alias (two-pass)

  const int b = blockIdx.x >> 3, h = blockIdx.x & 7;
  const int tid = threadIdx.x;
  const int lane = tid & 63, wv = tid >> 6;
  const int lr = lane & 15, lg = lane >> 4;

  for (int i = tid; i < BYTES / 16; i += 256) ((uint4*)smem)[i] = uint4{0, 0, 0, 0};
  __syncthreads();

  const __hip_bfloat16* qb = qk + (size_t)b * T * 1024 + h * 64;
  for (int v = tid; v < 512; v += 256) {
    int t = v >> 3, d0 = (v & 7) * 8;
    *(uint4*)&qs[t * RS + d0] = *(const uint4*)&qb[(size_t)t * 1024 + d0];
  }
  for (int v = tid; v < T * 8; v += 256) {
    int t = v >> 3, d0 = (v & 7) * 8;
    *(uint4*)&ksh[t * RS + d0] = *(const uint4*)&qb[(size_t)t * 1024 + 512 + d0];
  }
  constexpr int VV = TP / 8;
  for (int v = tid; v < 64 * VV; v += 256) {
    int dh = v / VV, tc = (v - dh * VV) * 8;
    *(uint4*)&vs[dh * PS + tc] =
        *(const uint4*)&vT[((size_t)b * 512 + h * 64 + dh) * TP + tc];
  }
  __syncthreads();

  // S = Q.K^T * 0.125
  f32x4 sacc[NFW][4];
  #pragma unroll
  for (int fi = 0; fi < NFW; ++fi)
    #pragma unroll
    for (int mi = 0; mi < 4; ++mi) sacc[fi][mi] = {0.f, 0.f, 0.f, 0.f};
  #pragma unroll
  for (int ks2 = 0; ks2 < 2; ++ks2) {
    short8 a[4];
    #pragma unroll
    for (int mi = 0; mi < 4; ++mi)
      a[mi] = *(const short8*)&qs[(mi * 16 + lr) * RS + ks2 * 32 + lg * 8];
    #pragma unroll
    for (int fi = 0; fi < NFW; ++fi) {
      const int f = wv + fi * 4;
      if (f < NCF) {
        short8 bb = *(const short8*)&ksh[(f * 16 + lr) * RS + ks2 * 32 + lg * 8];
        #pragma unroll
        for (int mi = 0; mi < 4; ++mi)
          sacc[fi][mi] = __builtin_amdgcn_mfma_f32_16x16x32_bf16(
              a[mi], bb, sacc[fi][mi], 0, 0, 0);
      }
    }
  }
  #pragma unroll
  for (int fi = 0; fi < NFW; ++fi) {
    const int f = wv + fi * 4;
    if (f < NCF) {
      #pragma unroll
      for (int mi = 0; mi < 4; ++mi)
        #pragma unroll
        for (int r = 0; r < 4; ++r)
          ss[(mi * 16 + lg * 4 + r) * SC + f * 16 + lr] = sacc[fi][mi][r] * 0.125f;
    }
  }
  __syncthreads();

  // softmax: 4 threads per row; pass 1 read+reduce, pass 2 write P (bf16).
  {
    const int row = tid >> 2, q4 = tid & 3;
    float sv[RANGE];
    float mx = -3.0e38f;
    #pragma unroll
    for (int i = 0; i < RANGE; ++i) {
      int c = q4 * RANGE + i;
      sv[i] = (c < T) ? ss[row * SC + c] : -3.0e38f;
      mx = fmaxf(mx, sv[i]);
    }
    mx = fmaxf(mx, __shfl_xor(mx, 1));
    mx = fmaxf(mx, __shfl_xor(mx, 2));
    float sm = 0.f;
    #pragma unroll
    for (int i = 0; i < RANGE; ++i) {
      int c = q4 * RANGE + i;
      sv[i] = (c < T) ? __expf(sv[i] - mx) : 0.f;
      sm += sv[i];
    }
    sm += __shfl_xor(sm, 1);
    sm += __shfl_xor(sm, 2);
    const float inv = 1.f / sm;
    __syncthreads();   // all S reads complete before P overwrites the region
    #pragma unroll
    for (int i = 0; i < RANGE; ++i)
      ps[row * PS + q4 * RANGE + i] = tobf(sv[i] * inv);
  }
  __syncthreads();

  // O = P.V
  f32x4 oacc[4];
  #pragma unroll
  for (int mi = 0; mi < 4; ++mi) oacc[mi] = {0.f, 0.f, 0.f, 0.f};
  #pragma unroll
  for (int ks2 = 0; ks2 < TK; ++ks2) {
    short8 bb = *(const short8*)&vs[(wv * 16 + lr) * PS + ks2 * 32 + lg * 8];
    #pragma unroll
    for (int mi = 0; mi < 4; ++mi) {
      short8 a = *(const short8*)&ps[(mi * 16 + lr) * PS + ks2 * 32 + lg * 8];
      oacc[mi] = __builtin_amdgcn_mfma_f32_16x16x32_bf16(a, bb, oacc[mi], 0, 0, 0);
    }
  }

  const int dh = wv * 16 + lr;
  const size_t chb = (size_t)b * 512 + h * 64 + dh;
  #pragma unroll
  for (int mi = 0; mi < 4; ++mi) {
    const int t0 = mi * 16 + lg * 4;
    const size_t idx = chb * 64 + t0;
    f32x4 v = oacc[mi];
    if constexpr (RESBF) {
      const __hip_bfloat16* rb = (const __hip_bfloat16*)res + chb * T + t0;
      #pragma unroll
      for (int r = 0; r < 4; ++r) v[r] += frombf(rb[r]);
    } else {
      v += *(const f32x4*)&((const float*)res)[idx];
    }
    *(f32x4*)&out[idx] = v;
  }
}

// ---------------------------------------------------------------------------
// MFMA conv 3x3 SAME on 8x8, CIN=512, weights direct global->VGPR (validated
// round 7). One barrier per cc; LDS = double-buffered 10x10 activation board.
// ---------------------------------------------------------------------------
template <bool RMSOUT, bool RESADD>
__global__ __launch_bounds__(256) void conv_mfma2(
    const float* __restrict__ x,            // (B,512,64) f32
    const __hip_bfloat16* __restrict__ W2,  // fragment slabs (see repack)
    const float* __restrict__ bias,         // (COUT)
    const float* __restrict__ nw,           // scalar rms weight (RMSOUT)
    const float* __restrict__ res,          // (B,COUT,64) f32 (RESADD)
    float* __restrict__ out,                // (B,COUT,64) f32
    int COUT)
{
  const int ntc = COUT >> 8;
  const int b = blockIdx.x / ntc;
  const int nt = blockIdx.x - b * ntc;
  const int o0 = nt << 8;
  const int NJ = COUT >> 4;
  const int tid = threadIdx.x;
  const int lane = tid & 63, wv = tid >> 6;
  const int lr = lane & 15, lg = lane >> 4;

  __shared__ __hip_bfloat16 xt[2][100 * 72];  // 10x10 zero-bordered boards

  f32x4 acc[4][4];
  #pragma unroll
  for (int mi = 0; mi < 4; ++mi)
    #pragma unroll
    for (int ni = 0; ni < 4; ++ni) acc[mi][ni] = {0.f, 0.f, 0.f, 0.f};

  for (int i = tid; i < 7200; i += 256) { xt[0][i] = tobf(0.f); xt[1][i] = tobf(0.f); }

  f32x4 sreg[4];
  const int s_ci = tid >> 4;
  const int s_p4 = (tid & 15) << 2;
  const int s_row = (((s_p4 >> 3) + 1) * 10 + (s_p4 & 7) + 1) * 72;

  #define STAGE_LOAD(cc_)                                                     \
    {                                                                         \
      const float* xb_ = x + ((size_t)b * 512 + (cc_) * 64 + s_ci) * 64 + s_p4; \
      _Pragma("unroll")                                                       \
      for (int u = 0; u < 4; ++u) sreg[u] = *(const f32x4*)&xb_[u * 1024];    \
    }
  #define STAGE_WRITE(buf_)                                                   \
    {                                                                         \
      _Pragma("unroll")                                                       \
      for (int u = 0; u < 4; ++u) {                                           \
        _Pragma("unroll")                                                     \
        for (int j = 0; j < 4; ++j)                                           \
          xt[buf_][s_row + j * 72 + s_ci + u * 16] = tobf(lrelu(sreg[u][j])); \
      }                                                                       \
    }

  STAGE_LOAD(0);
  __syncthreads();
  STAGE_WRITE(0);
  __syncthreads();

  const int ojb2 = ((o0 >> 4) + wv * 4) * 2;

  for (int cc = 0; cc < 8; ++cc) {
    const int cur = cc & 1;
    if (cc < 7) STAGE_LOAD(cc + 1);
    const __hip_bfloat16* xb = xt[cur];

    #pragma unroll
    for (int k = 0; k < 9; ++k) {
      const int dy = k / 3 - 1, dx = k - (k / 3) * 3 - 1;
      const int ii0 = (lr >> 3) + dy + 1;
      const int jj0 = (lr & 7) + dx + 1;
      const size_t slab = ((size_t)(cc * 9 + k) * NJ) * 2 + ojb2;
      short8 bv[2][4], av[2][4];
      #pragma unroll
      for (int ni = 0; ni < 4; ++ni)
        #pragma unroll
        for (int ks = 0; ks < 2; ++ks)
          bv[ks][ni] = *(const short8*)&W2[(slab + ni * 2 + ks) * 512 + lane * 8];
      #pragma unroll
      for (int ks = 0; ks < 2; ++ks)
        #pragma unroll
        for (int mi = 0; mi < 4; ++mi)
          av[ks][mi] = *(const short8*)&xb[((ii0 + mi * 2) * 10 + jj0) * 72 + ks * 32 + lg * 8];
      #pragma unroll
      for (int ks = 0; ks < 2; ++ks)
        #pragma unroll
        for (int mi = 0; mi < 4; ++mi)
          #pragma unroll
          for (int ni = 0; ni < 4; ++ni)
            acc[mi][ni] = __builtin_amdgcn_mfma_f32_16x16x32_bf16(
                av[ks][mi], bv[ks][ni], acc[mi][ni], 0, 0, 0);
    }
    if (cc < 7) STAGE_WRITE(cur ^ 1);
    __syncthreads();
  }
  #undef STAGE_LOAD
  #undef STAGE_WRITE

  #pragma unroll
  for (int ni = 0; ni < 4; ++ni) {
    const int o = o0 + wv * 64 + ni * 16 + lr;
    const float bvs = bias[o];
    float sc = 1.f;
    if constexpr (RMSOUT) {
      float ssq = 0.f;
      #pragma unroll
      for (int mi = 0; mi < 4; ++mi)
        #pragma unroll
        for (int r = 0; r < 4; ++r) {
          float v = acc[mi][ni][r] + bvs;
          ssq += v * v;
        }
      ssq += __shfl_xor(ssq, 16);
      ssq += __shfl_xor(ssq, 32);
      sc = nw[0] * rsqrtf(ssq * (1.f / 64.f) + 1e-6f);
    }
    #pragma unroll
    for (int mi = 0; mi < 4; ++mi) {
      size_t idx = ((size_t)b * COUT + o) * 64 + mi * 16 + lg * 4;
      f32x4 v;
      #pragma unroll
      for (int r = 0; r < 4; ++r) v[r] = (acc[mi][ni][r] + bvs) * sc;
      if constexpr (RESADD) v += *(const f32x4*)&res[idx];
      *(f32x4*)&out[idx] = v;
    }
  }
}

// ---------------------------------------------------------------------------
// Final VALID 8x8 conv: out[b] = sum_{c,p} lrelu(F1[b,c,p]) * w[c,p] + bias.
// ---------------------------------------------------------------------------
__global__ __launch_bounds__(256) void co2_kernel(
    const float* __restrict__ xf, const float* __restrict__ w,
    const float* __restrict__ cb, float* __restrict__ out)
{
  const int b = blockIdx.x, tid = threadIdx.x;
  const float* xb = xf + (size_t)b * 65536;
  float acc = 0.f;
  for (int i = tid; i < 65536; i += 256)
    acc += lrelu(xb[i]) * w[i];
  #pragma unroll
  for (int off = 32; off; off >>= 1) acc += __shfl_down(acc, off);
  __shared__ float red[4];
  if ((tid & 63) == 0) red[tid >> 6] = acc;
  __syncthreads();
  if (tid == 0) out[b] = red[0] + red[1] + red[2] + red[3] + cb[0];
}

// ---------------------------------------------------------------------------
extern "C" void kernel_launch(void* const* d_in, const int* in_sizes, int n_in,
                              void* d_out, int out_size, void* d_ws, size_t ws_size,
                              hipStream_t stream)
{
  const int*   fen        = (const int*)d_in[0];
  const int*   move       = (const int*)d_in[1];
  const float* rank_emb   = (const float*)d_in[2];
  const float* file_emb   = (const float*)d_in[3];
  const float* fen_emb    = (const float*)d_in[4];
  const float* move_emb   = (const float*)d_in[5];
  const float* abs_emb    = (const float*)d_in[6];
  const float* ln_w       = (const float*)d_in[7];
  const float* ln_b       = (const float*)d_in[8];
  const float* emb_qkv    = (const float*)d_in[9];
  const float* emb_norm_w = (const float*)d_in[10];
  const float* qkvw_in    = (const float*)d_in[11];
  const float* mha_norm_w = (const float*)d_in[12];
  const float* conv1_w    = (const float*)d_in[13];
  const float* conv1_b    = (const float*)d_in[14];
  const float* conv2_w    = (const float*)d_in[15];
  const float* conv2_b    = (const float*)d_in[16];
  const float* cb_norm_w  = (const float*)d_in[17];
  const float* out_norm_w = (const float*)d_in[18];
  const float* co1_w      = (const float*)d_in[19];
  const float* co1_b      = (const float*)d_in[20];
  const float* co2_w      = (const float*)d_in[21];
  const float* co2_b      = (const float*)d_in[22];
  float* out = (float*)d_out;

  char* base = (char*)d_ws;
  __hip_bfloat16* X71 = (__hip_bfloat16*)base;                       // 18,612,224 B
  float* X64 = (float*)(base + 18612224);                            // 33,554,432 B
  float* T1  = (float*)(base + 18612224 + 33554432);                 // 67,108,864 B
  __hip_bfloat16* Wq0 = (__hip_bfloat16*)(base + 119275520);         //  1,572,864 B
  __hip_bfloat16* Wq2 = (__hip_bfloat16*)(base + 120848384);         // 12,582,912 B
  // attn intermediates alias T1 (dead during conv phases and vice versa):
  __hip_bfloat16* qk2 = (__hip_bfloat16*)T1;                         // <=37,224,448 B
  __hip_bfloat16* vTb = (__hip_bfloat16*)((char*)T1 + 37224448);     // <=20,971,520 B
  float* F1 = T1;                                                    // co1 out, 67MB
  // conv weight slabs alias X71 region (dead after embedding attn):
  __hip_bfloat16* WcA = (__hip_bfloat16*)base;                 // up to 9,437,184 B (co1)
  __hip_bfloat16* WcB = (__hip_bfloat16*)(base + 4718592);     // 4,718,592 B

  // one-time QKV weight repacks
  repack_qkv_w0<<<3072, 256, 0, stream>>>(emb_qkv, Wq0);
  repack_qkv_w2<<<3072, 256, 0, stream>>>(qkvw_in, Wq2);

  // embeddings + layernorm -> X71 (bf16)
  build_ln_kernel<<<512, 256, 0, stream>>>(fen, move, rank_emb, file_emb,
                                           fen_emb, move_emb, abs_emb,
                                           ln_w, ln_b, X71);
  // embedding MHA (T=71): proj(+RMS) -> attn2 (residual = X71[:, :, :64])
  proj71_kernel<71, 80><<<1536, 256, 0, stream>>>(X71, Wq0, emb_norm_w, qk2, vTb);
  attn2_kernel<71, true><<<2048, 256, 0, stream>>>(qk2, vTb, X71, X64);

  for (int l = 0; l < 8; ++l) {
    repack_conv_w2<<<128, 256, 0, stream>>>(conv1_w + (size_t)l * 512 * 512 * 9,
                                            WcA, 512);
    conv_mfma2<true, false><<<512, 256, 0, stream>>>(X64, WcA, conv1_b + l * 512,
                                                     cb_norm_w + l, nullptr, T1, 512);
    repack_conv_w2<<<128, 256, 0, stream>>>(conv2_w + (size_t)l * 512 * 512 * 9,
                                            WcB, 512);
    conv_mfma2<false, true><<<512, 256, 0, stream>>>(T1, WcB, conv2_b + l * 512,
                                                     nullptr, X64, X64, 512);
    // MHA (T=64)
    proj64_kernel<<<1536, 256, 0, stream>>>(X64, Wq2 + (size_t)l * 786432,
                                            mha_norm_w + l, qk2, vTb);
    attn2_kernel<64, false><<<2048, 256, 0, stream>>>(qk2, vTb, X64, X64);
  }

  // head: co1 (512->1024 SAME, RMS fused) -> co2 (VALID 8x8 -> scalar)
  repack_conv_w2<<<256, 256, 0, stream>>>(co1_w, WcA, 1024);
  conv_mfma2<true, false><<<1024, 256, 0, stream>>>(X64, WcA, co1_b,
                                                    out_norm_w, nullptr, F1, 1024);
  co2_kernel<<<256, 256, 0, stream>>>(F1, co2_w, co2_b, out);
}

// Round 10
// 2686.148 us; speedup vs baseline: 25.7049x; 1.0031x over previous
//
#include <hip/hip_runtime.h>
#include <hip/hip_bf16.h>
#include <cstdint>
#include <cstddef>

// Net: B=256, D=512, L=8, H=8, T=71->64, DH=64.
// Round 9: proj (T=64 path) rebuilt on the validated conv_mfma2 skeleton —
// weights stream global->VGPR as pre-swizzled fragment slabs (no weight LDS,
// 1 barrier per K-chunk), activations double-buffered in LDS. T=71 embedding
// proj keeps the round-8 kernel (runs once).
// ws layout (bytes), total 133,431,296 (unchanged):
//   X71  bf16 @ 0          18,612,224   (embeds; region reused as WcA/WcB after)
//   X64  f32  @ 18,612,224 33,554,432   (residual stream)
//   T1   f32  @ 52,166,656 67,108,864   (conv tmp | qk2 37.2MB + vT 21MB | F1)
//   Wq0  bf16 @119,275,520  1,572,864   (layer-0 QKV weights, [j][d] layout)
//   Wq2  bf16 @120,848,384 12,582,912   (layers 1..8, fragment-slab layout)

typedef float f32x4 __attribute__((ext_vector_type(4)));
typedef short short8 __attribute__((ext_vector_type(8)));

__device__ __forceinline__ float lrelu(float v) { return v > 0.f ? v : 0.2f * v; }
__device__ __forceinline__ __hip_bfloat16 tobf(float v) { return __float2bfloat16(v); }
__device__ __forceinline__ float frombf(__hip_bfloat16 v) { return __bfloat162float(v); }

// ---------------------------------------------------------------------------
// Layer-0 QKV weight repack: emb_qkv (3,8,512,64) f32 -> Wq0[j][d] bf16.
// ---------------------------------------------------------------------------
__global__ __launch_bounds__(256) void repack_qkv_w0(
    const float* __restrict__ emb_qkv, __hip_bfloat16* __restrict__ Wq0)
{
  int o = blockIdx.x * 256 + threadIdx.x;        // < 1536*512
  int j = o >> 9, d = o & 511;
  int n = j >> 9, h = (j >> 6) & 7, dh = j & 63;
  Wq0[o] = tobf(emb_qkv[(((n * 8 + h) * 512 + d) << 6) + dh]);
}

// ---------------------------------------------------------------------------
// Layers 1..8 QKV weight repack into MFMA fragment slabs:
//   Wq2[((((L*8+kc)*2+ks)*96 + nj)*64 + lane)*8 + e] = w[j][d]
//   j = nj*16 + (lane&15), d = kc*64 + ks*32 + (lane>>4)*8 + e.
// One thread per slab-lane (writes one uint4).
// ---------------------------------------------------------------------------
__global__ __launch_bounds__(256) void repack_qkv_w2(
    const float* __restrict__ qkvw, __hip_bfloat16* __restrict__ Wq2)
{
  const int t = blockIdx.x * 256 + threadIdx.x;   // < 8*8*2*96*64 = 786432
  const int lane = t & 63;
  const int nj = (t >> 6) % 96;
  int rest = (t >> 6) / 96;
  const int ks = rest & 1;
  const int kc = (rest >> 1) & 7;
  const int L = rest >> 4;                        // layer index 0..7 (net layer l)
  const int j = nj * 16 + (lane & 15);
  const int d0 = kc * 64 + ks * 32 + (lane >> 4) * 8;
  const int n = j >> 9, h = (j >> 6) & 7, dh = j & 63;
  const float* src = qkvw + ((((size_t)L * 3 + n) * 8 + h) * 512 + d0) * 64 + dh;
  __hip_bfloat16 tmp[8];
  #pragma unroll
  for (int e = 0; e < 8; ++e) tmp[e] = tobf(src[(size_t)e * 64]);
  *(uint4*)&Wq2[(size_t)t * 8] = *(const uint4*)tmp;
}

// ---------------------------------------------------------------------------
// Conv weight repack into fragment slabs (validated round 7).
// ---------------------------------------------------------------------------
__global__ __launch_bounds__(256) void repack_conv_w2(
    const float* __restrict__ w, __hip_bfloat16* __restrict__ W2, int COUT)
{
  const int t = blockIdx.x * 256 + threadIdx.x;   // < COUT*64
  if (t >= (COUT << 6)) return;
  const int lr = t & 15;
  const int cbg = (t >> 4) & 63;
  const int oj = t >> 10;
  const int cc = cbg >> 3, ks = (cbg >> 2) & 1, lg = cbg & 3;
  const int o = oj * 16 + lr;
  const int NJ = COUT >> 4;
  const float* src = w + ((size_t)o * 512 + cbg * 8) * 9;  // 72 consecutive f32
  #pragma unroll
  for (int k = 0; k < 9; ++k) {
    __hip_bfloat16 tmp[8];
    #pragma unroll
    for (int e = 0; e < 8; ++e) tmp[e] = tobf(src[e * 9 + k]);
    size_t di = ((((size_t)cc * 9 + k) * NJ + oj) * 2 + ks) * 512 + (lg * 16 + lr) * 8;
    *(uint4*)&W2[di] = *(const uint4*)tmp;
  }
}

// ---------------------------------------------------------------------------
// Stage 1: embeddings + LayerNorm over T=71 -> X71 bf16 (validated).
// ---------------------------------------------------------------------------
__global__ __launch_bounds__(256) void build_ln_kernel(
    const int* __restrict__ fen, const int* __restrict__ move,
    const float* __restrict__ rank_emb, const float* __restrict__ file_emb,
    const float* __restrict__ fen_emb, const float* __restrict__ move_emb,
    const float* __restrict__ abs_emb, const float* __restrict__ lnw,
    const float* __restrict__ lnb, __hip_bfloat16* __restrict__ X71)
{
  const int gid = blockIdx.x * 256 + threadIdx.x;   // < 256*512
  const int b = gid >> 9, d = gid & 511;
  const int* fb = fen + b * 133;

  float sum = 0.f, sq = 0.f, mu = 0.f, rstd = 0.f;
  #pragma unroll 1
  for (int pass = 0; pass < 2; ++pass) {
    if (pass) {
      mu = sum * (1.f / 71.f);
      float var = sq * (1.f / 71.f) - mu * mu;
      rstd = rsqrtf(var + 1e-5f);
    }
    #pragma unroll 1
    for (int t = 0; t < 71; ++t) {
      float a = abs_emb[t * 512 + d];
      float v;
      if (t < 64) {
        float pos = rank_emb[(t >> 3) * 512 + d] + file_emb[(t & 7) * 512 + d];
        v = 0.5f * (fen_emb[fb[t] * 512 + d] + fen_emb[fb[64 + t] * 512 + d] + pos) + a;
      } else if (t < 69) {
        v = fen_emb[fb[t + 64] * 512 + d] + a;
      } else {
        int j = t - 69;
        int s = move[b * 2 + j];
        float pos = rank_emb[(s >> 3) * 512 + d] + file_emb[(s & 7) * 512 + d];
        v = (pos + move_emb[j * 512 + d]) * 0.58f + a;
      }
      if (pass) X71[(size_t)gid * 71 + t] = tobf((v - mu) * rstd * lnw[t] + lnb[t]);
      else { sum += v; sq += v * v; }
    }
  }
}

// ---------------------------------------------------------------------------
// T=71 embedding QKV projection + fused token-axis RMS (round 8, validated).
// Runs once per forward; uses Wq0 [j][d] layout.
// ---------------------------------------------------------------------------
template <int T, int TP>
__global__ __launch_bounds__(256) void proj71_kernel(
    const __hip_bfloat16* __restrict__ xin, const __hip_bfloat16* __restrict__ Wq,
    const float* __restrict__ nw,
    __hip_bfloat16* __restrict__ qk, __hip_bfloat16* __restrict__ vT)
{
  const int b  = blockIdx.x / 6;
  const int jb = (blockIdx.x % 6) * 256;
  const int tid = threadIdx.x;
  const int lane = tid & 63, wv = tid >> 6;
  const int lr = lane & 15, lg = lane >> 4;

  __shared__ __hip_bfloat16 xt[TP * 72];
  __shared__ __hip_bfloat16 wl[256 * 72];

  constexpr int MI = TP / 16;
  f32x4 acc[MI][4];
  #pragma unroll
  for (int mi = 0; mi < MI; ++mi)
    #pragma unroll
    for (int ni = 0; ni < 4; ++ni) acc[mi][ni] = {0.f, 0.f, 0.f, 0.f};

  for (int c0 = 0; c0 < 512; c0 += 64) {
    for (int i = tid; i < 64 * TP; i += 256) {
      int d = i / TP, t = i - d * TP;
      float v = (t < T) ? lrelu(frombf(xin[((size_t)(b * 512 + c0 + d)) * T + t])) : 0.f;
      xt[t * 72 + d] = tobf(v);
    }
    for (int i = tid; i < 2048; i += 256) {
      int j = i >> 3, cb = i & 7;
      *(uint4*)&wl[j * 72 + cb * 8] =
          *(const uint4*)&Wq[(size_t)(jb + j) * 512 + c0 + cb * 8];
    }
    __syncthreads();
    #pragma unroll
    for (int ks = 0; ks < 2; ++ks) {
      short8 a[MI], bb[4];
      #pragma unroll
      for (int mi = 0; mi < MI; ++mi)
        a[mi] = *(const short8*)&xt[(mi * 16 + lr) * 72 + ks * 32 + lg * 8];
      #pragma unroll
      for (int ni = 0; ni < 4; ++ni)
        bb[ni] = *(const short8*)&wl[(wv * 64 + ni * 16 + lr) * 72 + ks * 32 + lg * 8];
      #pragma unroll
      for (int mi = 0; mi < MI; ++mi)
        #pragma unroll
        for (int ni = 0; ni < 4; ++ni)
          acc[mi][ni] = __builtin_amdgcn_mfma_f32_16x16x32_bf16(
              a[mi], bb[ni], acc[mi][ni], 0, 0, 0);
    }
    __syncthreads();
  }

  #pragma unroll
  for (int ni = 0; ni < 4; ++ni) {
    const int j = jb + wv * 64 + ni * 16 + lr;
    float ss = 0.f;
    #pragma unroll
    for (int mi = 0; mi < MI; ++mi)
      #pragma unroll
      for (int r = 0; r < 4; ++r) ss += acc[mi][ni][r] * acc[mi][ni][r];
    ss += __shfl_xor(ss, 16);
    ss += __shfl_xor(ss, 32);
    const float sc = nw[0] * rsqrtf(ss * (1.f / T) + 1e-6f);
    if (j < 1024) {
      #pragma unroll
      for (int mi = 0; mi < MI; ++mi)
        #pragma unroll
        for (int r = 0; r < 4; ++r) {
          int t = mi * 16 + lg * 4 + r;
          if (t < T)
            qk[((size_t)b * T + t) * 1024 + j] = tobf(acc[mi][ni][r] * sc);
        }
    } else {
      const int jj = j - 1024;
      #pragma unroll
      for (int mi = 0; mi < MI; ++mi)
        #pragma unroll
        for (int r = 0; r < 4; ++r) {
          int t = mi * 16 + lg * 4 + r;   // rows t>=T are true zeros -> valid pad
          vT[((size_t)b * 512 + jj) * TP + t] = tobf(acc[mi][ni][r] * sc);
        }
    }
  }
}

// ---------------------------------------------------------------------------
// T=64 QKV projection, conv_mfma2-style: weights direct global->VGPR from
// fragment slabs; LDS = double-buffered 64x72 transposed activation tile;
// 1 barrier per K-chunk. Fused token-axis RMS epilogue (validated round 8).
// ---------------------------------------------------------------------------
__global__ __launch_bounds__(256) void proj64_kernel(
    const float* __restrict__ x,            // (B,512,64) f32
    const __hip_bfloat16* __restrict__ Wq2, // fragment slabs for this layer
    const float* __restrict__ nw,
    __hip_bfloat16* __restrict__ qk, __hip_bfloat16* __restrict__ vT)
{
  const int b    = blockIdx.x / 6;
  const int jseg = blockIdx.x % 6;
  const int tid = threadIdx.x;
  const int lane = tid & 63, wv = tid >> 6;
  const int lr = lane & 15, lg = lane >> 4;

  __shared__ __hip_bfloat16 xt[2][64 * 72];

  f32x4 acc[4][4];
  #pragma unroll
  for (int mi = 0; mi < 4; ++mi)
    #pragma unroll
    for (int ni = 0; ni < 4; ++ni) acc[mi][ni] = {0.f, 0.f, 0.f, 0.f};

  f32x4 sreg[4];
  const int s_d  = tid >> 4;           // d within chunk (+u*16)
  const int s_t4 = (tid & 15) << 2;    // 4 consecutive tokens

  #define PSTAGE_LOAD(kc_)                                                    \
    {                                                                         \
      const float* xb_ = x + ((size_t)b * 512 + (kc_) * 64 + s_d) * 64 + s_t4; \
      _Pragma("unroll")                                                       \
      for (int u = 0; u < 4; ++u) sreg[u] = *(const f32x4*)&xb_[u * 1024];    \
    }
  #define PSTAGE_WRITE(buf_)                                                  \
    {                                                                         \
      _Pragma("unroll")                                                       \
      for (int u = 0; u < 4; ++u) {                                           \
        _Pragma("unroll")                                                     \
        for (int j = 0; j < 4; ++j)                                           \
          xt[buf_][(s_t4 + j) * 72 + s_d + u * 16] = tobf(lrelu(sreg[u][j])); \
      }                                                                       \
    }

  PSTAGE_LOAD(0);
  PSTAGE_WRITE(0);
  __syncthreads();

  const int njb0 = jseg * 16 + wv * 4;

  for (int kc = 0; kc < 8; ++kc) {
    const int cur = kc & 1;
    if (kc < 7) PSTAGE_LOAD(kc + 1);
    const __hip_bfloat16* xb = xt[cur];
    #pragma unroll
    for (int ks = 0; ks < 2; ++ks) {
      short8 bv[4], av[4];
      #pragma unroll
      for (int ni = 0; ni < 4; ++ni)
        bv[ni] = *(const short8*)
            &Wq2[((((size_t)kc * 2 + ks) * 96) + njb0 + ni) * 512 + lane * 8];
      #pragma unroll
      for (int mi = 0; mi < 4; ++mi)
        av[mi] = *(const short8*)&xb[(mi * 16 + lr) * 72 + ks * 32 + lg * 8];
      #pragma unroll
      for (int mi = 0; mi < 4; ++mi)
        #pragma unroll
        for (int ni = 0; ni < 4; ++ni)
          acc[mi][ni] = __builtin_amdgcn_mfma_f32_16x16x32_bf16(
              av[mi], bv[ni], acc[mi][ni], 0, 0, 0);
    }
    if (kc < 7) PSTAGE_WRITE(cur ^ 1);
    __syncthreads();
  }
  #undef PSTAGE_LOAD
  #undef PSTAGE_WRITE

  // epilogue: per-column RMS over token axis, then Q/K or V^T writes.
  #pragma unroll
  for (int ni = 0; ni < 4; ++ni) {
    const int j = jseg * 256 + wv * 64 + ni * 16 + lr;
    float ss = 0.f;
    #pragma unroll
    for (int mi = 0; mi < 4; ++mi)
      #pragma unroll
      for (int r = 0; r < 4; ++r) ss += acc[mi][ni][r] * acc[mi][ni][r];
    ss += __shfl_xor(ss, 16);
    ss += __shfl_xor(ss, 32);
    const float sc = nw[0] * rsqrtf(ss * (1.f / 64.f) + 1e-6f);
    if (j < 1024) {
      #pragma unroll
      for (int mi = 0; mi < 4; ++mi)
        #pragma unroll
        for (int r = 0; r < 4; ++r) {
          int t = mi * 16 + lg * 4 + r;
          qk[((size_t)b * 64 + t) * 1024 + j] = tobf(acc[mi][ni][r] * sc);
        }
    } else {
      const int jj = j - 1024;
      #pragma unroll
      for (int mi = 0; mi < 4; ++mi)
        #pragma unroll
        for (int r = 0; r < 4; ++r) {
          int t = mi * 16 + lg * 4 + r;
          vT[((size_t)b * 512 + jj) * 64 + t] = tobf(acc[mi][ni][r] * sc);
        }
    }
  }
}

// ---------------------------------------------------------------------------
// MFMA attention per (b,h): S = Q·K^T/8 -> softmax -> O = P·V (+residual).
// Validated round 8.
// ---------------------------------------------------------------------------
template <int T, bool RESBF>
__global__ __launch_bounds__(256) void attn2_kernel(
    const __hip_bfloat16* __restrict__ qk,   // [b][t][1024] RMS'd Q|K
    const __hip_bfloat16* __restrict__ vT,   // [b][jj][TP]  RMS'd V^T
    const void* __restrict__ res, float* __restrict__ out)
{
  constexpr int TP = (T == 71) ? 80 : 64;    // vT global row stride
  constexpr int TK = (T + 31) / 32;          // PV K steps (2 or 3)
  constexpr int RS = 72;                     // q/k LDS row stride (bf16)
  constexpr int PS = TK * 32 + 8;            // vt/plds LDS row stride (72/104)
  constexpr int KR = (T == 71) ? 80 : 64;    // k LDS rows (key frag coverage)
  constexpr int SC = (T == 71) ? 82 : 66;    // slds f32 row stride
  constexpr int NCF = KR / 16;               // S col frags (5 or 4)
  constexpr int NFW = (NCF + 3) / 4;         // col frags per wave
  constexpr int RANGE = (TK * 32) / 4;       // softmax cols per thread (16/24)

  constexpr int Q_OFF = 0;
  constexpr int K_OFF = Q_OFF + 64 * RS * 2;
  constexpr int V_OFF = K_OFF + KR * RS * 2;
  constexpr int S_OFF = V_OFF + 64 * PS * 2;
  constexpr int BYTES = S_OFF + 64 * SC * 4;
  __shared__ __align__(16) char smem[BYTES];
  __hip_bfloat16* qs = (__hip_bfloat16*)(smem + Q_OFF);
  __hip_bfloat16* ksh = (__hip_bfloat16*)(smem + K_OFF);
  __hip_bfloat16* vs = (__hip_bfloat16*)(smem + V_OFF);
  float* ss = (float*)(smem + S_OFF);
  __hip_bfloat16* ps = (__hip_bfloat16*)(smem + S_OFF);   // alias (two-pass)

  const int b = blockIdx.x >> 3, h = blockIdx.x & 7;
  const int tid = threadIdx.x;
  const int lane = tid & 63, wv = tid >> 6;
  const int lr = lane & 15, lg = lane >> 4;

  for (int i = tid; i < BYTES / 16; i += 256) ((uint4*)smem)[i] = uint4{0, 0, 0, 0};
  __syncthreads();

  const __hip_bfloat16* qb = qk + (size_t)b * T * 1024 + h * 64;
  for (int v = tid; v < 512; v += 256) {
    int t = v >> 3, d0 = (v & 7) * 8;
    *(uint4*)&qs[t * RS + d0] = *(const uint4*)&qb[(size_t)t * 1024 + d0];
  }
  for (int v = tid; v < T * 8; v += 256) {
    int t = v >> 3, d0 = (v & 7) * 8;
    *(uint4*)&ksh[t * RS + d0] = *(const uint4*)&qb[(size_t)t * 1024 + 512 + d0];
  }
  constexpr int VV = TP / 8;
  for (int v = tid; v < 64 * VV; v += 256) {
    int dh = v / VV, tc = (v - dh * VV) * 8;
    *(uint4*)&vs[dh * PS + tc] =
        *(const uint4*)&vT[((size_t)b * 512 + h * 64 + dh) * TP + tc];
  }
  __syncthreads();

  // S = Q.K^T * 0.125
  f32x4 sacc[NFW][4];
  #pragma unroll
  for (int fi = 0; fi < NFW; ++fi)
    #pragma unroll
    for (int mi = 0; mi < 4; ++mi) sacc[fi][mi] = {0.f, 0.f, 0.f, 0.f};
  #pragma unroll
  for (int ks2 = 0; ks2 < 2; ++ks2) {
    short8 a[4];
    #pragma unroll
    for (int mi = 0; mi < 4; ++mi)
      a[mi] = *(const short8*)&qs[(mi * 16 + lr) * RS + ks2 * 32 + lg * 8];
    #pragma unroll
    for (int fi = 0; fi < NFW; ++fi) {
      const int f = wv + fi * 4;
      if (f < NCF) {
        short8 bb = *(const short8*)&ksh[(f * 16 + lr) * RS + ks2 * 32 + lg * 8];
        #pragma unroll
        for (int mi = 0; mi < 4; ++mi)
          sacc[fi][mi] = __builtin_amdgcn_mfma_f32_16x16x32_bf16(
              a[mi], bb, sacc[fi][mi], 0, 0, 0);
      }
    }
  }
  #pragma unroll
  for (int fi = 0; fi < NFW; ++fi) {
    const int f = wv + fi * 4;
    if (f < NCF) {
      #pragma unroll
      for (int mi = 0; mi < 4; ++mi)
        #pragma unroll
        for (int r = 0; r < 4; ++r)
          ss[(mi * 16 + lg * 4 + r) * SC + f * 16 + lr] = sacc[fi][mi][r] * 0.125f;
    }
  }
  __syncthreads();

  // softmax: 4 threads per row; pass 1 read+reduce, pass 2 write P (bf16).
  {
    const int row = tid >> 2, q4 = tid & 3;
    float sv[RANGE];
    float mx = -3.0e38f;
    #pragma unroll
    for (int i = 0; i < RANGE; ++i) {
      int c = q4 * RANGE + i;
      sv[i] = (c < T) ? ss[row * SC + c] : -3.0e38f;
      mx = fmaxf(mx, sv[i]);
    }
    mx = fmaxf(mx, __shfl_xor(mx, 1));
    mx = fmaxf(mx, __shfl_xor(mx, 2));
    float sm = 0.f;
    #pragma unroll
    for (int i = 0; i < RANGE; ++i) {
      int c = q4 * RANGE + i;
      sv[i] = (c < T) ? __expf(sv[i] - mx) : 0.f;
      sm += sv[i];
    }
    sm += __shfl_xor(sm, 1);
    sm += __shfl_xor(sm, 2);
    const float inv = 1.f / sm;
    __syncthreads();   // all S reads complete before P overwrites the region
    #pragma unroll
    for (int i = 0; i < RANGE; ++i)
      ps[row * PS + q4 * RANGE + i] = tobf(sv[i] * inv);
  }
  __syncthreads();

  // O = P.V
  f32x4 oacc[4];
  #pragma unroll
  for (int mi = 0; mi < 4; ++mi) oacc[mi] = {0.f, 0.f, 0.f, 0.f};
  #pragma unroll
  for (int ks2 = 0; ks2 < TK; ++ks2) {
    short8 bb = *(const short8*)&vs[(wv * 16 + lr) * PS + ks2 * 32 + lg * 8];
    #pragma unroll
    for (int mi = 0; mi < 4; ++mi) {
      short8 a = *(const short8*)&ps[(mi * 16 + lr) * PS + ks2 * 32 + lg * 8];
      oacc[mi] = __builtin_amdgcn_mfma_f32_16x16x32_bf16(a, bb, oacc[mi], 0, 0, 0);
    }
  }

  const int dh = wv * 16 + lr;
  const size_t chb = (size_t)b * 512 + h * 64 + dh;
  #pragma unroll
  for (int mi = 0; mi < 4; ++mi) {
    const int t0 = mi * 16 + lg * 4;
    const size_t idx = chb * 64 + t0;
    f32x4 v = oacc[mi];
    if constexpr (RESBF) {
      const __hip_bfloat16* rb = (const __hip_bfloat16*)res + chb * T + t0;
      #pragma unroll
      for (int r = 0; r < 4; ++r) v[r] += frombf(rb[r]);
    } else {
      v += *(const f32x4*)&((const float*)res)[idx];
    }
    *(f32x4*)&out[idx] = v;
  }
}

// ---------------------------------------------------------------------------
// MFMA conv 3x3 SAME on 8x8, CIN=512, weights direct global->VGPR (validated
// round 7). One barrier per cc; LDS = double-buffered 10x10 activation board.
// ---------------------------------------------------------------------------
template <bool RMSOUT, bool RESADD>
__global__ __launch_bounds__(256) void conv_mfma2(
    const float* __restrict__ x,            // (B,512,64) f32
    const __hip_bfloat16* __restrict__ W2,  // fragment slabs (see repack)
    const float* __restrict__ bias,         // (COUT)
    const float* __restrict__ nw,           // scalar rms weight (RMSOUT)
    const float* __restrict__ res,          // (B,COUT,64) f32 (RESADD)
    float* __restrict__ out,                // (B,COUT,64) f32
    int COUT)
{
  const int ntc = COUT >> 8;
  const int b = blockIdx.x / ntc;
  const int nt = blockIdx.x - b * ntc;
  const int o0 = nt << 8;
  const int NJ = COUT >> 4;
  const int tid = threadIdx.x;
  const int lane = tid & 63, wv = tid >> 6;
  const int lr = lane & 15, lg = lane >> 4;

  __shared__ __hip_bfloat16 xt[2][100 * 72];  // 10x10 zero-bordered boards

  f32x4 acc[4][4];
  #pragma unroll
  for (int mi = 0; mi < 4; ++mi)
    #pragma unroll
    for (int ni = 0; ni < 4; ++ni) acc[mi][ni] = {0.f, 0.f, 0.f, 0.f};

  for (int i = tid; i < 7200; i += 256) { xt[0][i] = tobf(0.f); xt[1][i] = tobf(0.f); }

  f32x4 sreg[4];
  const int s_ci = tid >> 4;
  const int s_p4 = (tid & 15) << 2;
  const int s_row = (((s_p4 >> 3) + 1) * 10 + (s_p4 & 7) + 1) * 72;

  #define STAGE_LOAD(cc_)                                                     \
    {                                                                         \
      const float* xb_ = x + ((size_t)b * 512 + (cc_) * 64 + s_ci) * 64 + s_p4; \
      _Pragma("unroll")                                                       \
      for (int u = 0; u < 4; ++u) sreg[u] = *(const f32x4*)&xb_[u * 1024];    \
    }
  #define STAGE_WRITE(buf_)                                                   \
    {                                                                         \
      _Pragma("unroll")                                                       \
      for (int u = 0; u < 4; ++u) {                                           \
        _Pragma("unroll")                                                     \
        for (int j = 0; j < 4; ++j)                                           \
          xt[buf_][s_row + j * 72 + s_ci + u * 16] = tobf(lrelu(sreg[u][j])); \
      }                                                                       \
    }

  STAGE_LOAD(0);
  __syncthreads();
  STAGE_WRITE(0);
  __syncthreads();

  const int ojb2 = ((o0 >> 4) + wv * 4) * 2;

  for (int cc = 0; cc < 8; ++cc) {
    const int cur = cc & 1;
    if (cc < 7) STAGE_LOAD(cc + 1);
    const __hip_bfloat16* xb = xt[cur];

    #pragma unroll
    for (int k = 0; k < 9; ++k) {
      const int dy = k / 3 - 1, dx = k - (k / 3) * 3 - 1;
      const int ii0 = (lr >> 3) + dy + 1;
      const int jj0 = (lr & 7) + dx + 1;
      const size_t slab = ((size_t)(cc * 9 + k) * NJ) * 2 + ojb2;
      short8 bv[2][4], av[2][4];
      #pragma unroll
      for (int ni = 0; ni < 4; ++ni)
        #pragma unroll
        for (int ks = 0; ks < 2; ++ks)
          bv[ks][ni] = *(const short8*)&W2[(slab + ni * 2 + ks) * 512 + lane * 8];
      #pragma unroll
      for (int ks = 0; ks < 2; ++ks)
        #pragma unroll
        for (int mi = 0; mi < 4; ++mi)
          av[ks][mi] = *(const short8*)&xb[((ii0 + mi * 2) * 10 + jj0) * 72 + ks * 32 + lg * 8];
      #pragma unroll
      for (int ks = 0; ks < 2; ++ks)
        #pragma unroll
        for (int mi = 0; mi < 4; ++mi)
          #pragma unroll
          for (int ni = 0; ni < 4; ++ni)
            acc[mi][ni] = __builtin_amdgcn_mfma_f32_16x16x32_bf16(
                av[ks][mi], bv[ks][ni], acc[mi][ni], 0, 0, 0);
    }
    if (cc < 7) STAGE_WRITE(cur ^ 1);
    __syncthreads();
  }
  #undef STAGE_LOAD
  #undef STAGE_WRITE

  #pragma unroll
  for (int ni = 0; ni < 4; ++ni) {
    const int o = o0 + wv * 64 + ni * 16 + lr;
    const float bvs = bias[o];
    float sc = 1.f;
    if constexpr (RMSOUT) {
      float ssq = 0.f;
      #pragma unroll
      for (int mi = 0; mi < 4; ++mi)
        #pragma unroll
        for (int r = 0; r < 4; ++r) {
          float v = acc[mi][ni][r] + bvs;
          ssq += v * v;
        }
      ssq += __shfl_xor(ssq, 16);
      ssq += __shfl_xor(ssq, 32);
      sc = nw[0] * rsqrtf(ssq * (1.f / 64.f) + 1e-6f);
    }
    #pragma unroll
    for (int mi = 0; mi < 4; ++mi) {
      size_t idx = ((size_t)b * COUT + o) * 64 + mi * 16 + lg * 4;
      f32x4 v;
      #pragma unroll
      for (int r = 0; r < 4; ++r) v[r] = (acc[mi][ni][r] + bvs) * sc;
      if constexpr (RESADD) v += *(const f32x4*)&res[idx];
      *(f32x4*)&out[idx] = v;
    }
  }
}

// ---------------------------------------------------------------------------
// Final VALID 8x8 conv: out[b] = sum_{c,p} lrelu(F1[b,c,p]) * w[c,p] + bias.
// ---------------------------------------------------------------------------
__global__ __launch_bounds__(256) void co2_kernel(
    const float* __restrict__ xf, const float* __restrict__ w,
    const float* __restrict__ cb, float* __restrict__ out)
{
  const int b = blockIdx.x, tid = threadIdx.x;
  const float* xb = xf + (size_t)b * 65536;
  float acc = 0.f;
  for (int i = tid; i < 65536; i += 256)
    acc += lrelu(xb[i]) * w[i];
  #pragma unroll
  for (int off = 32; off; off >>= 1) acc += __shfl_down(acc, off);
  __shared__ float red[4];
  if ((tid & 63) == 0) red[tid >> 6] = acc;
  __syncthreads();
  if (tid == 0) out[b] = red[0] + red[1] + red[2] + red[3] + cb[0];
}

// ---------------------------------------------------------------------------
extern "C" void kernel_launch(void* const* d_in, const int* in_sizes, int n_in,
                              void* d_out, int out_size, void* d_ws, size_t ws_size,
                              hipStream_t stream)
{
  const int*   fen        = (const int*)d_in[0];
  const int*   move       = (const int*)d_in[1];
  const float* rank_emb   = (const float*)d_in[2];
  const float* file_emb   = (const float*)d_in[3];
  const float* fen_emb    = (const float*)d_in[4];
  const float* move_emb   = (const float*)d_in[5];
  const float* abs_emb    = (const float*)d_in[6];
  const float* ln_w       = (const float*)d_in[7];
  const float* ln_b       = (const float*)d_in[8];
  const float* emb_qkv    = (const float*)d_in[9];
  const float* emb_norm_w = (const float*)d_in[10];
  const float* qkvw_in    = (const float*)d_in[11];
  const float* mha_norm_w = (const float*)d_in[12];
  const float* conv1_w    = (const float*)d_in[13];
  const float* conv1_b    = (const float*)d_in[14];
  const float* conv2_w    = (const float*)d_in[15];
  const float* conv2_b    = (const float*)d_in[16];
  const float* cb_norm_w  = (const float*)d_in[17];
  const float* out_norm_w = (const float*)d_in[18];
  const float* co1_w      = (const float*)d_in[19];
  const float* co1_b      = (const float*)d_in[20];
  const float* co2_w      = (const float*)d_in[21];
  const float* co2_b      = (const float*)d_in[22];
  float* out = (float*)d_out;

  char* base = (char*)d_ws;
  __hip_bfloat16* X71 = (__hip_bfloat16*)base;                       // 18,612,224 B
  float* X64 = (float*)(base + 18612224);                            // 33,554,432 B
  float* T1  = (float*)(base + 18612224 + 33554432);                 // 67,108,864 B
  __hip_bfloat16* Wq0 = (__hip_bfloat16*)(base + 119275520);         //  1,572,864 B
  __hip_bfloat16* Wq2 = (__hip_bfloat16*)(base + 120848384);         // 12,582,912 B
  // attn intermediates alias T1 (dead during conv phases and vice versa):
  __hip_bfloat16* qk2 = (__hip_bfloat16*)T1;                         // <=37,224,448 B
  __hip_bfloat16* vTb = (__hip_bfloat16*)((char*)T1 + 37224448);     // <=20,971,520 B
  float* F1 = T1;                                                    // co1 out, 67MB
  // conv weight slabs alias X71 region (dead after embedding attn):
  __hip_bfloat16* WcA = (__hip_bfloat16*)base;                 // up to 9,437,184 B (co1)
  __hip_bfloat16* WcB = (__hip_bfloat16*)(base + 4718592);     // 4,718,592 B

  // one-time QKV weight repacks
  repack_qkv_w0<<<3072, 256, 0, stream>>>(emb_qkv, Wq0);
  repack_qkv_w2<<<3072, 256, 0, stream>>>(qkvw_in, Wq2);

  // embeddings + layernorm -> X71 (bf16)
  build_ln_kernel<<<512, 256, 0, stream>>>(fen, move, rank_emb, file_emb,
                                           fen_emb, move_emb, abs_emb,
                                           ln_w, ln_b, X71);
  // embedding MHA (T=71): proj(+RMS) -> attn2 (residual = X71[:, :, :64])
  proj71_kernel<71, 80><<<1536, 256, 0, stream>>>(X71, Wq0, emb_norm_w, qk2, vTb);
  attn2_kernel<71, true><<<2048, 256, 0, stream>>>(qk2, vTb, X71, X64);

  for (int l = 0; l < 8; ++l) {
    repack_conv_w2<<<128, 256, 0, stream>>>(conv1_w + (size_t)l * 512 * 512 * 9,
                                            WcA, 512);
    conv_mfma2<true, false><<<512, 256, 0, stream>>>(X64, WcA, conv1_b + l * 512,
                                                     cb_norm_w + l, nullptr, T1, 512);
    repack_conv_w2<<<128, 256, 0, stream>>>(conv2_w + (size_t)l * 512 * 512 * 9,
                                            WcB, 512);
    conv_mfma2<false, true><<<512, 256, 0, stream>>>(T1, WcB, conv2_b + l * 512,
                                                     nullptr, X64, X64, 512);
    // MHA (T=64)
    proj64_kernel<<<1536, 256, 0, stream>>>(X64, Wq2 + (size_t)l * 786432,
                                            mha_norm_w + l, qk2, vTb);
    attn2_kernel<64, false><<<2048, 256, 0, stream>>>(qk2, vTb, X64, X64);
  }

  // head: co1 (512->1024 SAME, RMS fused) -> co2 (VALID 8x8 -> scalar)
  repack_conv_w2<<<256, 256, 0, stream>>>(co1_w, WcA, 1024);
  conv_mfma2<true, false><<<1024, 256, 0, stream>>>(X64, WcA, co1_b,
                                                    out_norm_w, nullptr, F1, 1024);
  co2_kernel<<<256, 256, 0, stream>>>(F1, co2_w, co2_b, out);
}